// Round 8
// baseline (1534.704 us; speedup 1.0000x reference)
//
#include <hip/hip_runtime.h>
#include <hip/hip_cooperative_groups.h>

#define NNODES 4096
#define NEDGES 65536
#define CH 128

namespace cg = cooperative_groups;

typedef __bf16 bf16x8_t __attribute__((ext_vector_type(8)));
typedef __bf16 bf16x4_t __attribute__((ext_vector_type(4)));
typedef __bf16 bf16x2_t __attribute__((ext_vector_type(2)));
typedef float f32x4_t __attribute__((ext_vector_type(4)));

// ---- fast tanh via hw exp2/rcp ----
__device__ __forceinline__ float fast_tanh(float x)
{
  float t = __builtin_amdgcn_exp2f(x * 2.885390081777927f);   // 2*log2(e)
  return 1.f - 2.f * __builtin_amdgcn_rcpf(t + 1.f);
}

// ---- block stats writer: f32 wave shfl-reduce, one float2 per block ----
__device__ __forceinline__ void write_stats(float s, float q, float2* __restrict__ partials,
                                            int pid, int tid, int nwaves)
{
#pragma unroll
  for (int d = 1; d < 64; d <<= 1) { s += __shfl_xor(s, d); q += __shfl_xor(q, d); }
  __shared__ float rs[8][2];
  const int wv = tid >> 6, lane = tid & 63;
  if (lane == 0) { rs[wv][0] = s; rs[wv][1] = q; }
  __syncthreads();
  if (tid == 0) {
    float S = 0.f, Q = 0.f;
    for (int i = 0; i < nwaves; ++i) { S += rs[i][0]; Q += rs[i][1]; }
    partials[pid] = {S, Q};
  }
}

// ---- inline params: f64 cross-block reduce of f32 partials -> (mean,rstd) or (factor,0) ----
__device__ __forceinline__ float2 params_inline(const float2* __restrict__ pp,
                                                int nblk, double M, int type)
{
  const int tid = threadIdx.x;
  double s = 0.0, q = 0.0;
  for (int i = tid; i < nblk; i += 256) { float2 v = pp[i]; s += (double)v.x; q += (double)v.y; }
#pragma unroll
  for (int d = 1; d < 64; d <<= 1) { s += __shfl_xor(s, d); q += __shfl_xor(q, d); }
  __shared__ double rs4[4], rq4[4];
  __shared__ float pr[2];
  const int wv = tid >> 6, lane = tid & 63;
  if (lane == 0) { rs4[wv] = s; rq4[wv] = q; }
  __syncthreads();
  if (tid == 0) {
    double S = rs4[0] + rs4[1] + rs4[2] + rs4[3];
    double Q = rq4[0] + rq4[1] + rq4[2] + rq4[3];
    if (type == 0) {
      double mean = S / M;
      double var = Q / M - mean * mean;
      if (var < 0.0) var = 0.0;
      pr[0] = (float)mean;
      pr[1] = (float)(1.0 / sqrt(var + 1e-5));
    } else {
      double var = (Q - S * S / M) / (M - 1.0);
      if (var < 1e-30) var = 1e-30;
      pr[0] = (float)(-2.0 / sqrt(var));
      pr[1] = 0.f;
    }
  }
  __syncthreads();
  return {pr[0], pr[1]};
}

// ================= cooperative fused opening edge double-layer =================
// phase A: eA = xe64 @ K1E^T (K=64), stats -> LDS ; grid sync ;
// phase B: xeT = tanh(ln(eA)) @ K2E^T (K=128), store global
__global__ __launch_bounds__(256, 4) void oedge_k(
    const __bf16* __restrict__ K1Eb, const __bf16* __restrict__ K2Eb,
    const __bf16* __restrict__ xeT64, __bf16* __restrict__ xeT,
    float2* __restrict__ pS)
{
  __shared__ __bf16 eAl[64 * 132];
  cg::grid_group grid = cg::this_grid();
  const int tid = threadIdx.x;
  const int wv = tid >> 6, lane = tid & 63;
  const int l15 = lane & 15, ks = lane >> 4;
  const int row = wv * 16 + l15;
  const int e = blockIdx.x * 64 + row;

  bf16x8_t bq[2];
  {
    const __bf16* xr = xeT64 + (size_t)e * 64 + ks * 8;
    bq[0] = *(const bf16x8_t*)(xr);
    bq[1] = *(const bf16x8_t*)(xr + 32);
  }
  float dsum = 0.f, dsq = 0.f;
#pragma unroll
  for (int ob = 0; ob < 8; ++ob) {
    f32x4_t acc = {0.f, 0.f, 0.f, 0.f};
    const __bf16* ar = K1Eb + (size_t)(ob * 16 + l15) * 64 + ks * 8;
    acc = __builtin_amdgcn_mfma_f32_16x16x32_bf16(*(const bf16x8_t*)(ar), bq[0], acc, 0, 0, 0);
    acc = __builtin_amdgcn_mfma_f32_16x16x32_bf16(*(const bf16x8_t*)(ar + 32), bq[1], acc, 0, 0, 0);
    const int ro = ob * 16 + ks * 4;
    float v0 = acc[0], v1 = acc[1], v2 = acc[2], v3 = acc[3];
    dsum += v0 + v1 + v2 + v3;
    dsq  += v0 * v0 + v1 * v1 + v2 * v2 + v3 * v3;
    bf16x4_t bv;
    bv[0] = (__bf16)v0; bv[1] = (__bf16)v1; bv[2] = (__bf16)v2; bv[3] = (__bf16)v3;
    *(bf16x4_t*)(eAl + row * 132 + ro) = bv;
  }
  write_stats(dsum, dsq, pS, blockIdx.x, tid, 4);
  grid.sync();

  float2 p1 = params_inline(pS, 1024, (double)CH * NEDGES, 0);
  bf16x8_t bq2[4];
#pragma unroll
  for (int kk = 0; kk < 4; ++kk) {
    bf16x8_t v = *(const bf16x8_t*)(eAl + row * 132 + ks * 8 + kk * 32);
#pragma unroll
    for (int j = 0; j < 8; ++j) v[j] = (__bf16)fast_tanh(((float)v[j] - p1.x) * p1.y);
    bq2[kk] = v;
  }
#pragma unroll
  for (int ob = 0; ob < 8; ++ob) {
    f32x4_t acc = {0.f, 0.f, 0.f, 0.f};
    const __bf16* ar = K2Eb + (size_t)(ob * 16 + l15) * CH + ks * 8;
#pragma unroll
    for (int kk = 0; kk < 4; ++kk)
      acc = __builtin_amdgcn_mfma_f32_16x16x32_bf16(*(const bf16x8_t*)(ar + kk * 32), bq2[kk], acc, 0, 0, 0);
    const int ro = ob * 16 + ks * 4;
    bf16x4_t bv;
    bv[0] = (__bf16)acc[0]; bv[1] = (__bf16)acc[1];
    bv[2] = (__bf16)acc[2]; bv[3] = (__bf16)acc[3];
    *(bf16x4_t*)(xeT + (size_t)e * CH + ro) = bv;
  }
}

// ================= cooperative fused per-layer edge pipeline =================
// phase 0: factor <- dstat partials; w[e] (stored to wbuf + LDS)
// phase A: eA = xeT @ KE1^T + w*(U_I+V_J) -> LDS, stats -> pSA ; grid sync
// phase B: eB = tanh(ln(eA)) @ KE2^T -> LDS, stats -> pSB ; grid sync
// phase C: xeT += 0.1 * ln(eB)
__global__ __launch_bounds__(256, 4) void fedge_k(
    const __bf16* __restrict__ KE1bi, const __bf16* __restrict__ KE2bi,
    __bf16* __restrict__ xeT, const __bf16* __restrict__ UVb,
    const __bf16* __restrict__ xnNb, const float* __restrict__ sbufh,
    const int* __restrict__ iI, const int* __restrict__ jJ,
    float* __restrict__ wbuf,
    const float2* __restrict__ pD, float2* __restrict__ pSA, float2* __restrict__ pSB)
{
  __shared__ __bf16 eAl[64 * 132];
  __shared__ __bf16 xel[64 * 132];
  __shared__ float wl[64];
  cg::grid_group grid = cg::this_grid();
  const int tid = threadIdx.x;
  const int wv = tid >> 6, lane = tid & 63;
  const int l15 = lane & 15, ks = lane >> 4;
  const int row = wv * 16 + l15;
  const int e = blockIdx.x * 64 + row;

  // ---- phase 0 ----
  float2 fp = params_inline(pD, 2080, (double)NNODES * (double)NNODES, 1);
  {
    const int eg = blockIdx.x * 64 + (tid >> 2);
    const int a = iI[eg], b = jJ[eg];
    const bf16x8_t* pa = (const bf16x8_t*)(xnNb + (size_t)a * CH + (tid & 3) * 32);
    const bf16x8_t* pb = (const bf16x8_t*)(xnNb + (size_t)b * CH + (tid & 3) * 32);
    float g = 0.f;
#pragma unroll
    for (int q = 0; q < 4; ++q) {
      bf16x8_t u = pa[q], v = pb[q];
#pragma unroll
      for (int j = 0; j < 8; ++j) g = fmaf((float)u[j], (float)v[j], g);
    }
    g += __shfl_xor(g, 1); g += __shfl_xor(g, 2);
    float d = sbufh[a] + sbufh[NNODES + a] + sbufh[b] + sbufh[NNODES + b] - 2.f * g;
    d = d > 0.f ? d : 0.f;
    float wgt = __builtin_amdgcn_exp2f(fp.x * d * 1.4426950408889634f);
    if ((tid & 3) == 0) { wl[tid >> 2] = wgt; wbuf[eg] = wgt; }
  }
  __syncthreads();

  // ---- phase A ----
  const int ie = iI[e], je = jJ[e];
  const float we = wl[row];
  bf16x8_t bq[4];
  {
    const __bf16* xr = xeT + (size_t)e * CH + ks * 8;
#pragma unroll
    for (int kk = 0; kk < 4; ++kk) {
      bf16x8_t v = *(const bf16x8_t*)(xr + kk * 32);
      bq[kk] = v;
      *(bf16x8_t*)(xel + row * 132 + ks * 8 + kk * 32) = v;
    }
  }
  float dsum = 0.f, dsq = 0.f;
#pragma unroll
  for (int ob = 0; ob < 8; ++ob) {
    f32x4_t acc = {0.f, 0.f, 0.f, 0.f};
    const __bf16* ar = KE1bi + (size_t)(ob * 16 + l15) * CH + ks * 8;
#pragma unroll
    for (int kk = 0; kk < 4; ++kk)
      acc = __builtin_amdgcn_mfma_f32_16x16x32_bf16(*(const bf16x8_t*)(ar + kk * 32), bq[kk], acc, 0, 0, 0);
    const int ro = ob * 16 + ks * 4;
    bf16x4_t u4 = *(const bf16x4_t*)&UVb[(size_t)ie * 256 + ro];
    bf16x4_t w4 = *(const bf16x4_t*)&UVb[(size_t)je * 256 + 128 + ro];
    float v0 = acc[0] + we * ((float)u4[0] + (float)w4[0]);
    float v1 = acc[1] + we * ((float)u4[1] + (float)w4[1]);
    float v2 = acc[2] + we * ((float)u4[2] + (float)w4[2]);
    float v3 = acc[3] + we * ((float)u4[3] + (float)w4[3]);
    dsum += v0 + v1 + v2 + v3;
    dsq  += v0 * v0 + v1 * v1 + v2 * v2 + v3 * v3;
    bf16x4_t bv;
    bv[0] = (__bf16)v0; bv[1] = (__bf16)v1; bv[2] = (__bf16)v2; bv[3] = (__bf16)v3;
    *(bf16x4_t*)(eAl + row * 132 + ro) = bv;
  }
  write_stats(dsum, dsq, pSA, blockIdx.x, tid, 4);
  grid.sync();

  // ---- phase B ----
  float2 p1 = params_inline(pSA, 1024, (double)CH * NEDGES, 0);
  bf16x8_t bq2[4];
#pragma unroll
  for (int kk = 0; kk < 4; ++kk) {
    bf16x8_t v = *(const bf16x8_t*)(eAl + row * 132 + ks * 8 + kk * 32);
#pragma unroll
    for (int j = 0; j < 8; ++j) v[j] = (__bf16)fast_tanh(((float)v[j] - p1.x) * p1.y);
    bq2[kk] = v;
  }
  __syncthreads();           // all eA reads done before eB overwrites
  dsum = 0.f; dsq = 0.f;
#pragma unroll
  for (int ob = 0; ob < 8; ++ob) {
    f32x4_t acc = {0.f, 0.f, 0.f, 0.f};
    const __bf16* ar = KE2bi + (size_t)(ob * 16 + l15) * CH + ks * 8;
#pragma unroll
    for (int kk = 0; kk < 4; ++kk)
      acc = __builtin_amdgcn_mfma_f32_16x16x32_bf16(*(const bf16x8_t*)(ar + kk * 32), bq2[kk], acc, 0, 0, 0);
    const int ro = ob * 16 + ks * 4;
    float v0 = acc[0], v1 = acc[1], v2 = acc[2], v3 = acc[3];
    dsum += v0 + v1 + v2 + v3;
    dsq  += v0 * v0 + v1 * v1 + v2 * v2 + v3 * v3;
    bf16x4_t bv;
    bv[0] = (__bf16)v0; bv[1] = (__bf16)v1; bv[2] = (__bf16)v2; bv[3] = (__bf16)v3;
    *(bf16x4_t*)(eAl + row * 132 + ro) = bv;
  }
  write_stats(dsum, dsq, pSB, blockIdx.x, tid, 4);
  grid.sync();

  // ---- phase C ----
  float2 p2 = params_inline(pSB, 1024, (double)CH * NEDGES, 0);
#pragma unroll
  for (int kk = 0; kk < 4; ++kk) {
    bf16x8_t b8 = *(const bf16x8_t*)(eAl + row * 132 + ks * 8 + kk * 32);
    bf16x8_t x8 = *(const bf16x8_t*)(xel + row * 132 + ks * 8 + kk * 32);
    bf16x8_t o8;
#pragma unroll
    for (int j = 0; j < 8; ++j)
      o8[j] = (__bf16)((float)x8[j] + 0.1f * (((float)b8[j] - p2.x) * p2.y));
    *(bf16x8_t*)(xeT + (size_t)e * CH + ks * 8 + kk * 32) = o8;
  }
}

// ================= bf16 MFMA node GEMM, col-tiled =================
// OM 0: bf16 out; 1: +bias elu bf16 out; 2: +bias f32 out; 3: f32 out; 4: resid[n][128] += 0.1*v
// XSPLIT: K 0..255 from X (stride 256), rest from X2 (stride 128)
// XT: fast_tanh((x-m)*r) on X load; STATS: float2 partials; EMITB: also write bf16 + sqnorm half
template<int K, bool XSPLIT, bool XT, bool STATS, int OM, bool EMITB>
__global__ __launch_bounds__(256) void nmfma_k(
    const __bf16* __restrict__ A, const __bf16* __restrict__ X,
    const __bf16* __restrict__ X2,
    __bf16* __restrict__ Cb, float* __restrict__ Cf, float* __restrict__ resid,
    const float* __restrict__ bias, int nout_stride,
    float2* __restrict__ partials,
    const float2* __restrict__ pp, int pnblk, double pM,
    __bf16* __restrict__ xbout, float* __restrict__ shout)
{
  float p0 = 0.f, p1 = 0.f;
  if constexpr (XT) { float2 pr = params_inline(pp, pnblk, pM, 0); p0 = pr.x; p1 = pr.y; }
  const int tid = threadIdx.x;
  const int wv = tid >> 6, lane = tid & 63;
  const int l15 = lane & 15, ks = lane >> 4;
  const int n = blockIdx.x * 64 + wv * 16 + l15;
  constexpr int KK = K / 32;
  bf16x8_t bq[KK];
  if constexpr (XSPLIT) {
    const __bf16* xr  = X  + (size_t)n * 256 + ks * 8;
    const __bf16* xr2 = X2 + (size_t)n * 128 + ks * 8;
#pragma unroll
    for (int kk = 0; kk < 8; ++kk) bq[kk] = *(const bf16x8_t*)(xr + kk * 32);
#pragma unroll
    for (int kk = 8; kk < KK; ++kk) bq[kk] = *(const bf16x8_t*)(xr2 + (kk - 8) * 32);
  } else {
    const __bf16* xr = X + (size_t)n * K + ks * 8;
#pragma unroll
    for (int kk = 0; kk < KK; ++kk) {
      bf16x8_t v = *(const bf16x8_t*)(xr + kk * 32);
      if constexpr (XT) {
#pragma unroll
        for (int j = 0; j < 8; ++j) v[j] = (__bf16)fast_tanh(((float)v[j] - p0) * p1);
      }
      bq[kk] = v;
    }
  }
  float dsum = 0.f, dsq = 0.f, ss = 0.f;
  const int ob0 = blockIdx.y * 4;
#pragma unroll
  for (int obb = 0; obb < 4; ++obb) {
    const int ob = ob0 + obb;
    f32x4_t acc = {0.f, 0.f, 0.f, 0.f};
    const __bf16* ar = A + (size_t)(ob * 16 + l15) * K + ks * 8;
#pragma unroll
    for (int kk = 0; kk < KK; ++kk) {
      bf16x8_t a = *(const bf16x8_t*)(ar + kk * 32);
      acc = __builtin_amdgcn_mfma_f32_16x16x32_bf16(a, bq[kk], acc, 0, 0, 0);
    }
    const int ro = ob * 16 + ks * 4;
    float v[4] = {acc[0], acc[1], acc[2], acc[3]};
    if constexpr (OM == 1 || OM == 2) {
#pragma unroll
      for (int r = 0; r < 4; ++r) v[r] += bias[ro + r];
    }
    if constexpr (OM == 1) {
#pragma unroll
      for (int r = 0; r < 4; ++r) v[r] = v[r] > 0.f ? v[r] : expm1f(v[r]);
    }
    if constexpr (STATS) {
#pragma unroll
      for (int r = 0; r < 4; ++r) { dsum += v[r]; dsq += v[r] * v[r]; }
    }
    if constexpr (OM == 4) {
      float4* rp = (float4*)&resid[(size_t)n * 128 + ro];
      float4 rr = *rp;
      rr.x += 0.1f * v[0]; rr.y += 0.1f * v[1]; rr.z += 0.1f * v[2]; rr.w += 0.1f * v[3];
      *rp = rr;
      if constexpr (EMITB) {
        bf16x4_t eb;
        eb[0] = (__bf16)rr.x; eb[1] = (__bf16)rr.y; eb[2] = (__bf16)rr.z; eb[3] = (__bf16)rr.w;
        *(bf16x4_t*)(xbout + (size_t)n * 128 + ro) = eb;
#pragma unroll
        for (int r = 0; r < 4; ++r) { float f = (float)eb[r]; ss += f * f; }
      }
    } else if constexpr (OM == 2 || OM == 3) {
      float4 fv = {v[0], v[1], v[2], v[3]};
      *(float4*)(Cf + (size_t)n * nout_stride + ro) = fv;
      if constexpr (EMITB) {
        bf16x4_t eb;
        eb[0] = (__bf16)v[0]; eb[1] = (__bf16)v[1]; eb[2] = (__bf16)v[2]; eb[3] = (__bf16)v[3];
        *(bf16x4_t*)(xbout + (size_t)n * 128 + ro) = eb;
#pragma unroll
        for (int r = 0; r < 4; ++r) { float f = (float)eb[r]; ss += f * f; }
      }
    } else {
      bf16x4_t bv;
      bv[0] = (__bf16)v[0]; bv[1] = (__bf16)v[1]; bv[2] = (__bf16)v[2]; bv[3] = (__bf16)v[3];
      *(bf16x4_t*)(Cb + (size_t)n * nout_stride + ro) = bv;
    }
  }
  if constexpr (EMITB) {
    ss += __shfl_xor(ss, 16);
    ss += __shfl_xor(ss, 32);
    if (lane < 16) shout[blockIdx.y * NNODES + n] = ss;
  }
  if constexpr (STATS)
    write_stats(dsum, dsq, partials, blockIdx.y * gridDim.x + blockIdx.x, tid, 4);
}

// ================= dstat via MFMA Gram matrix, triangular 1-D grid (2080 blocks) =================
__global__ __launch_bounds__(256) void dstat_k(
    const __bf16* __restrict__ fT, const float* __restrict__ sh,
    float2* __restrict__ partials)
{
  int rem = blockIdx.x, i0t = 0;
  while (rem >= 64 - i0t) { rem -= 64 - i0t; ++i0t; }
  const int i0 = i0t * 64, j0 = (i0t + rem) * 64;
  const float wgt = (j0 > i0) ? 2.f : 1.f;
  const int tid = threadIdx.x;
  const int wv = tid >> 6, lane = tid & 63, l15 = lane & 15, ks = lane >> 4;
  const int irow = i0 + wv * 16 + l15;
  bf16x8_t aq[4];
  const __bf16* ar = fT + (size_t)irow * 128 + ks * 8;
#pragma unroll
  for (int kk = 0; kk < 4; ++kk) aq[kk] = *(const bf16x8_t*)(ar + kk * 32);
  float si[4];
#pragma unroll
  for (int r = 0; r < 4; ++r) {
    int ii = i0 + wv * 16 + ks * 4 + r;
    si[r] = sh[ii] + sh[NNODES + ii];
  }
  float dsum = 0.f, dsq = 0.f;
#pragma unroll
  for (int jb = 0; jb < 4; ++jb) {
    const int jcol = j0 + jb * 16 + l15;
    const __bf16* br = fT + (size_t)jcol * 128 + ks * 8;
    f32x4_t acc = {0.f, 0.f, 0.f, 0.f};
#pragma unroll
    for (int kk = 0; kk < 4; ++kk) {
      bf16x8_t b = *(const bf16x8_t*)(br + kk * 32);
      acc = __builtin_amdgcn_mfma_f32_16x16x32_bf16(aq[kk], b, acc, 0, 0, 0);
    }
    const float sj = sh[jcol] + sh[NNODES + jcol];
#pragma unroll
    for (int r = 0; r < 4; ++r) {
      float d = si[r] + sj - 2.f * acc[r];
      d = d > 0.f ? d : 0.f;
      dsum += d; dsq += d * d;
    }
  }
  write_stats(dsum * wgt, dsq * wgt, partials, blockIdx.x, tid, 4);
}

// ================= transpose src [64][ncols] f32 -> dst [ncols][64] bf16 =================
__global__ __launch_bounds__(256) void etrans_k(const float* __restrict__ src,
                                                __bf16* __restrict__ dst, int ncols)
{
  __shared__ float t[64][65];
  const int e0 = blockIdx.x * 64;
  const int tx = threadIdx.x & 63, tw = threadIdx.x >> 6;
  for (int c = tw; c < 64; c += 4)
    t[tx][c] = src[(size_t)c * ncols + e0 + tx];
  __syncthreads();
  const int el = threadIdx.x >> 2, c0 = (threadIdx.x & 3) * 16;
  for (int q = 0; q < 4; ++q) {
    int c = c0 + q * 4;
    bf16x4_t b;
    b[0] = (__bf16)t[el][c];     b[1] = (__bf16)t[el][c + 1];
    b[2] = (__bf16)t[el][c + 2]; b[3] = (__bf16)t[el][c + 3];
    *(bf16x4_t*)&dst[(size_t)(e0 + el) * 64 + c] = b;
  }
}

// ================= weight conversion to bf16 (one launch) =================
__global__ void wcvt_k(const float* __restrict__ K1E, const float* __restrict__ K2E,
                       const float* __restrict__ KE1, const float* __restrict__ KE2,
                       const float* __restrict__ KNc, const float* __restrict__ W1,
                       const float* __restrict__ W2, const float* __restrict__ KN1,
                       const float* __restrict__ KN2, const float* __restrict__ K1N,
                       const float* __restrict__ K2N,
                       __bf16* __restrict__ K1Eb, __bf16* __restrict__ K2Eb,
                       __bf16* __restrict__ KE1b, __bf16* __restrict__ KE2b,
                       __bf16* __restrict__ KNcb, __bf16* __restrict__ W1b,
                       __bf16* __restrict__ W2b, __bf16* __restrict__ KN1b,
                       __bf16* __restrict__ KN2b, __bf16* __restrict__ a1a2b,
                       __bf16* __restrict__ K1Nb, __bf16* __restrict__ K2Nb)
{
  int id = blockIdx.x * 256 + threadIdx.x;
  if (id < 8192) { K1Eb[id] = (__bf16)K1E[id]; return; }
  id -= 8192;
  if (id < 16384) { K2Eb[id] = (__bf16)K2E[id]; return; }
  id -= 16384;
  if (id < 65536) {
    int l = id >> 14, rem = id & 16383, r = rem >> 7, c = rem & 127;
    KE1b[id] = (__bf16)KE1[(size_t)l * 49152 + r * 384 + 128 + c];
    return;
  }
  id -= 65536;
  if (id < 65536) { KE2b[id] = (__bf16)KE2[id]; return; }
  id -= 65536;
  if (id < 16384) { KNcb[id] = (__bf16)KNc[id]; return; }
  id -= 16384;
  if (id < 32768) { W1b[id] = (__bf16)W1[id]; return; }
  id -= 32768;
  if (id < 262144) { W2b[id] = (__bf16)W2[id]; return; }
  id -= 262144;
  if (id < 196608) { KN1b[id] = (__bf16)KN1[id]; return; }
  id -= 196608;
  if (id < 65536) { KN2b[id] = (__bf16)KN2[id]; return; }
  id -= 65536;
  if (id < 131072) {
    int l = id >> 15, rem = id & 32767, r = rem >> 7, c = rem & 127;
    int o = r & 127;
    float k1 = KE1[(size_t)l * 49152 + o * 384 + c];
    float k3 = KE1[(size_t)l * 49152 + o * 384 + 256 + c];
    a1a2b[id] = (__bf16)((r < 128) ? (0.5f * k1 + k3) : (0.5f * k1 - k3));
    return;
  }
  id -= 131072;
  if (id < 8192) { K1Nb[id] = (__bf16)K1N[id]; return; }
  id -= 8192;
  if (id < 16384) { K2Nb[id] = (__bf16)K2N[id]; return; }
}

// ================= CSR build =================
__global__ void hist_k(const int* __restrict__ iI, const int* __restrict__ jJ,
                       int* __restrict__ cnt)
{
  int e = blockIdx.x * 256 + threadIdx.x;
  atomicAdd(&cnt[iI[e]], 1);
  atomicAdd(&cnt[jJ[e]], 1);
}

__global__ __launch_bounds__(1024) void scan_k(const int* __restrict__ cnt,
                                               int* __restrict__ offs,
                                               int* __restrict__ cursor)
{
  __shared__ int tmp[1024];
  const int tid = threadIdx.x;
  int4 v = *(const int4*)&cnt[tid * 4];
  int s = v.x + v.y + v.z + v.w;
  tmp[tid] = s; __syncthreads();
  for (int d = 1; d < 1024; d <<= 1) {
    int t = (tid >= d) ? tmp[tid - d] : 0;
    __syncthreads();
    tmp[tid] += t;
    __syncthreads();
  }
  int base = tmp[tid] - s;
  int4 o = {base, base + v.x, base + v.x + v.y, base + v.x + v.y + v.z};
  *(int4*)&offs[tid * 4] = o;
  *(int4*)&cursor[tid * 4] = o;
  if (tid == 1023) offs[4096] = tmp[1023];
}

__global__ void fill_k(const int* __restrict__ iI, const int* __restrict__ jJ,
                       int* __restrict__ cursor, int* __restrict__ list)
{
  int e = blockIdx.x * 256 + threadIdx.x;
  int p1 = atomicAdd(&cursor[iI[e]], 1);
  list[p1] = e;
  int p2 = atomicAdd(&cursor[jJ[e]], 1);
  list[p2] = e | 0x80000000;
}

// ================= gather: 8 waves, 2 per node (incidence-split) -> catb bf16 [n][256] =================
__global__ __launch_bounds__(512) void gather_k(
    const __bf16* __restrict__ xeT, const float* __restrict__ w,
    const int* __restrict__ offs, const int* __restrict__ list,
    __bf16* __restrict__ catb)
{
  __shared__ float comb[4][4][64];
  const int wv = threadIdx.x >> 6, lane = threadIdx.x & 63;
  const int nn = wv >> 1, half = wv & 1;
  const int n = blockIdx.x * 4 + nn;
  const int k0 = offs[n], k1 = offs[n + 1];
  float s1a = 0.f, s1b = 0.f, s2a = 0.f, s2b = 0.f;
#pragma unroll 2
  for (int k = k0 + half; k < k1; k += 2) {
    int enc = list[k];
    int e = enc & 0x7fffffff;
    float we = w[e];
    bf16x2_t xv = *(const bf16x2_t*)&xeT[(size_t)e * 128 + lane * 2];
    float va = (float)xv[0] * we;
    float vb = (float)xv[1] * we;
    if (enc >= 0) { s1a += va; s1b += vb; }
    else          { s2a += va; s2b += vb; }
  }
  if (half == 1) {
    comb[nn][0][lane] = s1a; comb[nn][1][lane] = s1b;
    comb[nn][2][lane] = s2a; comb[nn][3][lane] = s2b;
  }
  __syncthreads();
  if (half == 0) {
    s1a += comb[nn][0][lane]; s1b += comb[nn][1][lane];
    s2a += comb[nn][2][lane]; s2b += comb[nn][3][lane];
    __bf16* row = catb + (size_t)n * 256;
    bf16x2_t av, dv;
    av[0] = (__bf16)(0.5f * (s1a + s2a)); av[1] = (__bf16)(0.5f * (s1b + s2b));
    dv[0] = (__bf16)(s1a - s2a);          dv[1] = (__bf16)(s1b - s2b);
    *(bf16x2_t*)&row[lane * 2] = av;
    *(bf16x2_t*)&row[128 + lane * 2] = dv;
  }
}

// ================= log_softmax rows of [N][1024] =================
__global__ __launch_bounds__(256) void logsoftmax_k(float* __restrict__ out)
{
  __shared__ float red[256];
  const int n = blockIdx.x, tid = threadIdx.x;
  float* row = out + (size_t)n * 1024;
  float v[4];
  float mx = -1e30f;
#pragma unroll
  for (int l = 0; l < 4; ++l) { v[l] = row[tid + 256 * l]; mx = fmaxf(mx, v[l]); }
  red[tid] = mx; __syncthreads();
  for (int s = 128; s > 0; s >>= 1) { if (tid < s) red[tid] = fmaxf(red[tid], red[tid + s]); __syncthreads(); }
  float m = red[0]; __syncthreads();
  float se = 0.f;
#pragma unroll
  for (int l = 0; l < 4; ++l) se += expf(v[l] - m);
  red[tid] = se; __syncthreads();
  for (int s = 128; s > 0; s >>= 1) { if (tid < s) red[tid] += red[tid + s]; __syncthreads(); }
  float L = m + logf(red[0]);
#pragma unroll
  for (int l = 0; l < 4; ++l) row[tid + 256 * l] = v[l] - L;
}

extern "C" void kernel_launch(void* const* d_in, const int* in_sizes, int n_in,
                              void* d_out, int out_size, void* d_ws, size_t ws_size,
                              hipStream_t stream)
{
  (void)in_sizes; (void)n_in; (void)out_size; (void)ws_size;
  const float* xn_in = (const float*)d_in[0];
  const float* xe_in = (const float*)d_in[1];
  const int*   iI    = (const int*)d_in[2];
  const int*   jJ    = (const int*)d_in[3];
  const float* K1N   = (const float*)d_in[4];
  const float* K2N   = (const float*)d_in[5];
  const float* K1E   = (const float*)d_in[6];
  const float* K2E   = (const float*)d_in[7];
  const float* KNc   = (const float*)d_in[8];
  const float* KE1   = (const float*)d_in[9];
  const float* KE2   = (const float*)d_in[10];
  const float* KN1   = (const float*)d_in[11];
  const float* KN2   = (const float*)d_in[12];
  const float* W1    = (const float*)d_in[13];
  const float* b1    = (const float*)d_in[14];
  const float* W2    = (const float*)d_in[15];
  const float* b2    = (const float*)d_in[16];
  float* out = (float*)d_out;

  float* ws = (float*)d_ws;
  size_t off = 0;
  auto alloc = [&](size_t n) { size_t o = off; off += (n + 63) & ~(size_t)63; return o; };
  float* xnN   = ws + alloc((size_t)NNODES * CH);                  // f32 node-major master
  __bf16* xeT  = (__bf16*)(ws + alloc((size_t)NEDGES * CH / 2));   // bf16 edge state
  __bf16* xeT64= (__bf16*)(ws + alloc((size_t)NEDGES * 64 / 2));   // opening input
  float* sbufh = ws + alloc(2 * NNODES);                           // sqnorm halves
  float* wbuf  = ws + alloc(NEDGES);
  __bf16* UVb  = (__bf16*)(ws + alloc((size_t)NNODES * 256 / 2));
  __bf16* xnNb = (__bf16*)(ws + alloc((size_t)NNODES * CH / 2));
  __bf16* catb = (__bf16*)(ws + alloc((size_t)NNODES * 256 / 2));
  __bf16* nAb  = (__bf16*)(ws + alloc((size_t)NNODES * CH / 2));
  __bf16* zb   = (__bf16*)(ws + alloc((size_t)NNODES * CH / 2));
  __bf16* l1bb = (__bf16*)(ws + alloc((size_t)NNODES * 256 / 2));
  __bf16* K1Eb = (__bf16*)(ws + alloc(8192 / 2));
  __bf16* K2Eb = (__bf16*)(ws + alloc(16384 / 2));
  __bf16* KE1b = (__bf16*)(ws + alloc(65536 / 2));
  __bf16* KE2b = (__bf16*)(ws + alloc(65536 / 2));
  __bf16* KNcb = (__bf16*)(ws + alloc(16384 / 2));
  __bf16* W1b  = (__bf16*)(ws + alloc(32768 / 2));
  __bf16* W2b  = (__bf16*)(ws + alloc(262144 / 2));
  __bf16* KN1b = (__bf16*)(ws + alloc(196608 / 2));
  __bf16* KN2b = (__bf16*)(ws + alloc(65536 / 2));
  __bf16* a1a2b= (__bf16*)(ws + alloc(131072 / 2));
  __bf16* K1Nb = (__bf16*)(ws + alloc(8192 / 2));
  __bf16* K2Nb = (__bf16*)(ws + alloc(16384 / 2));
  int* csr_cnt    = (int*)(ws + alloc(4096));
  int* csr_offs   = (int*)(ws + alloc(4160));
  int* csr_cursor = (int*)(ws + alloc(4096));
  int* csr_list   = (int*)(ws + alloc(2 * NEDGES));
  float2* pA = (float2*)(ws + alloc((size_t)4096 * 2));
  float2* pB = (float2*)(ws + alloc((size_t)4096 * 2));
  float2* pC = (float2*)(ws + alloc((size_t)4096 * 2));
  // alias: opening node transposed input (512 KB) in UVb (2 MB, first written layer 0)
  __bf16* xnT64b = UVb;

  const __bf16* BNUL = nullptr;
  const float* NUL = nullptr;
  const float2* PNUL = nullptr;
  __bf16* BNULm = nullptr;
  float* NULm = nullptr;

  // ---- weight conversion + CSR build (once) ----
  wcvt_k<<<3456, 256, 0, stream>>>(K1E, K2E, KE1, KE2, KNc, W1, W2, KN1, KN2, K1N, K2N,
                                   K1Eb, K2Eb, KE1b, KE2b, KNcb, W1b, W2b, KN1b, KN2b,
                                   a1a2b, K1Nb, K2Nb);
  hipMemsetAsync(csr_cnt, 0, 4096 * sizeof(int), stream);
  hist_k<<<NEDGES / 256, 256, 0, stream>>>(iI, jJ, csr_cnt);
  scan_k<<<1, 1024, 0, stream>>>(csr_cnt, csr_offs, csr_cursor);
  fill_k<<<NEDGES / 256, 256, 0, stream>>>(iI, jJ, csr_cursor, csr_list);

  // ---- opening: node double layer (MFMA, node-major, emits xnNb + sqnorm) ----
  etrans_k<<<NNODES / 64, 256, 0, stream>>>(xn_in, xnT64b, NNODES);
  nmfma_k<64, false, false, true, 0, false><<<dim3(64, 2), 256, 0, stream>>>(
      K1Nb, xnT64b, BNUL, nAb, nullptr, nullptr, NUL, 128, pA, PNUL, 0, 0.0, BNULm, NULm);
  nmfma_k<128, false, true, false, 3, true><<<dim3(64, 2), 256, 0, stream>>>(
      K2Nb, nAb, BNUL, nullptr, xnN, nullptr, NUL, 128, nullptr,
      pA, 128, (double)CH * NNODES, xnNb, sbufh);

  // ---- opening: fused edge double layer (cooperative) ----
  etrans_k<<<NEDGES / 64, 256, 0, stream>>>(xe_in, xeT64, NEDGES);
  {
    const __bf16* a0 = K1Eb; const __bf16* a1 = K2Eb;
    const __bf16* a2 = xeT64; __bf16* a3 = xeT; float2* a4 = pB;
    void* args[] = {&a0, &a1, &a2, &a3, &a4};
    hipLaunchCooperativeKernel((const void*)oedge_k, dim3(NEDGES / 64), dim3(256),
                               args, 0, stream);
  }

  for (int i = 0; i < 4; ++i) {
    const __bf16* KE1bi = KE1b + (size_t)i * 128 * 128;
    const __bf16* KE2bi = KE2b + (size_t)i * 128 * 128;
    const __bf16* KN1bi = KN1b + (size_t)i * 128 * 384;
    const __bf16* KN2bi = KN2b + (size_t)i * 128 * 128;
    const __bf16* a1a2i = a1a2b + (size_t)i * 256 * 128;

    // D statistics -> pA
    dstat_k<<<2080, 256, 0, stream>>>(xnNb, sbufh, pA);

    // UVb[n][256] = xnNb @ a1a2^T (bf16 out)
    nmfma_k<128, false, false, false, 0, false><<<dim3(64, 4), 256, 0, stream>>>(
        a1a2i, xnNb, BNUL, UVb, nullptr, nullptr, NUL, 256, nullptr, PNUL, 0, 0.0, BNULm, NULm);

    // fused edge pipeline (cooperative): w + pass1 + pass2 + lnres
    {
      const __bf16* f0 = KE1bi; const __bf16* f1 = KE2bi;
      __bf16* f2 = xeT; const __bf16* f3 = UVb; const __bf16* f4 = xnNb;
      const float* f5 = sbufh; const int* f6 = iI; const int* f7 = jJ;
      float* f8 = wbuf; const float2* f9 = pA; float2* f10 = pB; float2* f11 = pC;
      void* args[] = {&f0, &f1, &f2, &f3, &f4, &f5, &f6, &f7, &f8, &f9, &f10, &f11};
      hipLaunchCooperativeKernel((const void*)fedge_k, dim3(NEDGES / 64), dim3(256),
                                 args, 0, stream);
    }

    // node update: gather -> catb; KN1 (split cat+xn) stats -> pB; KN2 tanh + resid + emit
    gather_k<<<NNODES / 4, 512, 0, stream>>>(xeT, wbuf, csr_offs, csr_list, catb);
    nmfma_k<384, true, false, true, 0, false><<<dim3(64, 2), 256, 0, stream>>>(
        KN1bi, catb, xnNb, nAb, nullptr, nullptr, NUL, 128, pB, PNUL, 0, 0.0, BNULm, NULm);
    nmfma_k<128, false, true, false, 4, true><<<dim3(64, 2), 256, 0, stream>>>(
        KN2bi, nAb, BNUL, nullptr, nullptr, xnN, NUL, 128, nullptr,
        pB, 128, (double)CH * NNODES, xnNb, sbufh);
  }

  // ---- close + MLP head (bf16 MFMA, node-major) ----
  nmfma_k<128, false, false, false, 0, false><<<dim3(64, 2), 256, 0, stream>>>(
      KNcb, xnNb, BNUL, zb, nullptr, nullptr, NUL, 128, nullptr, PNUL, 0, 0.0, BNULm, NULm);
  nmfma_k<128, false, false, false, 1, false><<<dim3(64, 4), 256, 0, stream>>>(
      W1b, zb, BNUL, l1bb, nullptr, nullptr, b1, 256, nullptr, PNUL, 0, 0.0, BNULm, NULm);
  nmfma_k<256, false, false, false, 2, false><<<dim3(64, 16), 256, 0, stream>>>(
      W2b, l1bb, BNUL, nullptr, out, nullptr, b2, 1024, nullptr, PNUL, 0, 0.0, BNULm, NULm);
  logsoftmax_k<<<NNODES, 256, 0, stream>>>(out);
}

// Round 9
// 787.160 us; speedup vs baseline: 1.9497x; 1.9497x over previous
//
#include <hip/hip_runtime.h>

#define NNODES 4096
#define NEDGES 65536
#define CH 128

typedef __bf16 bf16x8_t __attribute__((ext_vector_type(8)));
typedef __bf16 bf16x4_t __attribute__((ext_vector_type(4)));
typedef __bf16 bf16x2_t __attribute__((ext_vector_type(2)));
typedef float f32x4_t __attribute__((ext_vector_type(4)));

// ---- fast tanh via hw exp2/rcp ----
__device__ __forceinline__ float fast_tanh(float x)
{
  float t = __builtin_amdgcn_exp2f(x * 2.885390081777927f);   // 2*log2(e)
  return 1.f - 2.f * __builtin_amdgcn_rcpf(t + 1.f);
}

// ---- block stats writer: f32 wave shfl-reduce, one float2 per block ----
__device__ __forceinline__ void write_stats(float s, float q, float2* __restrict__ partials,
                                            int pid, int tid, int nwaves)
{
#pragma unroll
  for (int d = 1; d < 64; d <<= 1) { s += __shfl_xor(s, d); q += __shfl_xor(q, d); }
  __shared__ float rs[8][2];
  const int wv = tid >> 6, lane = tid & 63;
  if (lane == 0) { rs[wv][0] = s; rs[wv][1] = q; }
  __syncthreads();
  if (tid == 0) {
    float S = 0.f, Q = 0.f;
    for (int i = 0; i < nwaves; ++i) { S += rs[i][0]; Q += rs[i][1]; }
    partials[pid] = {S, Q};
  }
}

// ---- inline params: f64 cross-block reduce of f32 partials -> (mean,rstd) or (factor,0) ----
__device__ __forceinline__ float2 params_inline(const float2* __restrict__ pp,
                                                int nblk, double M, int type)
{
  const int tid = threadIdx.x;
  double s = 0.0, q = 0.0;
  for (int i = tid; i < nblk; i += 256) { float2 v = pp[i]; s += (double)v.x; q += (double)v.y; }
#pragma unroll
  for (int d = 1; d < 64; d <<= 1) { s += __shfl_xor(s, d); q += __shfl_xor(q, d); }
  __shared__ double rs4[4], rq4[4];
  __shared__ float pr[2];
  const int wv = tid >> 6, lane = tid & 63;
  if (lane == 0) { rs4[wv] = s; rq4[wv] = q; }
  __syncthreads();
  if (tid == 0) {
    double S = rs4[0] + rs4[1] + rs4[2] + rs4[3];
    double Q = rq4[0] + rq4[1] + rq4[2] + rq4[3];
    if (type == 0) {
      double mean = S / M;
      double var = Q / M - mean * mean;
      if (var < 0.0) var = 0.0;
      pr[0] = (float)mean;
      pr[1] = (float)(1.0 / sqrt(var + 1e-5));
    } else {
      double var = (Q - S * S / M) / (M - 1.0);
      if (var < 1e-30) var = 1e-30;
      pr[0] = (float)(-2.0 / sqrt(var));
      pr[1] = 0.f;
    }
  }
  __syncthreads();
  return {pr[0], pr[1]};
}

// ================= bf16 MFMA edge GEMM (ob-split, OBS outs/block) =================
// grid (E/64, 8/OBS). EM 0: plain, stats   EM 2: + w*(U[I]+V[J]), stats (WPH computes w inline)
// EM 1: tanh-on-load, stats   EM 3: tanh-on-load, no stats
template<int EM, int K, int OBS, bool WPH>
__global__ __launch_bounds__(256) void emfma_k(
    const __bf16* __restrict__ A, const __bf16* __restrict__ X,
    __bf16* __restrict__ Cb,
    float2* __restrict__ partials,
    const __bf16* __restrict__ UVb, const __bf16* __restrict__ xnNb,
    const float* __restrict__ sbufh,
    const int* __restrict__ iI, const int* __restrict__ jJ,
    float* __restrict__ wbuf, const float2* __restrict__ pD,
    const float2* __restrict__ pp, int pnblk, double pM)
{
  __shared__ float wl[64];
  float p0 = 0.f, p1 = 0.f;
  if constexpr (EM == 1 || EM == 3) {
    float2 pr = params_inline(pp, pnblk, pM, 0); p0 = pr.x; p1 = pr.y;
  }
  const int tid = threadIdx.x;
  const int wv = tid >> 6, lane = tid & 63;
  const int l15 = lane & 15, ks = lane >> 4;
  const int row = wv * 16 + l15;
  const int e = blockIdx.x * 64 + row;
  if constexpr (WPH) {
    float2 fp = params_inline(pD, 2080, (double)NNODES * (double)NNODES, 1);
    const int eg = blockIdx.x * 64 + (tid >> 2);
    const int a = iI[eg], b = jJ[eg];
    const bf16x8_t* pa = (const bf16x8_t*)(xnNb + (size_t)a * CH + (tid & 3) * 32);
    const bf16x8_t* pb = (const bf16x8_t*)(xnNb + (size_t)b * CH + (tid & 3) * 32);
    float g = 0.f;
#pragma unroll
    for (int q = 0; q < 4; ++q) {
      bf16x8_t u = pa[q], v = pb[q];
#pragma unroll
      for (int j = 0; j < 8; ++j) g = fmaf((float)u[j], (float)v[j], g);
    }
    g += __shfl_xor(g, 1); g += __shfl_xor(g, 2);
    float d = sbufh[a] + sbufh[NNODES + a] + sbufh[b] + sbufh[NNODES + b] - 2.f * g;
    d = d > 0.f ? d : 0.f;
    float wgt = __builtin_amdgcn_exp2f(fp.x * d * 1.4426950408889634f);
    if ((tid & 3) == 0) {
      wl[tid >> 2] = wgt;
      if (blockIdx.y == 0) wbuf[eg] = wgt;
    }
    __syncthreads();
  }
  constexpr int KK = K / 32;
  bf16x8_t bq[KK];
  {
    const __bf16* xr = X + (size_t)e * K + ks * 8;
#pragma unroll
    for (int kk = 0; kk < KK; ++kk) {
      bf16x8_t v = *(const bf16x8_t*)(xr + kk * 32);
      if constexpr (EM == 1 || EM == 3) {
#pragma unroll
        for (int j = 0; j < 8; ++j) v[j] = (__bf16)fast_tanh(((float)v[j] - p0) * p1);
      }
      bq[kk] = v;
    }
  }
  float we = 0.f; int ie = 0, je = 0;
  if constexpr (EM == 2) { we = wl[row]; ie = iI[e]; je = jJ[e]; }
  float dsum = 0.f, dsq = 0.f;
  const int ob0 = blockIdx.y * OBS;
#pragma unroll
  for (int obb = 0; obb < OBS; ++obb) {
    const int ob = ob0 + obb;
    f32x4_t acc = {0.f, 0.f, 0.f, 0.f};
    const __bf16* ar = A + (size_t)(ob * 16 + l15) * K + ks * 8;
#pragma unroll
    for (int kk = 0; kk < KK; ++kk) {
      bf16x8_t a = *(const bf16x8_t*)(ar + kk * 32);
      acc = __builtin_amdgcn_mfma_f32_16x16x32_bf16(a, bq[kk], acc, 0, 0, 0);
    }
    const int ro = ob * 16 + ks * 4;
    float v0 = acc[0], v1 = acc[1], v2 = acc[2], v3 = acc[3];
    if constexpr (EM == 2) {
      bf16x4_t u4 = *(const bf16x4_t*)&UVb[(size_t)ie * 256 + ro];
      bf16x4_t w4 = *(const bf16x4_t*)&UVb[(size_t)je * 256 + 128 + ro];
      v0 += we * ((float)u4[0] + (float)w4[0]);
      v1 += we * ((float)u4[1] + (float)w4[1]);
      v2 += we * ((float)u4[2] + (float)w4[2]);
      v3 += we * ((float)u4[3] + (float)w4[3]);
    }
    if constexpr (EM != 3) {
      dsum += v0 + v1 + v2 + v3;
      dsq  += v0 * v0 + v1 * v1 + v2 * v2 + v3 * v3;
    }
    bf16x4_t bv;
    bv[0] = (__bf16)v0; bv[1] = (__bf16)v1; bv[2] = (__bf16)v2; bv[3] = (__bf16)v3;
    *(bf16x4_t*)(Cb + (size_t)e * 128 + ro) = bv;
  }
  if constexpr (EM != 3)
    write_stats(dsum, dsq, partials, blockIdx.y * gridDim.x + blockIdx.x, tid, 4);
}

// ================= bf16 MFMA node GEMM, col-tiled, OBS outs/block =================
// OM 0: bf16 out; 1: +bias elu bf16 out; 2: +bias f32 out; 3: f32 out; 4: resid[n][128] += 0.1*v
template<int K, bool XSPLIT, bool XT, bool STATS, int OM, bool EMITB, int OBS>
__global__ __launch_bounds__(256) void nmfma_k(
    const __bf16* __restrict__ A, const __bf16* __restrict__ X,
    const __bf16* __restrict__ X2,
    __bf16* __restrict__ Cb, float* __restrict__ Cf, float* __restrict__ resid,
    const float* __restrict__ bias, int nout_stride,
    float2* __restrict__ partials,
    const float2* __restrict__ pp, int pnblk, double pM,
    __bf16* __restrict__ xbout, float* __restrict__ shout)
{
  float p0 = 0.f, p1 = 0.f;
  if constexpr (XT) { float2 pr = params_inline(pp, pnblk, pM, 0); p0 = pr.x; p1 = pr.y; }
  const int tid = threadIdx.x;
  const int wv = tid >> 6, lane = tid & 63;
  const int l15 = lane & 15, ks = lane >> 4;
  const int n = blockIdx.x * 64 + wv * 16 + l15;
  constexpr int KK = K / 32;
  bf16x8_t bq[KK];
  if constexpr (XSPLIT) {
    const __bf16* xr  = X  + (size_t)n * 256 + ks * 8;
    const __bf16* xr2 = X2 + (size_t)n * 128 + ks * 8;
#pragma unroll
    for (int kk = 0; kk < 8; ++kk) bq[kk] = *(const bf16x8_t*)(xr + kk * 32);
#pragma unroll
    for (int kk = 8; kk < KK; ++kk) bq[kk] = *(const bf16x8_t*)(xr2 + (kk - 8) * 32);
  } else {
    const __bf16* xr = X + (size_t)n * K + ks * 8;
#pragma unroll
    for (int kk = 0; kk < KK; ++kk) {
      bf16x8_t v = *(const bf16x8_t*)(xr + kk * 32);
      if constexpr (XT) {
#pragma unroll
        for (int j = 0; j < 8; ++j) v[j] = (__bf16)fast_tanh(((float)v[j] - p0) * p1);
      }
      bq[kk] = v;
    }
  }
  float dsum = 0.f, dsq = 0.f, ss = 0.f;
  const int ob0 = blockIdx.y * OBS;
#pragma unroll
  for (int obb = 0; obb < OBS; ++obb) {
    const int ob = ob0 + obb;
    f32x4_t acc = {0.f, 0.f, 0.f, 0.f};
    const __bf16* ar = A + (size_t)(ob * 16 + l15) * K + ks * 8;
#pragma unroll
    for (int kk = 0; kk < KK; ++kk) {
      bf16x8_t a = *(const bf16x8_t*)(ar + kk * 32);
      acc = __builtin_amdgcn_mfma_f32_16x16x32_bf16(a, bq[kk], acc, 0, 0, 0);
    }
    const int ro = ob * 16 + ks * 4;
    float v[4] = {acc[0], acc[1], acc[2], acc[3]};
    if constexpr (OM == 1 || OM == 2) {
#pragma unroll
      for (int r = 0; r < 4; ++r) v[r] += bias[ro + r];
    }
    if constexpr (OM == 1) {
#pragma unroll
      for (int r = 0; r < 4; ++r) v[r] = v[r] > 0.f ? v[r] : expm1f(v[r]);
    }
    if constexpr (STATS) {
#pragma unroll
      for (int r = 0; r < 4; ++r) { dsum += v[r]; dsq += v[r] * v[r]; }
    }
    if constexpr (OM == 4) {
      float4* rp = (float4*)&resid[(size_t)n * 128 + ro];
      float4 rr = *rp;
      rr.x += 0.1f * v[0]; rr.y += 0.1f * v[1]; rr.z += 0.1f * v[2]; rr.w += 0.1f * v[3];
      *rp = rr;
      if constexpr (EMITB) {
        bf16x4_t eb;
        eb[0] = (__bf16)rr.x; eb[1] = (__bf16)rr.y; eb[2] = (__bf16)rr.z; eb[3] = (__bf16)rr.w;
        *(bf16x4_t*)(xbout + (size_t)n * 128 + ro) = eb;
#pragma unroll
        for (int r = 0; r < 4; ++r) { float f = (float)eb[r]; ss += f * f; }
      }
    } else if constexpr (OM == 2 || OM == 3) {
      float4 fv = {v[0], v[1], v[2], v[3]};
      *(float4*)(Cf + (size_t)n * nout_stride + ro) = fv;
      if constexpr (EMITB) {
        bf16x4_t eb;
        eb[0] = (__bf16)v[0]; eb[1] = (__bf16)v[1]; eb[2] = (__bf16)v[2]; eb[3] = (__bf16)v[3];
        *(bf16x4_t*)(xbout + (size_t)n * 128 + ro) = eb;
#pragma unroll
        for (int r = 0; r < 4; ++r) { float f = (float)eb[r]; ss += f * f; }
      }
    } else {
      bf16x4_t bv;
      bv[0] = (__bf16)v[0]; bv[1] = (__bf16)v[1]; bv[2] = (__bf16)v[2]; bv[3] = (__bf16)v[3];
      *(bf16x4_t*)(Cb + (size_t)n * nout_stride + ro) = bv;
    }
  }
  if constexpr (EMITB) {
    ss += __shfl_xor(ss, 16);
    ss += __shfl_xor(ss, 32);
    if (lane < 16) shout[blockIdx.y * NNODES + n] = ss;
  }
  if constexpr (STATS)
    write_stats(dsum, dsq, partials, blockIdx.y * gridDim.x + blockIdx.x, tid, 4);
}

// ================= dstat via MFMA Gram matrix, triangular 1-D grid (2080 blocks) =================
__global__ __launch_bounds__(256) void dstat_k(
    const __bf16* __restrict__ fT, const float* __restrict__ sh,
    float2* __restrict__ partials)
{
  int rem = blockIdx.x, i0t = 0;
  while (rem >= 64 - i0t) { rem -= 64 - i0t; ++i0t; }
  const int i0 = i0t * 64, j0 = (i0t + rem) * 64;
  const float wgt = (j0 > i0) ? 2.f : 1.f;
  const int tid = threadIdx.x;
  const int wv = tid >> 6, lane = tid & 63, l15 = lane & 15, ks = lane >> 4;
  const int irow = i0 + wv * 16 + l15;
  bf16x8_t aq[4];
  const __bf16* ar = fT + (size_t)irow * 128 + ks * 8;
#pragma unroll
  for (int kk = 0; kk < 4; ++kk) aq[kk] = *(const bf16x8_t*)(ar + kk * 32);
  float si[4];
#pragma unroll
  for (int r = 0; r < 4; ++r) {
    int ii = i0 + wv * 16 + ks * 4 + r;
    si[r] = sh[ii] + sh[NNODES + ii];
  }
  float dsum = 0.f, dsq = 0.f;
#pragma unroll
  for (int jb = 0; jb < 4; ++jb) {
    const int jcol = j0 + jb * 16 + l15;
    const __bf16* br = fT + (size_t)jcol * 128 + ks * 8;
    f32x4_t acc = {0.f, 0.f, 0.f, 0.f};
#pragma unroll
    for (int kk = 0; kk < 4; ++kk) {
      bf16x8_t b = *(const bf16x8_t*)(br + kk * 32);
      acc = __builtin_amdgcn_mfma_f32_16x16x32_bf16(aq[kk], b, acc, 0, 0, 0);
    }
    const float sj = sh[jcol] + sh[NNODES + jcol];
#pragma unroll
    for (int r = 0; r < 4; ++r) {
      float d = si[r] + sj - 2.f * acc[r];
      d = d > 0.f ? d : 0.f;
      dsum += d; dsq += d * d;
    }
  }
  write_stats(dsum * wgt, dsq * wgt, partials, blockIdx.x, tid, 4);
}

// ================= transpose src [64][ncols] f32 -> dst [ncols][64] bf16 =================
__global__ __launch_bounds__(256) void etrans_k(const float* __restrict__ src,
                                                __bf16* __restrict__ dst, int ncols)
{
  __shared__ float t[64][65];
  const int e0 = blockIdx.x * 64;
  const int tx = threadIdx.x & 63, tw = threadIdx.x >> 6;
  for (int c = tw; c < 64; c += 4)
    t[tx][c] = src[(size_t)c * ncols + e0 + tx];
  __syncthreads();
  const int el = threadIdx.x >> 2, c0 = (threadIdx.x & 3) * 16;
  for (int q = 0; q < 4; ++q) {
    int c = c0 + q * 4;
    bf16x4_t b;
    b[0] = (__bf16)t[el][c];     b[1] = (__bf16)t[el][c + 1];
    b[2] = (__bf16)t[el][c + 2]; b[3] = (__bf16)t[el][c + 3];
    *(bf16x4_t*)&dst[(size_t)(e0 + el) * 64 + c] = b;
  }
}

// ================= weight conversion to bf16 (one launch) =================
__global__ void wcvt_k(const float* __restrict__ K1E, const float* __restrict__ K2E,
                       const float* __restrict__ KE1, const float* __restrict__ KE2,
                       const float* __restrict__ KNc, const float* __restrict__ W1,
                       const float* __restrict__ W2, const float* __restrict__ KN1,
                       const float* __restrict__ KN2, const float* __restrict__ K1N,
                       const float* __restrict__ K2N,
                       __bf16* __restrict__ K1Eb, __bf16* __restrict__ K2Eb,
                       __bf16* __restrict__ KE1b, __bf16* __restrict__ KE2b,
                       __bf16* __restrict__ KNcb, __bf16* __restrict__ W1b,
                       __bf16* __restrict__ W2b, __bf16* __restrict__ KN1b,
                       __bf16* __restrict__ KN2b, __bf16* __restrict__ a1a2b,
                       __bf16* __restrict__ K1Nb, __bf16* __restrict__ K2Nb)
{
  int id = blockIdx.x * 256 + threadIdx.x;
  if (id < 8192) { K1Eb[id] = (__bf16)K1E[id]; return; }
  id -= 8192;
  if (id < 16384) { K2Eb[id] = (__bf16)K2E[id]; return; }
  id -= 16384;
  if (id < 65536) {
    int l = id >> 14, rem = id & 16383, r = rem >> 7, c = rem & 127;
    KE1b[id] = (__bf16)KE1[(size_t)l * 49152 + r * 384 + 128 + c];
    return;
  }
  id -= 65536;
  if (id < 65536) { KE2b[id] = (__bf16)KE2[id]; return; }
  id -= 65536;
  if (id < 16384) { KNcb[id] = (__bf16)KNc[id]; return; }
  id -= 16384;
  if (id < 32768) { W1b[id] = (__bf16)W1[id]; return; }
  id -= 32768;
  if (id < 262144) { W2b[id] = (__bf16)W2[id]; return; }
  id -= 262144;
  if (id < 196608) { KN1b[id] = (__bf16)KN1[id]; return; }
  id -= 196608;
  if (id < 65536) { KN2b[id] = (__bf16)KN2[id]; return; }
  id -= 65536;
  if (id < 131072) {
    int l = id >> 15, rem = id & 32767, r = rem >> 7, c = rem & 127;
    int o = r & 127;
    float k1 = KE1[(size_t)l * 49152 + o * 384 + c];
    float k3 = KE1[(size_t)l * 49152 + o * 384 + 256 + c];
    a1a2b[id] = (__bf16)((r < 128) ? (0.5f * k1 + k3) : (0.5f * k1 - k3));
    return;
  }
  id -= 131072;
  if (id < 8192) { K1Nb[id] = (__bf16)K1N[id]; return; }
  id -= 8192;
  if (id < 16384) { K2Nb[id] = (__bf16)K2N[id]; return; }
}

// ================= lnres: xeT = bf16(f32(xeT) + 0.1*ln(eB)) =================
__global__ __launch_bounds__(256) void lnres_k(
    const __bf16* __restrict__ eBT, __bf16* __restrict__ xeT,
    const float2* __restrict__ pp, int pnblk)
{
  float2 pr = params_inline(pp, pnblk, (double)CH * NEDGES, 0);
  const float m = pr.x, r = pr.y;
  const size_t base = (size_t)blockIdx.x * (256 * 16);
  for (int it = 0; it < 2; ++it) {
    size_t i = base + (size_t)it * 2048 + (size_t)threadIdx.x * 8;
    bf16x8_t b = *(const bf16x8_t*)(eBT + i);
    bf16x8_t x = *(const bf16x8_t*)(xeT + i);
    bf16x8_t ob;
#pragma unroll
    for (int j = 0; j < 8; ++j)
      ob[j] = (__bf16)((float)x[j] + 0.1f * (((float)b[j] - m) * r));
    *(bf16x8_t*)(xeT + i) = ob;
  }
}

// ================= CSR build =================
__global__ void hist_k(const int* __restrict__ iI, const int* __restrict__ jJ,
                       int* __restrict__ cnt)
{
  int e = blockIdx.x * 256 + threadIdx.x;
  atomicAdd(&cnt[iI[e]], 1);
  atomicAdd(&cnt[jJ[e]], 1);
}

__global__ __launch_bounds__(1024) void scan_k(const int* __restrict__ cnt,
                                               int* __restrict__ offs,
                                               int* __restrict__ cursor)
{
  __shared__ int tmp[1024];
  const int tid = threadIdx.x;
  int4 v = *(const int4*)&cnt[tid * 4];
  int s = v.x + v.y + v.z + v.w;
  tmp[tid] = s; __syncthreads();
  for (int d = 1; d < 1024; d <<= 1) {
    int t = (tid >= d) ? tmp[tid - d] : 0;
    __syncthreads();
    tmp[tid] += t;
    __syncthreads();
  }
  int base = tmp[tid] - s;
  int4 o = {base, base + v.x, base + v.x + v.y, base + v.x + v.y + v.z};
  *(int4*)&offs[tid * 4] = o;
  *(int4*)&cursor[tid * 4] = o;
  if (tid == 1023) offs[4096] = tmp[1023];
}

__global__ void fill_k(const int* __restrict__ iI, const int* __restrict__ jJ,
                       int* __restrict__ cursor, int* __restrict__ list)
{
  int e = blockIdx.x * 256 + threadIdx.x;
  int p1 = atomicAdd(&cursor[iI[e]], 1);
  list[p1] = e;
  int p2 = atomicAdd(&cursor[jJ[e]], 1);
  list[p2] = e | 0x80000000;
}

// ================= gather: 8 waves, 2 per node (incidence-split) -> catb bf16 [n][256] =================
__global__ __launch_bounds__(512) void gather_k(
    const __bf16* __restrict__ xeT, const float* __restrict__ w,
    const int* __restrict__ offs, const int* __restrict__ list,
    __bf16* __restrict__ catb)
{
  __shared__ float comb[4][4][64];
  const int wv = threadIdx.x >> 6, lane = threadIdx.x & 63;
  const int nn = wv >> 1, half = wv & 1;
  const int n = blockIdx.x * 4 + nn;
  const int k0 = offs[n], k1 = offs[n + 1];
  float s1a = 0.f, s1b = 0.f, s2a = 0.f, s2b = 0.f;
#pragma unroll 2
  for (int k = k0 + half; k < k1; k += 2) {
    int enc = list[k];
    int e = enc & 0x7fffffff;
    float we = w[e];
    bf16x2_t xv = *(const bf16x2_t*)&xeT[(size_t)e * 128 + lane * 2];
    float va = (float)xv[0] * we;
    float vb = (float)xv[1] * we;
    if (enc >= 0) { s1a += va; s1b += vb; }
    else          { s2a += va; s2b += vb; }
  }
  if (half == 1) {
    comb[nn][0][lane] = s1a; comb[nn][1][lane] = s1b;
    comb[nn][2][lane] = s2a; comb[nn][3][lane] = s2b;
  }
  __syncthreads();
  if (half == 0) {
    s1a += comb[nn][0][lane]; s1b += comb[nn][1][lane];
    s2a += comb[nn][2][lane]; s2b += comb[nn][3][lane];
    __bf16* row = catb + (size_t)n * 256;
    bf16x2_t av, dv;
    av[0] = (__bf16)(0.5f * (s1a + s2a)); av[1] = (__bf16)(0.5f * (s1b + s2b));
    dv[0] = (__bf16)(s1a - s2a);          dv[1] = (__bf16)(s1b - s2b);
    *(bf16x2_t*)&row[lane * 2] = av;
    *(bf16x2_t*)&row[128 + lane * 2] = dv;
  }
}

// ================= log_softmax rows of [N][1024] =================
__global__ __launch_bounds__(256) void logsoftmax_k(float* __restrict__ out)
{
  __shared__ float red[256];
  const int n = blockIdx.x, tid = threadIdx.x;
  float* row = out + (size_t)n * 1024;
  float v[4];
  float mx = -1e30f;
#pragma unroll
  for (int l = 0; l < 4; ++l) { v[l] = row[tid + 256 * l]; mx = fmaxf(mx, v[l]); }
  red[tid] = mx; __syncthreads();
  for (int s = 128; s > 0; s >>= 1) { if (tid < s) red[tid] = fmaxf(red[tid], red[tid + s]); __syncthreads(); }
  float m = red[0]; __syncthreads();
  float se = 0.f;
#pragma unroll
  for (int l = 0; l < 4; ++l) se += expf(v[l] - m);
  red[tid] = se; __syncthreads();
  for (int s = 128; s > 0; s >>= 1) { if (tid < s) red[tid] += red[tid + s]; __syncthreads(); }
  float L = m + logf(red[0]);
#pragma unroll
  for (int l = 0; l < 4; ++l) row[tid + 256 * l] = v[l] - L;
}

extern "C" void kernel_launch(void* const* d_in, const int* in_sizes, int n_in,
                              void* d_out, int out_size, void* d_ws, size_t ws_size,
                              hipStream_t stream)
{
  (void)in_sizes; (void)n_in; (void)out_size; (void)ws_size;
  const float* xn_in = (const float*)d_in[0];
  const float* xe_in = (const float*)d_in[1];
  const int*   iI    = (const int*)d_in[2];
  const int*   jJ    = (const int*)d_in[3];
  const float* K1N   = (const float*)d_in[4];
  const float* K2N   = (const float*)d_in[5];
  const float* K1E   = (const float*)d_in[6];
  const float* K2E   = (const float*)d_in[7];
  const float* KNc   = (const float*)d_in[8];
  const float* KE1   = (const float*)d_in[9];
  const float* KE2   = (const float*)d_in[10];
  const float* KN1   = (const float*)d_in[11];
  const float* KN2   = (const float*)d_in[12];
  const float* W1    = (const float*)d_in[13];
  const float* b1    = (const float*)d_in[14];
  const float* W2    = (const float*)d_in[15];
  const float* b2    = (const float*)d_in[16];
  float* out = (float*)d_out;

  float* ws = (float*)d_ws;
  size_t off = 0;
  auto alloc = [&](size_t n) { size_t o = off; off += (n + 63) & ~(size_t)63; return o; };
  float* xnN   = ws + alloc((size_t)NNODES * CH);                  // f32 node-major master
  __bf16* xeT  = (__bf16*)(ws + alloc((size_t)NEDGES * CH / 2));   // bf16 edge state
  __bf16* eAT  = (__bf16*)(ws + alloc((size_t)NEDGES * CH / 2));
  __bf16* eBT  = (__bf16*)(ws + alloc((size_t)NEDGES * CH / 2));
  float* sbufh = ws + alloc(2 * NNODES);                           // sqnorm halves
  float* wbuf  = ws + alloc(NEDGES);
  __bf16* UVb  = (__bf16*)(ws + alloc((size_t)NNODES * 256 / 2));
  __bf16* xnNb = (__bf16*)(ws + alloc((size_t)NNODES * CH / 2));
  __bf16* catb = (__bf16*)(ws + alloc((size_t)NNODES * 256 / 2));
  __bf16* nAb  = (__bf16*)(ws + alloc((size_t)NNODES * CH / 2));
  __bf16* zb   = (__bf16*)(ws + alloc((size_t)NNODES * CH / 2));
  __bf16* l1bb = (__bf16*)(ws + alloc((size_t)NNODES * 256 / 2));
  __bf16* K1Eb = (__bf16*)(ws + alloc(8192 / 2));
  __bf16* K2Eb = (__bf16*)(ws + alloc(16384 / 2));
  __bf16* KE1b = (__bf16*)(ws + alloc(65536 / 2));
  __bf16* KE2b = (__bf16*)(ws + alloc(65536 / 2));
  __bf16* KNcb = (__bf16*)(ws + alloc(16384 / 2));
  __bf16* W1b  = (__bf16*)(ws + alloc(32768 / 2));
  __bf16* W2b  = (__bf16*)(ws + alloc(262144 / 2));
  __bf16* KN1b = (__bf16*)(ws + alloc(196608 / 2));
  __bf16* KN2b = (__bf16*)(ws + alloc(65536 / 2));
  __bf16* a1a2b= (__bf16*)(ws + alloc(131072 / 2));
  __bf16* K1Nb = (__bf16*)(ws + alloc(8192 / 2));
  __bf16* K2Nb = (__bf16*)(ws + alloc(16384 / 2));
  int* csr_cnt    = (int*)(ws + alloc(4096));
  int* csr_offs   = (int*)(ws + alloc(4160));
  int* csr_cursor = (int*)(ws + alloc(4096));
  int* csr_list   = (int*)(ws + alloc(2 * NEDGES));
  float2* pA = (float2*)(ws + alloc((size_t)4096 * 2));
  float2* pB = (float2*)(ws + alloc((size_t)4096 * 2));
  float2* pC = (float2*)(ws + alloc((size_t)4096 * 2));
  // aliases (lifetimes disjoint): opening-only transposed inputs
  __bf16* xeT64  = eBT;               // [E][64], eBT first written layer-0 emfma pass 2
  __bf16* xnT64b = UVb;               // [N][64], UVb first written layer-0 UV kernel

  const __bf16* BNUL = nullptr;
  const float* NUL = nullptr;
  const int* NULI = nullptr;
  const float2* PNUL = nullptr;
  __bf16* BNULm = nullptr;
  float* NULm = nullptr;
  float* FNULm = nullptr;

  // ---- weight conversion + CSR build (once) ----
  wcvt_k<<<3456, 256, 0, stream>>>(K1E, K2E, KE1, KE2, KNc, W1, W2, KN1, KN2, K1N, K2N,
                                   K1Eb, K2Eb, KE1b, KE2b, KNcb, W1b, W2b, KN1b, KN2b,
                                   a1a2b, K1Nb, K2Nb);
  hipMemsetAsync(csr_cnt, 0, 4096 * sizeof(int), stream);
  hist_k<<<NEDGES / 256, 256, 0, stream>>>(iI, jJ, csr_cnt);
  scan_k<<<1, 1024, 0, stream>>>(csr_cnt, csr_offs, csr_cursor);
  fill_k<<<NEDGES / 256, 256, 0, stream>>>(iI, jJ, csr_cursor, csr_list);

  // ---- opening: node double layer (MFMA, node-major, emits xnNb + sqnorm) ----
  etrans_k<<<NNODES / 64, 256, 0, stream>>>(xn_in, xnT64b, NNODES);
  nmfma_k<64, false, false, true, 0, false, 1><<<dim3(64, 8), 256, 0, stream>>>(
      K1Nb, xnT64b, BNUL, nAb, nullptr, nullptr, NUL, 128, pA, PNUL, 0, 0.0, BNULm, NULm);
  nmfma_k<128, false, true, false, 3, true, 4><<<dim3(64, 2), 256, 0, stream>>>(
      K2Nb, nAb, BNUL, nullptr, xnN, nullptr, NUL, 128, nullptr,
      pA, 512, (double)CH * NNODES, xnNb, sbufh);

  // ---- opening: edge double layer (MFMA, ob-split) ----
  etrans_k<<<NEDGES / 64, 256, 0, stream>>>(xe_in, xeT64, NEDGES);
  emfma_k<0, 64, 2, false><<<dim3(NEDGES / 64, 4), 256, 0, stream>>>(
      K1Eb, xeT64, eAT, pA, BNUL, BNUL, NUL, NULI, NULI, FNULm, PNUL, PNUL, 0, 0.0);
  emfma_k<3, 128, 2, false><<<dim3(NEDGES / 64, 4), 256, 0, stream>>>(
      K2Eb, eAT, xeT, nullptr, BNUL, BNUL, NUL, NULI, NULI, FNULm, PNUL,
      pA, 4096, (double)CH * NEDGES);

  for (int i = 0; i < 4; ++i) {
    const __bf16* KE1bi = KE1b + (size_t)i * 128 * 128;
    const __bf16* KE2bi = KE2b + (size_t)i * 128 * 128;
    const __bf16* KN1bi = KN1b + (size_t)i * 128 * 384;
    const __bf16* KN2bi = KN2b + (size_t)i * 128 * 128;
    const __bf16* a1a2i = a1a2b + (size_t)i * 256 * 128;

    // D statistics -> pA
    dstat_k<<<2080, 256, 0, stream>>>(xnNb, sbufh, pA);

    // UVb[n][256] = xnNb @ a1a2^T (bf16 out)
    nmfma_k<128, false, false, false, 0, false, 1><<<dim3(64, 16), 256, 0, stream>>>(
        a1a2i, xnNb, BNUL, UVb, nullptr, nullptr, NUL, 256, nullptr, PNUL, 0, 0.0, BNULm, NULm);

    // edge pass 1 (w inline from pA): eA = xe @ KE1^T + w*(U_I+V_J), stats -> pB
    emfma_k<2, 128, 2, true><<<dim3(NEDGES / 64, 4), 256, 0, stream>>>(
        KE1bi, xeT, eAT, pB, UVb, xnNb, sbufh, iI, jJ, wbuf, pA, PNUL, 0, 0.0);
    // edge pass 2: eB = tanh(ln(eA)) @ KE2^T, params<-pB, stats -> pC
    emfma_k<1, 128, 2, false><<<dim3(NEDGES / 64, 4), 256, 0, stream>>>(
        KE2bi, eAT, eBT, pC, BNUL, BNUL, NUL, NULI, NULI, FNULm, PNUL,
        pB, 4096, (double)CH * NEDGES);
    // xe += 0.1 * ln(eB), params<-pC
    lnres_k<<<2048, 256, 0, stream>>>(eBT, xeT, pC, 4096);

    // node update: gather -> catb; KN1 (split cat+xn) stats -> pB; KN2 tanh + resid + emit
    gather_k<<<NNODES / 4, 512, 0, stream>>>(xeT, wbuf, csr_offs, csr_list, catb);
    nmfma_k<384, true, false, true, 0, false, 1><<<dim3(64, 8), 256, 0, stream>>>(
        KN1bi, catb, xnNb, nAb, nullptr, nullptr, NUL, 128, pB, PNUL, 0, 0.0, BNULm, NULm);
    nmfma_k<128, false, true, false, 4, true, 4><<<dim3(64, 2), 256, 0, stream>>>(
        KN2bi, nAb, BNUL, nullptr, nullptr, xnN, NUL, 128, nullptr,
        pB, 512, (double)CH * NNODES, xnNb, sbufh);
  }

  // ---- close + MLP head (bf16 MFMA, node-major) ----
  nmfma_k<128, false, false, false, 0, false, 1><<<dim3(64, 8), 256, 0, stream>>>(
      KNcb, xnNb, BNUL, zb, nullptr, nullptr, NUL, 128, nullptr, PNUL, 0, 0.0, BNULm, NULm);
  nmfma_k<128, false, false, false, 1, false, 1><<<dim3(64, 16), 256, 0, stream>>>(
      W1b, zb, BNUL, l1bb, nullptr, nullptr, b1, 256, nullptr, PNUL, 0, 0.0, BNULm, NULm);
  nmfma_k<256, false, false, false, 2, false, 1><<<dim3(64, 64), 256, 0, stream>>>(
      W2b, l1bb, BNUL, nullptr, out, nullptr, b2, 1024, nullptr, PNUL, 0, 0.0, BNULm, NULm);
  logsoftmax_k<<<NNODES, 256, 0, stream>>>(out);
}

// Round 10
// 677.238 us; speedup vs baseline: 2.2661x; 1.1623x over previous
//
#include <hip/hip_runtime.h>

#define NNODES 4096
#define NEDGES 65536
#define CH 128

typedef __bf16 bf16x8_t __attribute__((ext_vector_type(8)));
typedef __bf16 bf16x4_t __attribute__((ext_vector_type(4)));
typedef __bf16 bf16x2_t __attribute__((ext_vector_type(2)));
typedef float f32x4_t __attribute__((ext_vector_type(4)));

// ---- fast tanh via hw exp2/rcp ----
__device__ __forceinline__ float fast_tanh(float x)
{
  float t = __builtin_amdgcn_exp2f(x * 2.885390081777927f);   // 2*log2(e)
  return 1.f - 2.f * __builtin_amdgcn_rcpf(t + 1.f);
}

// ---- block stats writer: f32 wave shfl-reduce, one float2 per block ----
__device__ __forceinline__ void write_stats(float s, float q, float2* __restrict__ partials,
                                            int pid, int tid, int nwaves)
{
#pragma unroll
  for (int d = 1; d < 64; d <<= 1) { s += __shfl_xor(s, d); q += __shfl_xor(q, d); }
  __shared__ float rs[8][2];
  const int wv = tid >> 6, lane = tid & 63;
  if (lane == 0) { rs[wv][0] = s; rs[wv][1] = q; }
  __syncthreads();
  if (tid == 0) {
    float S = 0.f, Q = 0.f;
    for (int i = 0; i < nwaves; ++i) { S += rs[i][0]; Q += rs[i][1]; }
    partials[pid] = {S, Q};
  }
}

// ---- inline params: f64 cross-block reduce of f32 partials -> (mean,rstd) or (factor,0) ----
__device__ __forceinline__ float2 params_inline(const float2* __restrict__ pp,
                                                int nblk, double M, int type)
{
  const int tid = threadIdx.x;
  double s = 0.0, q = 0.0;
  for (int i = tid; i < nblk; i += 256) { float2 v = pp[i]; s += (double)v.x; q += (double)v.y; }
#pragma unroll
  for (int d = 1; d < 64; d <<= 1) { s += __shfl_xor(s, d); q += __shfl_xor(q, d); }
  __shared__ double rs4[4], rq4[4];
  __shared__ float pr[2];
  const int wv = tid >> 6, lane = tid & 63;
  if (lane == 0) { rs4[wv] = s; rq4[wv] = q; }
  __syncthreads();
  if (tid == 0) {
    double S = rs4[0] + rs4[1] + rs4[2] + rs4[3];
    double Q = rq4[0] + rq4[1] + rq4[2] + rq4[3];
    if (type == 0) {
      double mean = S / M;
      double var = Q / M - mean * mean;
      if (var < 0.0) var = 0.0;
      pr[0] = (float)mean;
      pr[1] = (float)(1.0 / sqrt(var + 1e-5));
    } else {
      double var = (Q - S * S / M) / (M - 1.0);
      if (var < 1e-30) var = 1e-30;
      pr[0] = (float)(-2.0 / sqrt(var));
      pr[1] = 0.f;
    }
  }
  __syncthreads();
  return {pr[0], pr[1]};
}

// ================= bf16 MFMA edge GEMM (ob-split, OBS outs/block) =================
// grid (E/64, 8/OBS). EM 0: plain, stats   EM 2: + w*(U[I]+V[J]), stats (WPH computes w inline)
// EM 1: tanh-on-load, stats   EM 3: tanh-on-load, no stats
template<int EM, int K, int OBS, bool WPH>
__global__ __launch_bounds__(256) void emfma_k(
    const __bf16* __restrict__ A, const __bf16* __restrict__ X,
    __bf16* __restrict__ Cb,
    float2* __restrict__ partials,
    const __bf16* __restrict__ UVb, const __bf16* __restrict__ xnNb,
    const float* __restrict__ sbufh,
    const int* __restrict__ iI, const int* __restrict__ jJ,
    float* __restrict__ wbuf, const float2* __restrict__ pD,
    const float2* __restrict__ pp, int pnblk, double pM)
{
  __shared__ float wl[64];
  float p0 = 0.f, p1 = 0.f;
  if constexpr (EM == 1 || EM == 3) {
    float2 pr = params_inline(pp, pnblk, pM, 0); p0 = pr.x; p1 = pr.y;
  }
  const int tid = threadIdx.x;
  const int wv = tid >> 6, lane = tid & 63;
  const int l15 = lane & 15, ks = lane >> 4;
  const int row = wv * 16 + l15;
  const int e = blockIdx.x * 64 + row;
  if constexpr (WPH) {
    float2 fp = params_inline(pD, 2080, (double)NNODES * (double)NNODES, 1);
    const int eg = blockIdx.x * 64 + (tid >> 2);
    const int a = iI[eg], b = jJ[eg];
    const bf16x8_t* pa = (const bf16x8_t*)(xnNb + (size_t)a * CH + (tid & 3) * 32);
    const bf16x8_t* pb = (const bf16x8_t*)(xnNb + (size_t)b * CH + (tid & 3) * 32);
    float g = 0.f;
#pragma unroll
    for (int q = 0; q < 4; ++q) {
      bf16x8_t u = pa[q], v = pb[q];
#pragma unroll
      for (int j = 0; j < 8; ++j) g = fmaf((float)u[j], (float)v[j], g);
    }
    g += __shfl_xor(g, 1); g += __shfl_xor(g, 2);
    float d = sbufh[a] + sbufh[NNODES + a] + sbufh[b] + sbufh[NNODES + b] - 2.f * g;
    d = d > 0.f ? d : 0.f;
    float wgt = __builtin_amdgcn_exp2f(fp.x * d * 1.4426950408889634f);
    if ((tid & 3) == 0) {
      wl[tid >> 2] = wgt;
      if (blockIdx.y == 0) wbuf[eg] = wgt;
    }
    __syncthreads();
  }
  constexpr int KK = K / 32;
  bf16x8_t bq[KK];
  {
    const __bf16* xr = X + (size_t)e * K + ks * 8;
#pragma unroll
    for (int kk = 0; kk < KK; ++kk) {
      bf16x8_t v = *(const bf16x8_t*)(xr + kk * 32);
      if constexpr (EM == 1 || EM == 3) {
#pragma unroll
        for (int j = 0; j < 8; ++j) v[j] = (__bf16)fast_tanh(((float)v[j] - p0) * p1);
      }
      bq[kk] = v;
    }
  }
  float we = 0.f; int ie = 0, je = 0;
  if constexpr (EM == 2) { we = wl[row]; ie = iI[e]; je = jJ[e]; }
  float dsum = 0.f, dsq = 0.f;
  const int ob0 = blockIdx.y * OBS;
#pragma unroll
  for (int obb = 0; obb < OBS; ++obb) {
    const int ob = ob0 + obb;
    f32x4_t acc = {0.f, 0.f, 0.f, 0.f};
    const __bf16* ar = A + (size_t)(ob * 16 + l15) * K + ks * 8;
#pragma unroll
    for (int kk = 0; kk < KK; ++kk) {
      bf16x8_t a = *(const bf16x8_t*)(ar + kk * 32);
      acc = __builtin_amdgcn_mfma_f32_16x16x32_bf16(a, bq[kk], acc, 0, 0, 0);
    }
    const int ro = ob * 16 + ks * 4;
    float v0 = acc[0], v1 = acc[1], v2 = acc[2], v3 = acc[3];
    if constexpr (EM == 2) {
      bf16x4_t u4 = *(const bf16x4_t*)&UVb[(size_t)ie * 256 + ro];
      bf16x4_t w4 = *(const bf16x4_t*)&UVb[(size_t)je * 256 + 128 + ro];
      v0 += we * ((float)u4[0] + (float)w4[0]);
      v1 += we * ((float)u4[1] + (float)w4[1]);
      v2 += we * ((float)u4[2] + (float)w4[2]);
      v3 += we * ((float)u4[3] + (float)w4[3]);
    }
    if constexpr (EM != 3) {
      dsum += v0 + v1 + v2 + v3;
      dsq  += v0 * v0 + v1 * v1 + v2 * v2 + v3 * v3;
    }
    bf16x4_t bv;
    bv[0] = (__bf16)v0; bv[1] = (__bf16)v1; bv[2] = (__bf16)v2; bv[3] = (__bf16)v3;
    *(bf16x4_t*)(Cb + (size_t)e * 128 + ro) = bv;
  }
  if constexpr (EM != 3)
    write_stats(dsum, dsq, partials, blockIdx.y * gridDim.x + blockIdx.x, tid, 4);
}

// ================= bf16 MFMA node GEMM, col-tiled, OBS outs/block =================
// OM 0: bf16 out; 1: +bias elu bf16 out; 2: +bias f32 out; 3: f32 out; 4: resid[n][128] += 0.1*v
template<int K, bool XSPLIT, bool XT, bool STATS, int OM, bool EMITB, int OBS>
__global__ __launch_bounds__(256) void nmfma_k(
    const __bf16* __restrict__ A, const __bf16* __restrict__ X,
    const __bf16* __restrict__ X2,
    __bf16* __restrict__ Cb, float* __restrict__ Cf, float* __restrict__ resid,
    const float* __restrict__ bias, int nout_stride,
    float2* __restrict__ partials,
    const float2* __restrict__ pp, int pnblk, double pM,
    __bf16* __restrict__ xbout, float* __restrict__ shout)
{
  float p0 = 0.f, p1 = 0.f;
  if constexpr (XT) { float2 pr = params_inline(pp, pnblk, pM, 0); p0 = pr.x; p1 = pr.y; }
  const int tid = threadIdx.x;
  const int wv = tid >> 6, lane = tid & 63;
  const int l15 = lane & 15, ks = lane >> 4;
  const int n = blockIdx.x * 64 + wv * 16 + l15;
  constexpr int KK = K / 32;
  bf16x8_t bq[KK];
  if constexpr (XSPLIT) {
    const __bf16* xr  = X  + (size_t)n * 256 + ks * 8;
    const __bf16* xr2 = X2 + (size_t)n * 128 + ks * 8;
#pragma unroll
    for (int kk = 0; kk < 8; ++kk) bq[kk] = *(const bf16x8_t*)(xr + kk * 32);
#pragma unroll
    for (int kk = 8; kk < KK; ++kk) bq[kk] = *(const bf16x8_t*)(xr2 + (kk - 8) * 32);
  } else {
    const __bf16* xr = X + (size_t)n * K + ks * 8;
#pragma unroll
    for (int kk = 0; kk < KK; ++kk) {
      bf16x8_t v = *(const bf16x8_t*)(xr + kk * 32);
      if constexpr (XT) {
#pragma unroll
        for (int j = 0; j < 8; ++j) v[j] = (__bf16)fast_tanh(((float)v[j] - p0) * p1);
      }
      bq[kk] = v;
    }
  }
  float dsum = 0.f, dsq = 0.f, ss = 0.f;
  const int ob0 = blockIdx.y * OBS;
#pragma unroll
  for (int obb = 0; obb < OBS; ++obb) {
    const int ob = ob0 + obb;
    f32x4_t acc = {0.f, 0.f, 0.f, 0.f};
    const __bf16* ar = A + (size_t)(ob * 16 + l15) * K + ks * 8;
#pragma unroll
    for (int kk = 0; kk < KK; ++kk) {
      bf16x8_t a = *(const bf16x8_t*)(ar + kk * 32);
      acc = __builtin_amdgcn_mfma_f32_16x16x32_bf16(a, bq[kk], acc, 0, 0, 0);
    }
    const int ro = ob * 16 + ks * 4;
    float v[4] = {acc[0], acc[1], acc[2], acc[3]};
    if constexpr (OM == 1 || OM == 2) {
#pragma unroll
      for (int r = 0; r < 4; ++r) v[r] += bias[ro + r];
    }
    if constexpr (OM == 1) {
#pragma unroll
      for (int r = 0; r < 4; ++r) v[r] = v[r] > 0.f ? v[r] : expm1f(v[r]);
    }
    if constexpr (STATS) {
#pragma unroll
      for (int r = 0; r < 4; ++r) { dsum += v[r]; dsq += v[r] * v[r]; }
    }
    if constexpr (OM == 4) {
      float4* rp = (float4*)&resid[(size_t)n * 128 + ro];
      float4 rr = *rp;
      rr.x += 0.1f * v[0]; rr.y += 0.1f * v[1]; rr.z += 0.1f * v[2]; rr.w += 0.1f * v[3];
      *rp = rr;
      if constexpr (EMITB) {
        bf16x4_t eb;
        eb[0] = (__bf16)rr.x; eb[1] = (__bf16)rr.y; eb[2] = (__bf16)rr.z; eb[3] = (__bf16)rr.w;
        *(bf16x4_t*)(xbout + (size_t)n * 128 + ro) = eb;
#pragma unroll
        for (int r = 0; r < 4; ++r) { float f = (float)eb[r]; ss += f * f; }
      }
    } else if constexpr (OM == 2 || OM == 3) {
      float4 fv = {v[0], v[1], v[2], v[3]};
      *(float4*)(Cf + (size_t)n * nout_stride + ro) = fv;
      if constexpr (EMITB) {
        bf16x4_t eb;
        eb[0] = (__bf16)v[0]; eb[1] = (__bf16)v[1]; eb[2] = (__bf16)v[2]; eb[3] = (__bf16)v[3];
        *(bf16x4_t*)(xbout + (size_t)n * 128 + ro) = eb;
#pragma unroll
        for (int r = 0; r < 4; ++r) { float f = (float)eb[r]; ss += f * f; }
      }
    } else {
      bf16x4_t bv;
      bv[0] = (__bf16)v[0]; bv[1] = (__bf16)v[1]; bv[2] = (__bf16)v[2]; bv[3] = (__bf16)v[3];
      *(bf16x4_t*)(Cb + (size_t)n * nout_stride + ro) = bv;
    }
  }
  if constexpr (EMITB) {
    ss += __shfl_xor(ss, 16);
    ss += __shfl_xor(ss, 32);
    if (lane < 16) shout[blockIdx.y * NNODES + n] = ss;
  }
  if constexpr (STATS)
    write_stats(dsum, dsq, partials, blockIdx.y * gridDim.x + blockIdx.x, tid, 4);
}

// ================= dstat via MFMA Gram matrix, triangular 1-D grid (2080 blocks) =================
__global__ __launch_bounds__(256) void dstat_k(
    const __bf16* __restrict__ fT, const float* __restrict__ sh,
    float2* __restrict__ partials)
{
  int rem = blockIdx.x, i0t = 0;
  while (rem >= 64 - i0t) { rem -= 64 - i0t; ++i0t; }
  const int i0 = i0t * 64, j0 = (i0t + rem) * 64;
  const float wgt = (j0 > i0) ? 2.f : 1.f;
  const int tid = threadIdx.x;
  const int wv = tid >> 6, lane = tid & 63, l15 = lane & 15, ks = lane >> 4;
  const int irow = i0 + wv * 16 + l15;
  bf16x8_t aq[4];
  const __bf16* ar = fT + (size_t)irow * 128 + ks * 8;
#pragma unroll
  for (int kk = 0; kk < 4; ++kk) aq[kk] = *(const bf16x8_t*)(ar + kk * 32);
  float si[4];
#pragma unroll
  for (int r = 0; r < 4; ++r) {
    int ii = i0 + wv * 16 + ks * 4 + r;
    si[r] = sh[ii] + sh[NNODES + ii];
  }
  float dsum = 0.f, dsq = 0.f;
#pragma unroll
  for (int jb = 0; jb < 4; ++jb) {
    const int jcol = j0 + jb * 16 + l15;
    const __bf16* br = fT + (size_t)jcol * 128 + ks * 8;
    f32x4_t acc = {0.f, 0.f, 0.f, 0.f};
#pragma unroll
    for (int kk = 0; kk < 4; ++kk) {
      bf16x8_t b = *(const bf16x8_t*)(br + kk * 32);
      acc = __builtin_amdgcn_mfma_f32_16x16x32_bf16(aq[kk], b, acc, 0, 0, 0);
    }
    const float sj = sh[jcol] + sh[NNODES + jcol];
#pragma unroll
    for (int r = 0; r < 4; ++r) {
      float d = si[r] + sj - 2.f * acc[r];
      d = d > 0.f ? d : 0.f;
      dsum += d; dsq += d * d;
    }
  }
  write_stats(dsum * wgt, dsq * wgt, partials, blockIdx.x, tid, 4);
}

// ================= transpose src [64][ncols] f32 -> dst [ncols][64] bf16 =================
__global__ __launch_bounds__(256) void etrans_k(const float* __restrict__ src,
                                                __bf16* __restrict__ dst, int ncols)
{
  __shared__ float t[64][65];
  const int e0 = blockIdx.x * 64;
  const int tx = threadIdx.x & 63, tw = threadIdx.x >> 6;
  for (int c = tw; c < 64; c += 4)
    t[tx][c] = src[(size_t)c * ncols + e0 + tx];
  __syncthreads();
  const int el = threadIdx.x >> 2, c0 = (threadIdx.x & 3) * 16;
  for (int q = 0; q < 4; ++q) {
    int c = c0 + q * 4;
    bf16x4_t b;
    b[0] = (__bf16)t[el][c];     b[1] = (__bf16)t[el][c + 1];
    b[2] = (__bf16)t[el][c + 2]; b[3] = (__bf16)t[el][c + 3];
    *(bf16x4_t*)&dst[(size_t)(e0 + el) * 64 + c] = b;
  }
}

// ================= weight conversion to bf16 (one launch) =================
__global__ void wcvt_k(const float* __restrict__ K1E, const float* __restrict__ K2E,
                       const float* __restrict__ KE1, const float* __restrict__ KE2,
                       const float* __restrict__ KNc, const float* __restrict__ W1,
                       const float* __restrict__ W2, const float* __restrict__ KN1,
                       const float* __restrict__ KN2, const float* __restrict__ K1N,
                       const float* __restrict__ K2N,
                       __bf16* __restrict__ K1Eb, __bf16* __restrict__ K2Eb,
                       __bf16* __restrict__ KE1b, __bf16* __restrict__ KE2b,
                       __bf16* __restrict__ KNcb, __bf16* __restrict__ W1b,
                       __bf16* __restrict__ W2b, __bf16* __restrict__ KN1b,
                       __bf16* __restrict__ KN2b, __bf16* __restrict__ a1a2b,
                       __bf16* __restrict__ K1Nb, __bf16* __restrict__ K2Nb)
{
  int id = blockIdx.x * 256 + threadIdx.x;
  if (id < 8192) { K1Eb[id] = (__bf16)K1E[id]; return; }
  id -= 8192;
  if (id < 16384) { K2Eb[id] = (__bf16)K2E[id]; return; }
  id -= 16384;
  if (id < 65536) {
    int l = id >> 14, rem = id & 16383, r = rem >> 7, c = rem & 127;
    KE1b[id] = (__bf16)KE1[(size_t)l * 49152 + r * 384 + 128 + c];
    return;
  }
  id -= 65536;
  if (id < 65536) { KE2b[id] = (__bf16)KE2[id]; return; }
  id -= 65536;
  if (id < 16384) { KNcb[id] = (__bf16)KNc[id]; return; }
  id -= 16384;
  if (id < 32768) { W1b[id] = (__bf16)W1[id]; return; }
  id -= 32768;
  if (id < 262144) { W2b[id] = (__bf16)W2[id]; return; }
  id -= 262144;
  if (id < 196608) { KN1b[id] = (__bf16)KN1[id]; return; }
  id -= 196608;
  if (id < 65536) { KN2b[id] = (__bf16)KN2[id]; return; }
  id -= 65536;
  if (id < 131072) {
    int l = id >> 15, rem = id & 32767, r = rem >> 7, c = rem & 127;
    int o = r & 127;
    float k1 = KE1[(size_t)l * 49152 + o * 384 + c];
    float k3 = KE1[(size_t)l * 49152 + o * 384 + 256 + c];
    a1a2b[id] = (__bf16)((r < 128) ? (0.5f * k1 + k3) : (0.5f * k1 - k3));
    return;
  }
  id -= 131072;
  if (id < 8192) { K1Nb[id] = (__bf16)K1N[id]; return; }
  id -= 8192;
  if (id < 16384) { K2Nb[id] = (__bf16)K2N[id]; return; }
}

// ================= lnres: xeT = bf16(f32(xeT) + 0.1*ln(eB)) =================
__global__ __launch_bounds__(256) void lnres_k(
    const __bf16* __restrict__ eBT, __bf16* __restrict__ xeT,
    const float2* __restrict__ pp, int pnblk)
{
  float2 pr = params_inline(pp, pnblk, (double)CH * NEDGES, 0);
  const float m = pr.x, r = pr.y;
  const size_t base = (size_t)blockIdx.x * (256 * 16);
  for (int it = 0; it < 2; ++it) {
    size_t i = base + (size_t)it * 2048 + (size_t)threadIdx.x * 8;
    bf16x8_t b = *(const bf16x8_t*)(eBT + i);
    bf16x8_t x = *(const bf16x8_t*)(xeT + i);
    bf16x8_t ob;
#pragma unroll
    for (int j = 0; j < 8; ++j)
      ob[j] = (__bf16)((float)x[j] + 0.1f * (((float)b[j] - m) * r));
    *(bf16x8_t*)(xeT + i) = ob;
  }
}

// ================= CSR build =================
__global__ void hist_k(const int* __restrict__ iI, const int* __restrict__ jJ,
                       int* __restrict__ cnt)
{
  int e = blockIdx.x * 256 + threadIdx.x;
  atomicAdd(&cnt[iI[e]], 1);
  atomicAdd(&cnt[jJ[e]], 1);
}

__global__ __launch_bounds__(1024) void scan_k(const int* __restrict__ cnt,
                                               int* __restrict__ offs,
                                               int* __restrict__ cursor)
{
  __shared__ int tmp[1024];
  const int tid = threadIdx.x;
  int4 v = *(const int4*)&cnt[tid * 4];
  int s = v.x + v.y + v.z + v.w;
  tmp[tid] = s; __syncthreads();
  for (int d = 1; d < 1024; d <<= 1) {
    int t = (tid >= d) ? tmp[tid - d] : 0;
    __syncthreads();
    tmp[tid] += t;
    __syncthreads();
  }
  int base = tmp[tid] - s;
  int4 o = {base, base + v.x, base + v.x + v.y, base + v.x + v.y + v.z};
  *(int4*)&offs[tid * 4] = o;
  *(int4*)&cursor[tid * 4] = o;
  if (tid == 1023) offs[4096] = tmp[1023];
}

__global__ void fill_k(const int* __restrict__ iI, const int* __restrict__ jJ,
                       int* __restrict__ cursor, int* __restrict__ list)
{
  int e = blockIdx.x * 256 + threadIdx.x;
  int p1 = atomicAdd(&cursor[iI[e]], 1);
  list[p1] = e;
  int p2 = atomicAdd(&cursor[jJ[e]], 1);
  list[p2] = e | 0x80000000;
}

// ================= gather: 8 waves, 2 per node (incidence-split) -> catb bf16 [n][256] =================
__global__ __launch_bounds__(512) void gather_k(
    const __bf16* __restrict__ xeT, const float* __restrict__ w,
    const int* __restrict__ offs, const int* __restrict__ list,
    __bf16* __restrict__ catb)
{
  __shared__ float comb[4][4][64];
  const int wv = threadIdx.x >> 6, lane = threadIdx.x & 63;
  const int nn = wv >> 1, half = wv & 1;
  const int n = blockIdx.x * 4 + nn;
  const int k0 = offs[n], k1 = offs[n + 1];
  float s1a = 0.f, s1b = 0.f, s2a = 0.f, s2b = 0.f;
#pragma unroll 2
  for (int k = k0 + half; k < k1; k += 2) {
    int enc = list[k];
    int e = enc & 0x7fffffff;
    float we = w[e];
    bf16x2_t xv = *(const bf16x2_t*)&xeT[(size_t)e * 128 + lane * 2];
    float va = (float)xv[0] * we;
    float vb = (float)xv[1] * we;
    if (enc >= 0) { s1a += va; s1b += vb; }
    else          { s2a += va; s2b += vb; }
  }
  if (half == 1) {
    comb[nn][0][lane] = s1a; comb[nn][1][lane] = s1b;
    comb[nn][2][lane] = s2a; comb[nn][3][lane] = s2b;
  }
  __syncthreads();
  if (half == 0) {
    s1a += comb[nn][0][lane]; s1b += comb[nn][1][lane];
    s2a += comb[nn][2][lane]; s2b += comb[nn][3][lane];
    __bf16* row = catb + (size_t)n * 256;
    bf16x2_t av, dv;
    av[0] = (__bf16)(0.5f * (s1a + s2a)); av[1] = (__bf16)(0.5f * (s1b + s2b));
    dv[0] = (__bf16)(s1a - s2a);          dv[1] = (__bf16)(s1b - s2b);
    *(bf16x2_t*)&row[lane * 2] = av;
    *(bf16x2_t*)&row[128 + lane * 2] = dv;
  }
}

// ================= log_softmax rows of [N][1024] =================
__global__ __launch_bounds__(256) void logsoftmax_k(float* __restrict__ out)
{
  __shared__ float red[256];
  const int n = blockIdx.x, tid = threadIdx.x;
  float* row = out + (size_t)n * 1024;
  float v[4];
  float mx = -1e30f;
#pragma unroll
  for (int l = 0; l < 4; ++l) { v[l] = row[tid + 256 * l]; mx = fmaxf(mx, v[l]); }
  red[tid] = mx; __syncthreads();
  for (int s = 128; s > 0; s >>= 1) { if (tid < s) red[tid] = fmaxf(red[tid], red[tid + s]); __syncthreads(); }
  float m = red[0]; __syncthreads();
  float se = 0.f;
#pragma unroll
  for (int l = 0; l < 4; ++l) se += expf(v[l] - m);
  red[tid] = se; __syncthreads();
  for (int s = 128; s > 0; s >>= 1) { if (tid < s) red[tid] += red[tid + s]; __syncthreads(); }
  float L = m + logf(red[0]);
#pragma unroll
  for (int l = 0; l < 4; ++l) row[tid + 256 * l] = v[l] - L;
}

extern "C" void kernel_launch(void* const* d_in, const int* in_sizes, int n_in,
                              void* d_out, int out_size, void* d_ws, size_t ws_size,
                              hipStream_t stream)
{
  (void)in_sizes; (void)n_in; (void)out_size; (void)ws_size;
  const float* xn_in = (const float*)d_in[0];
  const float* xe_in = (const float*)d_in[1];
  const int*   iI    = (const int*)d_in[2];
  const int*   jJ    = (const int*)d_in[3];
  const float* K1N   = (const float*)d_in[4];
  const float* K2N   = (const float*)d_in[5];
  const float* K1E   = (const float*)d_in[6];
  const float* K2E   = (const float*)d_in[7];
  const float* KNc   = (const float*)d_in[8];
  const float* KE1   = (const float*)d_in[9];
  const float* KE2   = (const float*)d_in[10];
  const float* KN1   = (const float*)d_in[11];
  const float* KN2   = (const float*)d_in[12];
  const float* W1    = (const float*)d_in[13];
  const float* b1    = (const float*)d_in[14];
  const float* W2    = (const float*)d_in[15];
  const float* b2    = (const float*)d_in[16];
  float* out = (float*)d_out;

  float* ws = (float*)d_ws;
  size_t off = 0;
  auto alloc = [&](size_t n) { size_t o = off; off += (n + 63) & ~(size_t)63; return o; };
  float* xnN   = ws + alloc((size_t)NNODES * CH);                  // f32 node-major master
  __bf16* xeT  = (__bf16*)(ws + alloc((size_t)NEDGES * CH / 2));   // bf16 edge state
  __bf16* eAT  = (__bf16*)(ws + alloc((size_t)NEDGES * CH / 2));
  __bf16* eBT  = (__bf16*)(ws + alloc((size_t)NEDGES * CH / 2));
  float* sbufh = ws + alloc(2 * NNODES);                           // sqnorm halves
  float* wbuf  = ws + alloc(NEDGES);
  __bf16* UVb  = (__bf16*)(ws + alloc((size_t)NNODES * 256 / 2));
  __bf16* xnNb = (__bf16*)(ws + alloc((size_t)NNODES * CH / 2));
  __bf16* catb = (__bf16*)(ws + alloc((size_t)NNODES * 256 / 2));
  __bf16* nAb  = (__bf16*)(ws + alloc((size_t)NNODES * CH / 2));
  __bf16* zb   = (__bf16*)(ws + alloc((size_t)NNODES * CH / 2));
  __bf16* l1bb = (__bf16*)(ws + alloc((size_t)NNODES * 256 / 2));
  __bf16* K1Eb = (__bf16*)(ws + alloc(8192 / 2));
  __bf16* K2Eb = (__bf16*)(ws + alloc(16384 / 2));
  __bf16* KE1b = (__bf16*)(ws + alloc(65536 / 2));
  __bf16* KE2b = (__bf16*)(ws + alloc(65536 / 2));
  __bf16* KNcb = (__bf16*)(ws + alloc(16384 / 2));
  __bf16* W1b  = (__bf16*)(ws + alloc(32768 / 2));
  __bf16* W2b  = (__bf16*)(ws + alloc(262144 / 2));
  __bf16* KN1b = (__bf16*)(ws + alloc(196608 / 2));
  __bf16* KN2b = (__bf16*)(ws + alloc(65536 / 2));
  __bf16* a1a2b= (__bf16*)(ws + alloc(131072 / 2));
  __bf16* K1Nb = (__bf16*)(ws + alloc(8192 / 2));
  __bf16* K2Nb = (__bf16*)(ws + alloc(16384 / 2));
  int* csr_cnt    = (int*)(ws + alloc(4096));
  int* csr_offs   = (int*)(ws + alloc(4160));
  int* csr_cursor = (int*)(ws + alloc(4096));
  int* csr_list   = (int*)(ws + alloc(2 * NEDGES));
  float2* pA = (float2*)(ws + alloc((size_t)4096 * 2));
  float2* pB = (float2*)(ws + alloc((size_t)4096 * 2));
  float2* pC = (float2*)(ws + alloc((size_t)4096 * 2));
  // aliases (lifetimes disjoint): opening-only transposed inputs
  __bf16* xeT64  = eBT;               // [E][64], eBT first written layer-0 emfma pass 2
  __bf16* xnT64b = UVb;               // [N][64], UVb first written layer-0 UV kernel

  const __bf16* BNUL = nullptr;
  const float* NUL = nullptr;
  const int* NULI = nullptr;
  const float2* PNUL = nullptr;
  __bf16* BNULm = nullptr;
  float* NULm = nullptr;
  float* FNULm = nullptr;

  // ---- weight conversion + CSR build (once) ----
  wcvt_k<<<3456, 256, 0, stream>>>(K1E, K2E, KE1, KE2, KNc, W1, W2, KN1, KN2, K1N, K2N,
                                   K1Eb, K2Eb, KE1b, KE2b, KNcb, W1b, W2b, KN1b, KN2b,
                                   a1a2b, K1Nb, K2Nb);
  hipMemsetAsync(csr_cnt, 0, 4096 * sizeof(int), stream);
  hist_k<<<NEDGES / 256, 256, 0, stream>>>(iI, jJ, csr_cnt);
  scan_k<<<1, 1024, 0, stream>>>(csr_cnt, csr_offs, csr_cursor);
  fill_k<<<NEDGES / 256, 256, 0, stream>>>(iI, jJ, csr_cursor, csr_list);

  // ---- opening: node double layer (MFMA, node-major, emits xnNb + sqnorm) ----
  etrans_k<<<NNODES / 64, 256, 0, stream>>>(xn_in, xnT64b, NNODES);
  nmfma_k<64, false, false, true, 0, false, 1><<<dim3(64, 8), 256, 0, stream>>>(
      K1Nb, xnT64b, BNUL, nAb, nullptr, nullptr, NUL, 128, pA, PNUL, 0, 0.0, BNULm, NULm);
  nmfma_k<128, false, true, false, 3, true, 4><<<dim3(64, 2), 256, 0, stream>>>(
      K2Nb, nAb, BNUL, nullptr, xnN, nullptr, NUL, 128, nullptr,
      pA, 512, (double)CH * NNODES, xnNb, sbufh);

  // ---- opening: edge double layer (MFMA, ob-split y=2) ----
  etrans_k<<<NEDGES / 64, 256, 0, stream>>>(xe_in, xeT64, NEDGES);
  emfma_k<0, 64, 4, false><<<dim3(NEDGES / 64, 2), 256, 0, stream>>>(
      K1Eb, xeT64, eAT, pA, BNUL, BNUL, NUL, NULI, NULI, FNULm, PNUL, PNUL, 0, 0.0);
  emfma_k<3, 128, 4, false><<<dim3(NEDGES / 64, 2), 256, 0, stream>>>(
      K2Eb, eAT, xeT, nullptr, BNUL, BNUL, NUL, NULI, NULI, FNULm, PNUL,
      pA, 2048, (double)CH * NEDGES);

  for (int i = 0; i < 4; ++i) {
    const __bf16* KE1bi = KE1b + (size_t)i * 128 * 128;
    const __bf16* KE2bi = KE2b + (size_t)i * 128 * 128;
    const __bf16* KN1bi = KN1b + (size_t)i * 128 * 384;
    const __bf16* KN2bi = KN2b + (size_t)i * 128 * 128;
    const __bf16* a1a2i = a1a2b + (size_t)i * 256 * 128;

    // D statistics -> pA
    dstat_k<<<2080, 256, 0, stream>>>(xnNb, sbufh, pA);

    // UVb[n][256] = xnNb @ a1a2^T (bf16 out)
    nmfma_k<128, false, false, false, 0, false, 1><<<dim3(64, 16), 256, 0, stream>>>(
        a1a2i, xnNb, BNUL, UVb, nullptr, nullptr, NUL, 256, nullptr, PNUL, 0, 0.0, BNULm, NULm);

    // edge pass 1 (w inline from pA): eA = xe @ KE1^T + w*(U_I+V_J), stats -> pB
    emfma_k<2, 128, 4, true><<<dim3(NEDGES / 64, 2), 256, 0, stream>>>(
        KE1bi, xeT, eAT, pB, UVb, xnNb, sbufh, iI, jJ, wbuf, pA, PNUL, 0, 0.0);
    // edge pass 2: eB = tanh(ln(eA)) @ KE2^T, params<-pB, stats -> pC
    emfma_k<1, 128, 4, false><<<dim3(NEDGES / 64, 2), 256, 0, stream>>>(
        KE2bi, eAT, eBT, pC, BNUL, BNUL, NUL, NULI, NULI, FNULm, PNUL,
        pB, 2048, (double)CH * NEDGES);
    // xe += 0.1 * ln(eB), params<-pC
    lnres_k<<<2048, 256, 0, stream>>>(eBT, xeT, pC, 2048);

    // node update: gather -> catb; KN1 (split cat+xn) stats -> pB; KN2 tanh + resid + emit
    gather_k<<<NNODES / 4, 512, 0, stream>>>(xeT, wbuf, csr_offs, csr_list, catb);
    nmfma_k<384, true, false, true, 0, false, 1><<<dim3(64, 8), 256, 0, stream>>>(
        KN1bi, catb, xnNb, nAb, nullptr, nullptr, NUL, 128, pB, PNUL, 0, 0.0, BNULm, NULm);
    nmfma_k<128, false, true, false, 4, true, 4><<<dim3(64, 2), 256, 0, stream>>>(
        KN2bi, nAb, BNUL, nullptr, nullptr, xnN, NUL, 128, nullptr,
        pB, 512, (double)CH * NNODES, xnNb, sbufh);
  }

  // ---- close + MLP head (bf16 MFMA, node-major) ----
  nmfma_k<128, false, false, false, 0, false, 1><<<dim3(64, 8), 256, 0, stream>>>(
      KNcb, xnNb, BNUL, zb, nullptr, nullptr, NUL, 128, nullptr, PNUL, 0, 0.0, BNULm, NULm);
  nmfma_k<128, false, false, false, 1, false, 1><<<dim3(64, 16), 256, 0, stream>>>(
      W1b, zb, BNUL, l1bb, nullptr, nullptr, b1, 256, nullptr, PNUL, 0, 0.0, BNULm, NULm);
  nmfma_k<256, false, false, false, 2, false, 1><<<dim3(64, 64), 256, 0, stream>>>(
      W2b, l1bb, BNUL, nullptr, out, nullptr, b2, 1024, nullptr, PNUL, 0, 0.0, BNULm, NULm);
  logsoftmax_k<<<NNODES, 256, 0, stream>>>(out);
}

// Round 11
// 676.392 us; speedup vs baseline: 2.2690x; 1.0013x over previous
//
#include <hip/hip_runtime.h>

#define NNODES 4096
#define NEDGES 65536
#define CH 128

typedef __bf16 bf16x8_t __attribute__((ext_vector_type(8)));
typedef __bf16 bf16x4_t __attribute__((ext_vector_type(4)));
typedef __bf16 bf16x2_t __attribute__((ext_vector_type(2)));
typedef float f32x4_t __attribute__((ext_vector_type(4)));

// ---- fast tanh via hw exp2/rcp ----
__device__ __forceinline__ float fast_tanh(float x)
{
  float t = __builtin_amdgcn_exp2f(x * 2.885390081777927f);   // 2*log2(e)
  return 1.f - 2.f * __builtin_amdgcn_rcpf(t + 1.f);
}

// ---- block stats writer: f32 wave shfl-reduce, one float2 per block ----
__device__ __forceinline__ void write_stats(float s, float q, float2* __restrict__ partials,
                                            int pid, int tid, int nwaves)
{
#pragma unroll
  for (int d = 1; d < 64; d <<= 1) { s += __shfl_xor(s, d); q += __shfl_xor(q, d); }
  __shared__ float rs[8][2];
  const int wv = tid >> 6, lane = tid & 63;
  if (lane == 0) { rs[wv][0] = s; rs[wv][1] = q; }
  __syncthreads();
  if (tid == 0) {
    float S = 0.f, Q = 0.f;
    for (int i = 0; i < nwaves; ++i) { S += rs[i][0]; Q += rs[i][1]; }
    partials[pid] = {S, Q};
  }
}

// ---- inline params: f64 cross-block reduce of f32 partials -> (mean,rstd) or (factor,0) ----
__device__ __forceinline__ float2 params_inline(const float2* __restrict__ pp,
                                                int nblk, double M, int type)
{
  const int tid = threadIdx.x;
  double s = 0.0, q = 0.0;
  for (int i = tid; i < nblk; i += 256) { float2 v = pp[i]; s += (double)v.x; q += (double)v.y; }
#pragma unroll
  for (int d = 1; d < 64; d <<= 1) { s += __shfl_xor(s, d); q += __shfl_xor(q, d); }
  __shared__ double rs4[4], rq4[4];
  __shared__ float pr[2];
  const int wv = tid >> 6, lane = tid & 63;
  if (lane == 0) { rs4[wv] = s; rq4[wv] = q; }
  __syncthreads();
  if (tid == 0) {
    double S = rs4[0] + rs4[1] + rs4[2] + rs4[3];
    double Q = rq4[0] + rq4[1] + rq4[2] + rq4[3];
    if (type == 0) {
      double mean = S / M;
      double var = Q / M - mean * mean;
      if (var < 0.0) var = 0.0;
      pr[0] = (float)mean;
      pr[1] = (float)(1.0 / sqrt(var + 1e-5));
    } else {
      double var = (Q - S * S / M) / (M - 1.0);
      if (var < 1e-30) var = 1e-30;
      pr[0] = (float)(-2.0 / sqrt(var));
      pr[1] = 0.f;
    }
  }
  __syncthreads();
  return {pr[0], pr[1]};
}

// ================= bf16 MFMA edge GEMM (ob-split, OBS outs/block) =================
// grid (E/64, 8/OBS). EM 0: plain, stats   EM 2: + w*(U[I]+V[J]), stats (WPH computes w inline)
// EM 1: tanh-on-load, stats   EM 3: tanh-on-load, no stats
template<int EM, int K, int OBS, bool WPH>
__global__ __launch_bounds__(256) void emfma_k(
    const __bf16* __restrict__ A, const __bf16* __restrict__ X,
    __bf16* __restrict__ Cb,
    float2* __restrict__ partials,
    const __bf16* __restrict__ UVb, const __bf16* __restrict__ xnNb,
    const float* __restrict__ sbufh,
    const int* __restrict__ iI, const int* __restrict__ jJ,
    float* __restrict__ wbuf, const float2* __restrict__ pD,
    const float2* __restrict__ pp, int pnblk, double pM)
{
  __shared__ float wl[64];
  __shared__ int il[64], jl[64];
  const int tid = threadIdx.x;
  const int wv = tid >> 6, lane = tid & 63;
  const int l15 = lane & 15, ks = lane >> 4;
  const int row = wv * 16 + l15;
  const int e = blockIdx.x * 64 + row;
  constexpr int KK = K / 32;
  // hoisted raw X loads: issue before any params/weight work
  bf16x8_t bq[KK];
  {
    const __bf16* xr = X + (size_t)e * K + ks * 8;
#pragma unroll
    for (int kk = 0; kk < KK; ++kk) bq[kk] = *(const bf16x8_t*)(xr + kk * 32);
  }
  if constexpr (WPH) {
    // fused prologue: pD cross-block reduce overlapped with edge-weight gather
    double s = 0.0, q = 0.0;
    for (int i = tid; i < 2080; i += 256) { float2 v = pD[i]; s += (double)v.x; q += (double)v.y; }
    const int eg = blockIdx.x * 64 + (tid >> 2);
    const int a = iI[eg], b = jJ[eg];
    if ((tid & 3) == 0) { il[tid >> 2] = a; jl[tid >> 2] = b; }
    const bf16x8_t* pa = (const bf16x8_t*)(xnNb + (size_t)a * CH + (tid & 3) * 32);
    const bf16x8_t* pb = (const bf16x8_t*)(xnNb + (size_t)b * CH + (tid & 3) * 32);
    float g = 0.f;
#pragma unroll
    for (int q4 = 0; q4 < 4; ++q4) {
      bf16x8_t u = pa[q4], v = pb[q4];
#pragma unroll
      for (int j = 0; j < 8; ++j) g = fmaf((float)u[j], (float)v[j], g);
    }
    g += __shfl_xor(g, 1); g += __shfl_xor(g, 2);
    float dd = sbufh[a] + sbufh[NNODES + a] + sbufh[b] + sbufh[NNODES + b] - 2.f * g;
    dd = dd > 0.f ? dd : 0.f;
#pragma unroll
    for (int d = 1; d < 64; d <<= 1) { s += __shfl_xor(s, d); q += __shfl_xor(q, d); }
    __shared__ double rs4[4], rq4[4];
    __shared__ float prf;
    if (lane == 0) { rs4[wv] = s; rq4[wv] = q; }
    __syncthreads();
    if (tid == 0) {
      double S = rs4[0] + rs4[1] + rs4[2] + rs4[3];
      double Q = rq4[0] + rq4[1] + rq4[2] + rq4[3];
      const double M = (double)NNODES * (double)NNODES;
      double var = (Q - S * S / M) / (M - 1.0);
      if (var < 1e-30) var = 1e-30;
      prf = (float)(-2.0 / sqrt(var));
    }
    __syncthreads();
    float wgt = __builtin_amdgcn_exp2f(prf * dd * 1.4426950408889634f);
    if ((tid & 3) == 0) {
      wl[tid >> 2] = wgt;
      if (blockIdx.y == 0) wbuf[eg] = wgt;
    }
    __syncthreads();
  }
  if constexpr (EM == 1 || EM == 3) {
    float2 pr = params_inline(pp, pnblk, pM, 0);
    const float p0 = pr.x, p1 = pr.y;
#pragma unroll
    for (int kk = 0; kk < KK; ++kk) {
#pragma unroll
      for (int j = 0; j < 8; ++j)
        bq[kk][j] = (__bf16)fast_tanh(((float)bq[kk][j] - p0) * p1);
    }
  }
  float we = 0.f; int ie = 0, je = 0;
  if constexpr (EM == 2) { we = wl[row]; ie = il[row]; je = jl[row]; }
  float dsum = 0.f, dsq = 0.f;
  const int ob0 = blockIdx.y * OBS;
#pragma unroll
  for (int obb = 0; obb < OBS; ++obb) {
    const int ob = ob0 + obb;
    f32x4_t acc = {0.f, 0.f, 0.f, 0.f};
    const __bf16* ar = A + (size_t)(ob * 16 + l15) * K + ks * 8;
#pragma unroll
    for (int kk = 0; kk < KK; ++kk) {
      bf16x8_t a = *(const bf16x8_t*)(ar + kk * 32);
      acc = __builtin_amdgcn_mfma_f32_16x16x32_bf16(a, bq[kk], acc, 0, 0, 0);
    }
    const int ro = ob * 16 + ks * 4;
    float v0 = acc[0], v1 = acc[1], v2 = acc[2], v3 = acc[3];
    if constexpr (EM == 2) {
      bf16x4_t u4 = *(const bf16x4_t*)&UVb[(size_t)ie * 256 + ro];
      bf16x4_t w4 = *(const bf16x4_t*)&UVb[(size_t)je * 256 + 128 + ro];
      v0 += we * ((float)u4[0] + (float)w4[0]);
      v1 += we * ((float)u4[1] + (float)w4[1]);
      v2 += we * ((float)u4[2] + (float)w4[2]);
      v3 += we * ((float)u4[3] + (float)w4[3]);
    }
    if constexpr (EM != 3) {
      dsum += v0 + v1 + v2 + v3;
      dsq  += v0 * v0 + v1 * v1 + v2 * v2 + v3 * v3;
    }
    bf16x4_t bv;
    bv[0] = (__bf16)v0; bv[1] = (__bf16)v1; bv[2] = (__bf16)v2; bv[3] = (__bf16)v3;
    *(bf16x4_t*)(Cb + (size_t)e * 128 + ro) = bv;
  }
  if constexpr (EM != 3)
    write_stats(dsum, dsq, partials, blockIdx.y * gridDim.x + blockIdx.x, tid, 4);
}

// ================= bf16 MFMA node GEMM, col-tiled, OBS outs/block =================
// OM 0: bf16 out; 1: +bias elu bf16 out; 2: +bias f32 out; 3: f32 out; 4: resid[n][128] += 0.1*v
template<int K, bool XSPLIT, bool XT, bool STATS, int OM, bool EMITB, int OBS>
__global__ __launch_bounds__(256) void nmfma_k(
    const __bf16* __restrict__ A, const __bf16* __restrict__ X,
    const __bf16* __restrict__ X2,
    __bf16* __restrict__ Cb, float* __restrict__ Cf, float* __restrict__ resid,
    const float* __restrict__ bias, int nout_stride,
    float2* __restrict__ partials,
    const float2* __restrict__ pp, int pnblk, double pM,
    __bf16* __restrict__ xbout, float* __restrict__ shout)
{
  const int tid = threadIdx.x;
  const int wv = tid >> 6, lane = tid & 63;
  const int l15 = lane & 15, ks = lane >> 4;
  const int n = blockIdx.x * 64 + wv * 16 + l15;
  constexpr int KK = K / 32;
  bf16x8_t bq[KK];
  if constexpr (XSPLIT) {
    const __bf16* xr  = X  + (size_t)n * 256 + ks * 8;
    const __bf16* xr2 = X2 + (size_t)n * 128 + ks * 8;
#pragma unroll
    for (int kk = 0; kk < 8; ++kk) bq[kk] = *(const bf16x8_t*)(xr + kk * 32);
#pragma unroll
    for (int kk = 8; kk < KK; ++kk) bq[kk] = *(const bf16x8_t*)(xr2 + (kk - 8) * 32);
  } else {
    const __bf16* xr = X + (size_t)n * K + ks * 8;
#pragma unroll
    for (int kk = 0; kk < KK; ++kk) bq[kk] = *(const bf16x8_t*)(xr + kk * 32);
  }
  if constexpr (XT) {
    float2 pr = params_inline(pp, pnblk, pM, 0);
    const float p0 = pr.x, p1 = pr.y;
#pragma unroll
    for (int kk = 0; kk < KK; ++kk) {
#pragma unroll
      for (int j = 0; j < 8; ++j)
        bq[kk][j] = (__bf16)fast_tanh(((float)bq[kk][j] - p0) * p1);
    }
  }
  float dsum = 0.f, dsq = 0.f, ss = 0.f;
  const int ob0 = blockIdx.y * OBS;
#pragma unroll
  for (int obb = 0; obb < OBS; ++obb) {
    const int ob = ob0 + obb;
    f32x4_t acc = {0.f, 0.f, 0.f, 0.f};
    const __bf16* ar = A + (size_t)(ob * 16 + l15) * K + ks * 8;
#pragma unroll
    for (int kk = 0; kk < KK; ++kk) {
      bf16x8_t a = *(const bf16x8_t*)(ar + kk * 32);
      acc = __builtin_amdgcn_mfma_f32_16x16x32_bf16(a, bq[kk], acc, 0, 0, 0);
    }
    const int ro = ob * 16 + ks * 4;
    float v[4] = {acc[0], acc[1], acc[2], acc[3]};
    if constexpr (OM == 1 || OM == 2) {
#pragma unroll
      for (int r = 0; r < 4; ++r) v[r] += bias[ro + r];
    }
    if constexpr (OM == 1) {
#pragma unroll
      for (int r = 0; r < 4; ++r) v[r] = v[r] > 0.f ? v[r] : expm1f(v[r]);
    }
    if constexpr (STATS) {
#pragma unroll
      for (int r = 0; r < 4; ++r) { dsum += v[r]; dsq += v[r] * v[r]; }
    }
    if constexpr (OM == 4) {
      float4* rp = (float4*)&resid[(size_t)n * 128 + ro];
      float4 rr = *rp;
      rr.x += 0.1f * v[0]; rr.y += 0.1f * v[1]; rr.z += 0.1f * v[2]; rr.w += 0.1f * v[3];
      *rp = rr;
      if constexpr (EMITB) {
        bf16x4_t eb;
        eb[0] = (__bf16)rr.x; eb[1] = (__bf16)rr.y; eb[2] = (__bf16)rr.z; eb[3] = (__bf16)rr.w;
        *(bf16x4_t*)(xbout + (size_t)n * 128 + ro) = eb;
#pragma unroll
        for (int r = 0; r < 4; ++r) { float f = (float)eb[r]; ss += f * f; }
      }
    } else if constexpr (OM == 2 || OM == 3) {
      float4 fv = {v[0], v[1], v[2], v[3]};
      *(float4*)(Cf + (size_t)n * nout_stride + ro) = fv;
      if constexpr (EMITB) {
        bf16x4_t eb;
        eb[0] = (__bf16)v[0]; eb[1] = (__bf16)v[1]; eb[2] = (__bf16)v[2]; eb[3] = (__bf16)v[3];
        *(bf16x4_t*)(xbout + (size_t)n * 128 + ro) = eb;
#pragma unroll
        for (int r = 0; r < 4; ++r) { float f = (float)eb[r]; ss += f * f; }
      }
    } else {
      bf16x4_t bv;
      bv[0] = (__bf16)v[0]; bv[1] = (__bf16)v[1]; bv[2] = (__bf16)v[2]; bv[3] = (__bf16)v[3];
      *(bf16x4_t*)(Cb + (size_t)n * nout_stride + ro) = bv;
    }
  }
  if constexpr (EMITB) {
    ss += __shfl_xor(ss, 16);
    ss += __shfl_xor(ss, 32);
    if (lane < 16) shout[blockIdx.y * NNODES + n] = ss;
  }
  if constexpr (STATS)
    write_stats(dsum, dsq, partials, blockIdx.y * gridDim.x + blockIdx.x, tid, 4);
}

// ================= dstat via MFMA Gram matrix, triangular 1-D grid (2080 blocks) =================
__global__ __launch_bounds__(256) void dstat_k(
    const __bf16* __restrict__ fT, const float* __restrict__ sh,
    float2* __restrict__ partials)
{
  int rem = blockIdx.x, i0t = 0;
  while (rem >= 64 - i0t) { rem -= 64 - i0t; ++i0t; }
  const int i0 = i0t * 64, j0 = (i0t + rem) * 64;
  const float wgt = (j0 > i0) ? 2.f : 1.f;
  const int tid = threadIdx.x;
  const int wv = tid >> 6, lane = tid & 63, l15 = lane & 15, ks = lane >> 4;
  const int irow = i0 + wv * 16 + l15;
  bf16x8_t aq[4];
  const __bf16* ar = fT + (size_t)irow * 128 + ks * 8;
#pragma unroll
  for (int kk = 0; kk < 4; ++kk) aq[kk] = *(const bf16x8_t*)(ar + kk * 32);
  float si[4];
#pragma unroll
  for (int r = 0; r < 4; ++r) {
    int ii = i0 + wv * 16 + ks * 4 + r;
    si[r] = sh[ii] + sh[NNODES + ii];
  }
  float dsum = 0.f, dsq = 0.f;
#pragma unroll
  for (int jb = 0; jb < 4; ++jb) {
    const int jcol = j0 + jb * 16 + l15;
    const __bf16* br = fT + (size_t)jcol * 128 + ks * 8;
    f32x4_t acc = {0.f, 0.f, 0.f, 0.f};
#pragma unroll
    for (int kk = 0; kk < 4; ++kk) {
      bf16x8_t b = *(const bf16x8_t*)(br + kk * 32);
      acc = __builtin_amdgcn_mfma_f32_16x16x32_bf16(aq[kk], b, acc, 0, 0, 0);
    }
    const float sj = sh[jcol] + sh[NNODES + jcol];
#pragma unroll
    for (int r = 0; r < 4; ++r) {
      float d = si[r] + sj - 2.f * acc[r];
      d = d > 0.f ? d : 0.f;
      dsum += d; dsq += d * d;
    }
  }
  write_stats(dsum * wgt, dsq * wgt, partials, blockIdx.x, tid, 4);
}

// ================= transpose src [64][ncols] f32 -> dst [ncols][64] bf16 =================
__global__ __launch_bounds__(256) void etrans_k(const float* __restrict__ src,
                                                __bf16* __restrict__ dst, int ncols)
{
  __shared__ float t[64][65];
  const int e0 = blockIdx.x * 64;
  const int tx = threadIdx.x & 63, tw = threadIdx.x >> 6;
  for (int c = tw; c < 64; c += 4)
    t[tx][c] = src[(size_t)c * ncols + e0 + tx];
  __syncthreads();
  const int el = threadIdx.x >> 2, c0 = (threadIdx.x & 3) * 16;
  for (int q = 0; q < 4; ++q) {
    int c = c0 + q * 4;
    bf16x4_t b;
    b[0] = (__bf16)t[el][c];     b[1] = (__bf16)t[el][c + 1];
    b[2] = (__bf16)t[el][c + 2]; b[3] = (__bf16)t[el][c + 3];
    *(bf16x4_t*)&dst[(size_t)(e0 + el) * 64 + c] = b;
  }
}

// ================= weight conversion to bf16 (one launch) =================
__global__ void wcvt_k(const float* __restrict__ K1E, const float* __restrict__ K2E,
                       const float* __restrict__ KE1, const float* __restrict__ KE2,
                       const float* __restrict__ KNc, const float* __restrict__ W1,
                       const float* __restrict__ W2, const float* __restrict__ KN1,
                       const float* __restrict__ KN2, const float* __restrict__ K1N,
                       const float* __restrict__ K2N,
                       __bf16* __restrict__ K1Eb, __bf16* __restrict__ K2Eb,
                       __bf16* __restrict__ KE1b, __bf16* __restrict__ KE2b,
                       __bf16* __restrict__ KNcb, __bf16* __restrict__ W1b,
                       __bf16* __restrict__ W2b, __bf16* __restrict__ KN1b,
                       __bf16* __restrict__ KN2b, __bf16* __restrict__ a1a2b,
                       __bf16* __restrict__ K1Nb, __bf16* __restrict__ K2Nb)
{
  int id = blockIdx.x * 256 + threadIdx.x;
  if (id < 8192) { K1Eb[id] = (__bf16)K1E[id]; return; }
  id -= 8192;
  if (id < 16384) { K2Eb[id] = (__bf16)K2E[id]; return; }
  id -= 16384;
  if (id < 65536) {
    int l = id >> 14, rem = id & 16383, r = rem >> 7, c = rem & 127;
    KE1b[id] = (__bf16)KE1[(size_t)l * 49152 + r * 384 + 128 + c];
    return;
  }
  id -= 65536;
  if (id < 65536) { KE2b[id] = (__bf16)KE2[id]; return; }
  id -= 65536;
  if (id < 16384) { KNcb[id] = (__bf16)KNc[id]; return; }
  id -= 16384;
  if (id < 32768) { W1b[id] = (__bf16)W1[id]; return; }
  id -= 32768;
  if (id < 262144) { W2b[id] = (__bf16)W2[id]; return; }
  id -= 262144;
  if (id < 196608) { KN1b[id] = (__bf16)KN1[id]; return; }
  id -= 196608;
  if (id < 65536) { KN2b[id] = (__bf16)KN2[id]; return; }
  id -= 65536;
  if (id < 131072) {
    int l = id >> 15, rem = id & 32767, r = rem >> 7, c = rem & 127;
    int o = r & 127;
    float k1 = KE1[(size_t)l * 49152 + o * 384 + c];
    float k3 = KE1[(size_t)l * 49152 + o * 384 + 256 + c];
    a1a2b[id] = (__bf16)((r < 128) ? (0.5f * k1 + k3) : (0.5f * k1 - k3));
    return;
  }
  id -= 131072;
  if (id < 8192) { K1Nb[id] = (__bf16)K1N[id]; return; }
  id -= 8192;
  if (id < 16384) { K2Nb[id] = (__bf16)K2N[id]; return; }
}

// ================= lnres: xeT = bf16(f32(xeT) + 0.1*ln(eB)) =================
__global__ __launch_bounds__(256) void lnres_k(
    const __bf16* __restrict__ eBT, __bf16* __restrict__ xeT,
    const float2* __restrict__ pp, int pnblk)
{
  const size_t base = (size_t)blockIdx.x * (256 * 16);
  const size_t i0 = base + (size_t)threadIdx.x * 8;
  const size_t i1 = i0 + 2048;
  // hoisted loads
  bf16x8_t b0 = *(const bf16x8_t*)(eBT + i0);
  bf16x8_t x0 = *(const bf16x8_t*)(xeT + i0);
  bf16x8_t b1 = *(const bf16x8_t*)(eBT + i1);
  bf16x8_t x1 = *(const bf16x8_t*)(xeT + i1);
  float2 pr = params_inline(pp, pnblk, (double)CH * NEDGES, 0);
  const float m = pr.x, r = pr.y;
  bf16x8_t o0, o1;
#pragma unroll
  for (int j = 0; j < 8; ++j) {
    o0[j] = (__bf16)((float)x0[j] + 0.1f * (((float)b0[j] - m) * r));
    o1[j] = (__bf16)((float)x1[j] + 0.1f * (((float)b1[j] - m) * r));
  }
  *(bf16x8_t*)(xeT + i0) = o0;
  *(bf16x8_t*)(xeT + i1) = o1;
}

// ================= CSR build =================
__global__ void hist_k(const int* __restrict__ iI, const int* __restrict__ jJ,
                       int* __restrict__ cnt)
{
  int e = blockIdx.x * 256 + threadIdx.x;
  atomicAdd(&cnt[iI[e]], 1);
  atomicAdd(&cnt[jJ[e]], 1);
}

__global__ __launch_bounds__(1024) void scan_k(const int* __restrict__ cnt,
                                               int* __restrict__ offs,
                                               int* __restrict__ cursor)
{
  __shared__ int tmp[1024];
  const int tid = threadIdx.x;
  int4 v = *(const int4*)&cnt[tid * 4];
  int s = v.x + v.y + v.z + v.w;
  tmp[tid] = s; __syncthreads();
  for (int d = 1; d < 1024; d <<= 1) {
    int t = (tid >= d) ? tmp[tid - d] : 0;
    __syncthreads();
    tmp[tid] += t;
    __syncthreads();
  }
  int base = tmp[tid] - s;
  int4 o = {base, base + v.x, base + v.x + v.y, base + v.x + v.y + v.z};
  *(int4*)&offs[tid * 4] = o;
  *(int4*)&cursor[tid * 4] = o;
  if (tid == 1023) offs[4096] = tmp[1023];
}

__global__ void fill_k(const int* __restrict__ iI, const int* __restrict__ jJ,
                       int* __restrict__ cursor, int* __restrict__ list)
{
  int e = blockIdx.x * 256 + threadIdx.x;
  int p1 = atomicAdd(&cursor[iI[e]], 1);
  list[p1] = e;
  int p2 = atomicAdd(&cursor[jJ[e]], 1);
  list[p2] = e | 0x80000000;
}

// ================= gather: 8 waves, 2 per node (incidence-split) -> catb bf16 [n][256] =================
__global__ __launch_bounds__(512) void gather_k(
    const __bf16* __restrict__ xeT, const float* __restrict__ w,
    const int* __restrict__ offs, const int* __restrict__ list,
    __bf16* __restrict__ catb)
{
  __shared__ float comb[4][4][64];
  const int wv = threadIdx.x >> 6, lane = threadIdx.x & 63;
  const int nn = wv >> 1, half = wv & 1;
  const int n = blockIdx.x * 4 + nn;
  const int k0 = offs[n], k1 = offs[n + 1];
  float s1a = 0.f, s1b = 0.f, s2a = 0.f, s2b = 0.f;
#pragma unroll 2
  for (int k = k0 + half; k < k1; k += 2) {
    int enc = list[k];
    int e = enc & 0x7fffffff;
    float we = w[e];
    bf16x2_t xv = *(const bf16x2_t*)&xeT[(size_t)e * 128 + lane * 2];
    float va = (float)xv[0] * we;
    float vb = (float)xv[1] * we;
    if (enc >= 0) { s1a += va; s1b += vb; }
    else          { s2a += va; s2b += vb; }
  }
  if (half == 1) {
    comb[nn][0][lane] = s1a; comb[nn][1][lane] = s1b;
    comb[nn][2][lane] = s2a; comb[nn][3][lane] = s2b;
  }
  __syncthreads();
  if (half == 0) {
    s1a += comb[nn][0][lane]; s1b += comb[nn][1][lane];
    s2a += comb[nn][2][lane]; s2b += comb[nn][3][lane];
    __bf16* row = catb + (size_t)n * 256;
    bf16x2_t av, dv;
    av[0] = (__bf16)(0.5f * (s1a + s2a)); av[1] = (__bf16)(0.5f * (s1b + s2b));
    dv[0] = (__bf16)(s1a - s2a);          dv[1] = (__bf16)(s1b - s2b);
    *(bf16x2_t*)&row[lane * 2] = av;
    *(bf16x2_t*)&row[128 + lane * 2] = dv;
  }
}

// ================= log_softmax rows of [N][1024] =================
__global__ __launch_bounds__(256) void logsoftmax_k(float* __restrict__ out)
{
  __shared__ float red[256];
  const int n = blockIdx.x, tid = threadIdx.x;
  float* row = out + (size_t)n * 1024;
  float v[4];
  float mx = -1e30f;
#pragma unroll
  for (int l = 0; l < 4; ++l) { v[l] = row[tid + 256 * l]; mx = fmaxf(mx, v[l]); }
  red[tid] = mx; __syncthreads();
  for (int s = 128; s > 0; s >>= 1) { if (tid < s) red[tid] = fmaxf(red[tid], red[tid + s]); __syncthreads(); }
  float m = red[0]; __syncthreads();
  float se = 0.f;
#pragma unroll
  for (int l = 0; l < 4; ++l) se += expf(v[l] - m);
  red[tid] = se; __syncthreads();
  for (int s = 128; s > 0; s >>= 1) { if (tid < s) red[tid] += red[tid + s]; __syncthreads(); }
  float L = m + logf(red[0]);
#pragma unroll
  for (int l = 0; l < 4; ++l) row[tid + 256 * l] = v[l] - L;
}

extern "C" void kernel_launch(void* const* d_in, const int* in_sizes, int n_in,
                              void* d_out, int out_size, void* d_ws, size_t ws_size,
                              hipStream_t stream)
{
  (void)in_sizes; (void)n_in; (void)out_size; (void)ws_size;
  const float* xn_in = (const float*)d_in[0];
  const float* xe_in = (const float*)d_in[1];
  const int*   iI    = (const int*)d_in[2];
  const int*   jJ    = (const int*)d_in[3];
  const float* K1N   = (const float*)d_in[4];
  const float* K2N   = (const float*)d_in[5];
  const float* K1E   = (const float*)d_in[6];
  const float* K2E   = (const float*)d_in[7];
  const float* KNc   = (const float*)d_in[8];
  const float* KE1   = (const float*)d_in[9];
  const float* KE2   = (const float*)d_in[10];
  const float* KN1   = (const float*)d_in[11];
  const float* KN2   = (const float*)d_in[12];
  const float* W1    = (const float*)d_in[13];
  const float* b1    = (const float*)d_in[14];
  const float* W2    = (const float*)d_in[15];
  const float* b2    = (const float*)d_in[16];
  float* out = (float*)d_out;

  float* ws = (float*)d_ws;
  size_t off = 0;
  auto alloc = [&](size_t n) { size_t o = off; off += (n + 63) & ~(size_t)63; return o; };
  float* xnN   = ws + alloc((size_t)NNODES * CH);                  // f32 node-major master
  __bf16* xeT  = (__bf16*)(ws + alloc((size_t)NEDGES * CH / 2));   // bf16 edge state
  __bf16* eAT  = (__bf16*)(ws + alloc((size_t)NEDGES * CH / 2));
  __bf16* eBT  = (__bf16*)(ws + alloc((size_t)NEDGES * CH / 2));
  float* sbufh = ws + alloc(2 * NNODES);                           // sqnorm halves
  float* wbuf  = ws + alloc(NEDGES);
  __bf16* UVb  = (__bf16*)(ws + alloc((size_t)NNODES * 256 / 2));
  __bf16* xnNb = (__bf16*)(ws + alloc((size_t)NNODES * CH / 2));
  __bf16* catb = (__bf16*)(ws + alloc((size_t)NNODES * 256 / 2));
  __bf16* nAb  = (__bf16*)(ws + alloc((size_t)NNODES * CH / 2));
  __bf16* zb   = (__bf16*)(ws + alloc((size_t)NNODES * CH / 2));
  __bf16* l1bb = (__bf16*)(ws + alloc((size_t)NNODES * 256 / 2));
  __bf16* K1Eb = (__bf16*)(ws + alloc(8192 / 2));
  __bf16* K2Eb = (__bf16*)(ws + alloc(16384 / 2));
  __bf16* KE1b = (__bf16*)(ws + alloc(65536 / 2));
  __bf16* KE2b = (__bf16*)(ws + alloc(65536 / 2));
  __bf16* KNcb = (__bf16*)(ws + alloc(16384 / 2));
  __bf16* W1b  = (__bf16*)(ws + alloc(32768 / 2));
  __bf16* W2b  = (__bf16*)(ws + alloc(262144 / 2));
  __bf16* KN1b = (__bf16*)(ws + alloc(196608 / 2));
  __bf16* KN2b = (__bf16*)(ws + alloc(65536 / 2));
  __bf16* a1a2b= (__bf16*)(ws + alloc(131072 / 2));
  __bf16* K1Nb = (__bf16*)(ws + alloc(8192 / 2));
  __bf16* K2Nb = (__bf16*)(ws + alloc(16384 / 2));
  int* csr_cnt    = (int*)(ws + alloc(4096));
  int* csr_offs   = (int*)(ws + alloc(4160));
  int* csr_cursor = (int*)(ws + alloc(4096));
  int* csr_list   = (int*)(ws + alloc(2 * NEDGES));
  float2* pA = (float2*)(ws + alloc((size_t)4096 * 2));
  float2* pB = (float2*)(ws + alloc((size_t)4096 * 2));
  float2* pC = (float2*)(ws + alloc((size_t)4096 * 2));
  // aliases (lifetimes disjoint): opening-only transposed inputs
  __bf16* xeT64  = eBT;               // [E][64], eBT first written layer-0 emfma pass 2
  __bf16* xnT64b = UVb;               // [N][64], UVb first written layer-0 UV kernel

  const __bf16* BNUL = nullptr;
  const float* NUL = nullptr;
  const int* NULI = nullptr;
  const float2* PNUL = nullptr;
  __bf16* BNULm = nullptr;
  float* NULm = nullptr;
  float* FNULm = nullptr;

  // ---- weight conversion + CSR build (once) ----
  wcvt_k<<<3456, 256, 0, stream>>>(K1E, K2E, KE1, KE2, KNc, W1, W2, KN1, KN2, K1N, K2N,
                                   K1Eb, K2Eb, KE1b, KE2b, KNcb, W1b, W2b, KN1b, KN2b,
                                   a1a2b, K1Nb, K2Nb);
  hipMemsetAsync(csr_cnt, 0, 4096 * sizeof(int), stream);
  hist_k<<<NEDGES / 256, 256, 0, stream>>>(iI, jJ, csr_cnt);
  scan_k<<<1, 1024, 0, stream>>>(csr_cnt, csr_offs, csr_cursor);
  fill_k<<<NEDGES / 256, 256, 0, stream>>>(iI, jJ, csr_cursor, csr_list);

  // ---- opening: node double layer (MFMA, node-major, emits xnNb + sqnorm) ----
  etrans_k<<<NNODES / 64, 256, 0, stream>>>(xn_in, xnT64b, NNODES);
  nmfma_k<64, false, false, true, 0, false, 1><<<dim3(64, 8), 256, 0, stream>>>(
      K1Nb, xnT64b, BNUL, nAb, nullptr, nullptr, NUL, 128, pA, PNUL, 0, 0.0, BNULm, NULm);
  nmfma_k<128, false, true, false, 3, true, 4><<<dim3(64, 2), 256, 0, stream>>>(
      K2Nb, nAb, BNUL, nullptr, xnN, nullptr, NUL, 128, nullptr,
      pA, 512, (double)CH * NNODES, xnNb, sbufh);

  // ---- opening: edge double layer (MFMA, ob-split y=2) ----
  etrans_k<<<NEDGES / 64, 256, 0, stream>>>(xe_in, xeT64, NEDGES);
  emfma_k<0, 64, 4, false><<<dim3(NEDGES / 64, 2), 256, 0, stream>>>(
      K1Eb, xeT64, eAT, pA, BNUL, BNUL, NUL, NULI, NULI, FNULm, PNUL, PNUL, 0, 0.0);
  emfma_k<3, 128, 4, false><<<dim3(NEDGES / 64, 2), 256, 0, stream>>>(
      K2Eb, eAT, xeT, nullptr, BNUL, BNUL, NUL, NULI, NULI, FNULm, PNUL,
      pA, 2048, (double)CH * NEDGES);

  for (int i = 0; i < 4; ++i) {
    const __bf16* KE1bi = KE1b + (size_t)i * 128 * 128;
    const __bf16* KE2bi = KE2b + (size_t)i * 128 * 128;
    const __bf16* KN1bi = KN1b + (size_t)i * 128 * 384;
    const __bf16* KN2bi = KN2b + (size_t)i * 128 * 128;
    const __bf16* a1a2i = a1a2b + (size_t)i * 256 * 128;

    // D statistics -> pA
    dstat_k<<<2080, 256, 0, stream>>>(xnNb, sbufh, pA);

    // UVb[n][256] = xnNb @ a1a2^T (bf16 out)
    nmfma_k<128, false, false, false, 0, false, 1><<<dim3(64, 16), 256, 0, stream>>>(
        a1a2i, xnNb, BNUL, UVb, nullptr, nullptr, NUL, 256, nullptr, PNUL, 0, 0.0, BNULm, NULm);

    // edge pass 1 (w inline from pA): eA = xe @ KE1^T + w*(U_I+V_J), stats -> pB
    emfma_k<2, 128, 4, true><<<dim3(NEDGES / 64, 2), 256, 0, stream>>>(
        KE1bi, xeT, eAT, pB, UVb, xnNb, sbufh, iI, jJ, wbuf, pA, PNUL, 0, 0.0);
    // edge pass 2: eB = tanh(ln(eA)) @ KE2^T, params<-pB, stats -> pC
    emfma_k<1, 128, 4, false><<<dim3(NEDGES / 64, 2), 256, 0, stream>>>(
        KE2bi, eAT, eBT, pC, BNUL, BNUL, NUL, NULI, NULI, FNULm, PNUL,
        pB, 2048, (double)CH * NEDGES);
    // xe += 0.1 * ln(eB), params<-pC
    lnres_k<<<2048, 256, 0, stream>>>(eBT, xeT, pC, 2048);

    // node update: gather -> catb; KN1 (split cat+xn) stats -> pB; KN2 tanh + resid + emit
    gather_k<<<NNODES / 4, 512, 0, stream>>>(xeT, wbuf, csr_offs, csr_list, catb);
    nmfma_k<384, true, false, true, 0, false, 1><<<dim3(64, 8), 256, 0, stream>>>(
        KN1bi, catb, xnNb, nAb, nullptr, nullptr, NUL, 128, pB, PNUL, 0, 0.0, BNULm, NULm);
    nmfma_k<128, false, true, false, 4, true, 4><<<dim3(64, 2), 256, 0, stream>>>(
        KN2bi, nAb, BNUL, nullptr, nullptr, xnN, NUL, 128, nullptr,
        pB, 512, (double)CH * NNODES, xnNb, sbufh);
  }

  // ---- close + MLP head (bf16 MFMA, node-major) ----
  nmfma_k<128, false, false, false, 0, false, 1><<<dim3(64, 8), 256, 0, stream>>>(
      KNcb, xnNb, BNUL, zb, nullptr, nullptr, NUL, 128, nullptr, PNUL, 0, 0.0, BNULm, NULm);
  nmfma_k<128, false, false, false, 1, false, 1><<<dim3(64, 16), 256, 0, stream>>>(
      W1b, zb, BNUL, l1bb, nullptr, nullptr, b1, 256, nullptr, PNUL, 0, 0.0, BNULm, NULm);
  nmfma_k<256, false, false, false, 2, false, 1><<<dim3(64, 64), 256, 0, stream>>>(
      W2b, l1bb, BNUL, nullptr, out, nullptr, b2, 1024, nullptr, PNUL, 0, 0.0, BNULm, NULm);
  logsoftmax_k<<<NNODES, 256, 0, stream>>>(out);
}

// Round 12
// 666.439 us; speedup vs baseline: 2.3028x; 1.0149x over previous
//
#include <hip/hip_runtime.h>

#define NNODES 4096
#define NEDGES 65536
#define CH 128

typedef __bf16 bf16x8_t __attribute__((ext_vector_type(8)));
typedef __bf16 bf16x4_t __attribute__((ext_vector_type(4)));
typedef __bf16 bf16x2_t __attribute__((ext_vector_type(2)));
typedef float f32x4_t __attribute__((ext_vector_type(4)));

// ---- fast tanh via hw exp2/rcp ----
__device__ __forceinline__ float fast_tanh(float x)
{
  float t = __builtin_amdgcn_exp2f(x * 2.885390081777927f);   // 2*log2(e)
  return 1.f - 2.f * __builtin_amdgcn_rcpf(t + 1.f);
}

// ---- block stats writer: f32 wave shfl-reduce, one float2 per block ----
__device__ __forceinline__ void write_stats(float s, float q, float2* __restrict__ partials,
                                            int pid, int tid, int nwaves)
{
#pragma unroll
  for (int d = 1; d < 64; d <<= 1) { s += __shfl_xor(s, d); q += __shfl_xor(q, d); }
  __shared__ float rs[8][2];
  const int wv = tid >> 6, lane = tid & 63;
  if (lane == 0) { rs[wv][0] = s; rs[wv][1] = q; }
  __syncthreads();
  if (tid == 0) {
    float S = 0.f, Q = 0.f;
    for (int i = 0; i < nwaves; ++i) { S += rs[i][0]; Q += rs[i][1]; }
    partials[pid] = {S, Q};
  }
}

// ---- inline params: f64 cross-block reduce of f32 partials -> (mean,rstd) or (factor,0) ----
__device__ __forceinline__ float2 params_inline(const float2* __restrict__ pp,
                                                int nblk, double M, int type)
{
  const int tid = threadIdx.x;
  double s = 0.0, q = 0.0;
  for (int i = tid; i < nblk; i += 256) { float2 v = pp[i]; s += (double)v.x; q += (double)v.y; }
#pragma unroll
  for (int d = 1; d < 64; d <<= 1) { s += __shfl_xor(s, d); q += __shfl_xor(q, d); }
  __shared__ double rs4[4], rq4[4];
  __shared__ float pr[2];
  const int wv = tid >> 6, lane = tid & 63;
  if (lane == 0) { rs4[wv] = s; rq4[wv] = q; }
  __syncthreads();
  if (tid == 0) {
    double S = rs4[0] + rs4[1] + rs4[2] + rs4[3];
    double Q = rq4[0] + rq4[1] + rq4[2] + rq4[3];
    if (type == 0) {
      double mean = S / M;
      double var = Q / M - mean * mean;
      if (var < 0.0) var = 0.0;
      pr[0] = (float)mean;
      pr[1] = (float)(1.0 / sqrt(var + 1e-5));
    } else {
      double var = (Q - S * S / M) / (M - 1.0);
      if (var < 1e-30) var = 1e-30;
      pr[0] = (float)(-2.0 / sqrt(var));
      pr[1] = 0.f;
    }
  }
  __syncthreads();
  return {pr[0], pr[1]};
}

// ================= bf16 MFMA edge GEMM: EPB edge-groups (64 each) per block =================
// grid (E/(64*EPB), 8/OBS). EM 0: plain, stats   EM 2: + w*(U[I]+V[J]), stats (WPH inline w)
// EM 1: tanh-on-load, stats   EM 3: tanh-on-load, no stats
template<int EM, int K, int OBS, bool WPH, int EPB>
__global__ __launch_bounds__(256) void emfma_k(
    const __bf16* __restrict__ A, const __bf16* __restrict__ X,
    __bf16* __restrict__ Cb,
    float2* __restrict__ partials,
    const __bf16* __restrict__ UVb, const __bf16* __restrict__ xnNb,
    const float* __restrict__ sbufh,
    const int* __restrict__ iI, const int* __restrict__ jJ,
    float* __restrict__ wbuf, const float2* __restrict__ pD,
    const float2* __restrict__ pp, int pnblk, double pM)
{
  __shared__ float wl[64 * EPB];
  __shared__ int il[64 * EPB], jl[64 * EPB];
  const int tid = threadIdx.x;
  const int wv = tid >> 6, lane = tid & 63;
  const int l15 = lane & 15, ks = lane >> 4;
  const int row = wv * 16 + l15;
  const int base_e = blockIdx.x * 64 * EPB;
  constexpr int KK = K / 32;
  // hoisted raw X loads for all groups
  bf16x8_t bq[EPB][KK];
#pragma unroll
  for (int g = 0; g < EPB; ++g) {
    const __bf16* xr = X + (size_t)(base_e + g * 64 + row) * K + ks * 8;
#pragma unroll
    for (int kk = 0; kk < KK; ++kk) bq[g][kk] = *(const bf16x8_t*)(xr + kk * 32);
  }
  if constexpr (WPH) {
    static_assert(EPB == 4, "WPH assumes 256 edges/block");
    // pD cross-block reduce overlapped with per-thread edge-weight dot (1 thread : 1 edge)
    double s = 0.0, q = 0.0;
    for (int i = tid; i < 2080; i += 256) { float2 v = pD[i]; s += (double)v.x; q += (double)v.y; }
    const int eg = base_e + tid;
    const int a = iI[eg], b = jJ[eg];
    il[tid] = a; jl[tid] = b;
    const bf16x8_t* pa = (const bf16x8_t*)(xnNb + (size_t)a * CH);
    const bf16x8_t* pb = (const bf16x8_t*)(xnNb + (size_t)b * CH);
    float g0 = 0.f, g1 = 0.f, g2 = 0.f, g3 = 0.f;
#pragma unroll
    for (int q16 = 0; q16 < 16; q16 += 4) {
      bf16x8_t u0 = pa[q16],     v0 = pb[q16];
      bf16x8_t u1 = pa[q16 + 1], v1 = pb[q16 + 1];
      bf16x8_t u2 = pa[q16 + 2], v2 = pb[q16 + 2];
      bf16x8_t u3 = pa[q16 + 3], v3 = pb[q16 + 3];
#pragma unroll
      for (int j = 0; j < 8; ++j) {
        g0 = fmaf((float)u0[j], (float)v0[j], g0);
        g1 = fmaf((float)u1[j], (float)v1[j], g1);
        g2 = fmaf((float)u2[j], (float)v2[j], g2);
        g3 = fmaf((float)u3[j], (float)v3[j], g3);
      }
    }
    float gg = (g0 + g1) + (g2 + g3);
    float dd = sbufh[a] + sbufh[NNODES + a] + sbufh[b] + sbufh[NNODES + b] - 2.f * gg;
    dd = dd > 0.f ? dd : 0.f;
#pragma unroll
    for (int d = 1; d < 64; d <<= 1) { s += __shfl_xor(s, d); q += __shfl_xor(q, d); }
    __shared__ double rs4[4], rq4[4];
    __shared__ float prf;
    if (lane == 0) { rs4[wv] = s; rq4[wv] = q; }
    __syncthreads();
    if (tid == 0) {
      double S = rs4[0] + rs4[1] + rs4[2] + rs4[3];
      double Q = rq4[0] + rq4[1] + rq4[2] + rq4[3];
      const double M = (double)NNODES * (double)NNODES;
      double var = (Q - S * S / M) / (M - 1.0);
      if (var < 1e-30) var = 1e-30;
      prf = (float)(-2.0 / sqrt(var));
    }
    __syncthreads();
    float wgt = __builtin_amdgcn_exp2f(prf * dd * 1.4426950408889634f);
    wl[tid] = wgt;
    if (blockIdx.y == 0) wbuf[eg] = wgt;
    __syncthreads();
  }
  if constexpr (EM == 1 || EM == 3) {
    float2 pr = params_inline(pp, pnblk, pM, 0);
    const float p0 = pr.x, p1 = pr.y;
#pragma unroll
    for (int g = 0; g < EPB; ++g)
#pragma unroll
      for (int kk = 0; kk < KK; ++kk) {
#pragma unroll
        for (int j = 0; j < 8; ++j)
          bq[g][kk][j] = (__bf16)fast_tanh(((float)bq[g][kk][j] - p0) * p1);
      }
  }
  float dsum = 0.f, dsq = 0.f;
  const int ob0 = blockIdx.y * OBS;
#pragma unroll
  for (int g = 0; g < EPB; ++g) {
    const int e = base_e + g * 64 + row;
    float we = 0.f; int ie = 0, je = 0;
    if constexpr (EM == 2) { we = wl[g * 64 + row]; ie = il[g * 64 + row]; je = jl[g * 64 + row]; }
#pragma unroll
    for (int obb = 0; obb < OBS; ++obb) {
      const int ob = ob0 + obb;
      f32x4_t acc = {0.f, 0.f, 0.f, 0.f};
      const __bf16* ar = A + (size_t)(ob * 16 + l15) * K + ks * 8;
#pragma unroll
      for (int kk = 0; kk < KK; ++kk) {
        bf16x8_t a = *(const bf16x8_t*)(ar + kk * 32);
        acc = __builtin_amdgcn_mfma_f32_16x16x32_bf16(a, bq[g][kk], acc, 0, 0, 0);
      }
      const int ro = ob * 16 + ks * 4;
      float v0 = acc[0], v1 = acc[1], v2 = acc[2], v3 = acc[3];
      if constexpr (EM == 2) {
        bf16x4_t u4 = *(const bf16x4_t*)&UVb[(size_t)ie * 256 + ro];
        bf16x4_t w4 = *(const bf16x4_t*)&UVb[(size_t)je * 256 + 128 + ro];
        v0 += we * ((float)u4[0] + (float)w4[0]);
        v1 += we * ((float)u4[1] + (float)w4[1]);
        v2 += we * ((float)u4[2] + (float)w4[2]);
        v3 += we * ((float)u4[3] + (float)w4[3]);
      }
      if constexpr (EM != 3) {
        dsum += v0 + v1 + v2 + v3;
        dsq  += v0 * v0 + v1 * v1 + v2 * v2 + v3 * v3;
      }
      bf16x4_t bv;
      bv[0] = (__bf16)v0; bv[1] = (__bf16)v1; bv[2] = (__bf16)v2; bv[3] = (__bf16)v3;
      *(bf16x4_t*)(Cb + (size_t)e * 128 + ro) = bv;
    }
  }
  if constexpr (EM != 3)
    write_stats(dsum, dsq, partials, blockIdx.y * gridDim.x + blockIdx.x, tid, 4);
}

// ================= bf16 MFMA node GEMM, col-tiled, OBS outs/block =================
// OM 0: bf16 out; 1: +bias elu bf16 out; 2: +bias f32 out; 3: f32 out; 4: resid[n][128] += 0.1*v
template<int K, bool XSPLIT, bool XT, bool STATS, int OM, bool EMITB, int OBS>
__global__ __launch_bounds__(256) void nmfma_k(
    const __bf16* __restrict__ A, const __bf16* __restrict__ X,
    const __bf16* __restrict__ X2,
    __bf16* __restrict__ Cb, float* __restrict__ Cf, float* __restrict__ resid,
    const float* __restrict__ bias, int nout_stride,
    float2* __restrict__ partials,
    const float2* __restrict__ pp, int pnblk, double pM,
    __bf16* __restrict__ xbout, float* __restrict__ shout)
{
  const int tid = threadIdx.x;
  const int wv = tid >> 6, lane = tid & 63;
  const int l15 = lane & 15, ks = lane >> 4;
  const int n = blockIdx.x * 64 + wv * 16 + l15;
  constexpr int KK = K / 32;
  bf16x8_t bq[KK];
  if constexpr (XSPLIT) {
    const __bf16* xr  = X  + (size_t)n * 256 + ks * 8;
    const __bf16* xr2 = X2 + (size_t)n * 128 + ks * 8;
#pragma unroll
    for (int kk = 0; kk < 8; ++kk) bq[kk] = *(const bf16x8_t*)(xr + kk * 32);
#pragma unroll
    for (int kk = 8; kk < KK; ++kk) bq[kk] = *(const bf16x8_t*)(xr2 + (kk - 8) * 32);
  } else {
    const __bf16* xr = X + (size_t)n * K + ks * 8;
#pragma unroll
    for (int kk = 0; kk < KK; ++kk) bq[kk] = *(const bf16x8_t*)(xr + kk * 32);
  }
  if constexpr (XT) {
    float2 pr = params_inline(pp, pnblk, pM, 0);
    const float p0 = pr.x, p1 = pr.y;
#pragma unroll
    for (int kk = 0; kk < KK; ++kk) {
#pragma unroll
      for (int j = 0; j < 8; ++j)
        bq[kk][j] = (__bf16)fast_tanh(((float)bq[kk][j] - p0) * p1);
    }
  }
  float dsum = 0.f, dsq = 0.f, ss = 0.f;
  const int ob0 = blockIdx.y * OBS;
#pragma unroll
  for (int obb = 0; obb < OBS; ++obb) {
    const int ob = ob0 + obb;
    f32x4_t acc = {0.f, 0.f, 0.f, 0.f};
    const __bf16* ar = A + (size_t)(ob * 16 + l15) * K + ks * 8;
#pragma unroll
    for (int kk = 0; kk < KK; ++kk) {
      bf16x8_t a = *(const bf16x8_t*)(ar + kk * 32);
      acc = __builtin_amdgcn_mfma_f32_16x16x32_bf16(a, bq[kk], acc, 0, 0, 0);
    }
    const int ro = ob * 16 + ks * 4;
    float v[4] = {acc[0], acc[1], acc[2], acc[3]};
    if constexpr (OM == 1 || OM == 2) {
#pragma unroll
      for (int r = 0; r < 4; ++r) v[r] += bias[ro + r];
    }
    if constexpr (OM == 1) {
#pragma unroll
      for (int r = 0; r < 4; ++r) v[r] = v[r] > 0.f ? v[r] : expm1f(v[r]);
    }
    if constexpr (STATS) {
#pragma unroll
      for (int r = 0; r < 4; ++r) { dsum += v[r]; dsq += v[r] * v[r]; }
    }
    if constexpr (OM == 4) {
      float4* rp = (float4*)&resid[(size_t)n * 128 + ro];
      float4 rr = *rp;
      rr.x += 0.1f * v[0]; rr.y += 0.1f * v[1]; rr.z += 0.1f * v[2]; rr.w += 0.1f * v[3];
      *rp = rr;
      if constexpr (EMITB) {
        bf16x4_t eb;
        eb[0] = (__bf16)rr.x; eb[1] = (__bf16)rr.y; eb[2] = (__bf16)rr.z; eb[3] = (__bf16)rr.w;
        *(bf16x4_t*)(xbout + (size_t)n * 128 + ro) = eb;
#pragma unroll
        for (int r = 0; r < 4; ++r) { float f = (float)eb[r]; ss += f * f; }
      }
    } else if constexpr (OM == 2 || OM == 3) {
      float4 fv = {v[0], v[1], v[2], v[3]};
      *(float4*)(Cf + (size_t)n * nout_stride + ro) = fv;
      if constexpr (EMITB) {
        bf16x4_t eb;
        eb[0] = (__bf16)v[0]; eb[1] = (__bf16)v[1]; eb[2] = (__bf16)v[2]; eb[3] = (__bf16)v[3];
        *(bf16x4_t*)(xbout + (size_t)n * 128 + ro) = eb;
#pragma unroll
        for (int r = 0; r < 4; ++r) { float f = (float)eb[r]; ss += f * f; }
      }
    } else {
      bf16x4_t bv;
      bv[0] = (__bf16)v[0]; bv[1] = (__bf16)v[1]; bv[2] = (__bf16)v[2]; bv[3] = (__bf16)v[3];
      *(bf16x4_t*)(Cb + (size_t)n * nout_stride + ro) = bv;
    }
  }
  if constexpr (EMITB) {
    ss += __shfl_xor(ss, 16);
    ss += __shfl_xor(ss, 32);
    if (lane < 16) shout[blockIdx.y * NNODES + n] = ss;
  }
  if constexpr (STATS)
    write_stats(dsum, dsq, partials, blockIdx.y * gridDim.x + blockIdx.x, tid, 4);
}

// ================= dstat via MFMA Gram matrix, triangular 1-D grid (2080 blocks) =================
__global__ __launch_bounds__(256) void dstat_k(
    const __bf16* __restrict__ fT, const float* __restrict__ sh,
    float2* __restrict__ partials)
{
  int rem = blockIdx.x, i0t = 0;
  while (rem >= 64 - i0t) { rem -= 64 - i0t; ++i0t; }
  const int i0 = i0t * 64, j0 = (i0t + rem) * 64;
  const float wgt = (j0 > i0) ? 2.f : 1.f;
  const int tid = threadIdx.x;
  const int wv = tid >> 6, lane = tid & 63, l15 = lane & 15, ks = lane >> 4;
  const int irow = i0 + wv * 16 + l15;
  bf16x8_t aq[4];
  const __bf16* ar = fT + (size_t)irow * 128 + ks * 8;
#pragma unroll
  for (int kk = 0; kk < 4; ++kk) aq[kk] = *(const bf16x8_t*)(ar + kk * 32);
  float si[4];
#pragma unroll
  for (int r = 0; r < 4; ++r) {
    int ii = i0 + wv * 16 + ks * 4 + r;
    si[r] = sh[ii] + sh[NNODES + ii];
  }
  float dsum = 0.f, dsq = 0.f;
#pragma unroll
  for (int jb = 0; jb < 4; ++jb) {
    const int jcol = j0 + jb * 16 + l15;
    const __bf16* br = fT + (size_t)jcol * 128 + ks * 8;
    f32x4_t acc = {0.f, 0.f, 0.f, 0.f};
#pragma unroll
    for (int kk = 0; kk < 4; ++kk) {
      bf16x8_t b = *(const bf16x8_t*)(br + kk * 32);
      acc = __builtin_amdgcn_mfma_f32_16x16x32_bf16(aq[kk], b, acc, 0, 0, 0);
    }
    const float sj = sh[jcol] + sh[NNODES + jcol];
#pragma unroll
    for (int r = 0; r < 4; ++r) {
      float d = si[r] + sj - 2.f * acc[r];
      d = d > 0.f ? d : 0.f;
      dsum += d; dsq += d * d;
    }
  }
  write_stats(dsum * wgt, dsq * wgt, partials, blockIdx.x, tid, 4);
}

// ================= transpose src [64][ncols] f32 -> dst [ncols][64] bf16 =================
__global__ __launch_bounds__(256) void etrans_k(const float* __restrict__ src,
                                                __bf16* __restrict__ dst, int ncols)
{
  __shared__ float t[64][65];
  const int e0 = blockIdx.x * 64;
  const int tx = threadIdx.x & 63, tw = threadIdx.x >> 6;
  for (int c = tw; c < 64; c += 4)
    t[tx][c] = src[(size_t)c * ncols + e0 + tx];
  __syncthreads();
  const int el = threadIdx.x >> 2, c0 = (threadIdx.x & 3) * 16;
  for (int q = 0; q < 4; ++q) {
    int c = c0 + q * 4;
    bf16x4_t b;
    b[0] = (__bf16)t[el][c];     b[1] = (__bf16)t[el][c + 1];
    b[2] = (__bf16)t[el][c + 2]; b[3] = (__bf16)t[el][c + 3];
    *(bf16x4_t*)&dst[(size_t)(e0 + el) * 64 + c] = b;
  }
}

// ================= weight conversion to bf16 (one launch) =================
__global__ void wcvt_k(const float* __restrict__ K1E, const float* __restrict__ K2E,
                       const float* __restrict__ KE1, const float* __restrict__ KE2,
                       const float* __restrict__ KNc, const float* __restrict__ W1,
                       const float* __restrict__ W2, const float* __restrict__ KN1,
                       const float* __restrict__ KN2, const float* __restrict__ K1N,
                       const float* __restrict__ K2N,
                       __bf16* __restrict__ K1Eb, __bf16* __restrict__ K2Eb,
                       __bf16* __restrict__ KE1b, __bf16* __restrict__ KE2b,
                       __bf16* __restrict__ KNcb, __bf16* __restrict__ W1b,
                       __bf16* __restrict__ W2b, __bf16* __restrict__ KN1b,
                       __bf16* __restrict__ KN2b, __bf16* __restrict__ a1a2b,
                       __bf16* __restrict__ K1Nb, __bf16* __restrict__ K2Nb)
{
  int id = blockIdx.x * 256 + threadIdx.x;
  if (id < 8192) { K1Eb[id] = (__bf16)K1E[id]; return; }
  id -= 8192;
  if (id < 16384) { K2Eb[id] = (__bf16)K2E[id]; return; }
  id -= 16384;
  if (id < 65536) {
    int l = id >> 14, rem = id & 16383, r = rem >> 7, c = rem & 127;
    KE1b[id] = (__bf16)KE1[(size_t)l * 49152 + r * 384 + 128 + c];
    return;
  }
  id -= 65536;
  if (id < 65536) { KE2b[id] = (__bf16)KE2[id]; return; }
  id -= 65536;
  if (id < 16384) { KNcb[id] = (__bf16)KNc[id]; return; }
  id -= 16384;
  if (id < 32768) { W1b[id] = (__bf16)W1[id]; return; }
  id -= 32768;
  if (id < 262144) { W2b[id] = (__bf16)W2[id]; return; }
  id -= 262144;
  if (id < 196608) { KN1b[id] = (__bf16)KN1[id]; return; }
  id -= 196608;
  if (id < 65536) { KN2b[id] = (__bf16)KN2[id]; return; }
  id -= 65536;
  if (id < 131072) {
    int l = id >> 15, rem = id & 32767, r = rem >> 7, c = rem & 127;
    int o = r & 127;
    float k1 = KE1[(size_t)l * 49152 + o * 384 + c];
    float k3 = KE1[(size_t)l * 49152 + o * 384 + 256 + c];
    a1a2b[id] = (__bf16)((r < 128) ? (0.5f * k1 + k3) : (0.5f * k1 - k3));
    return;
  }
  id -= 131072;
  if (id < 8192) { K1Nb[id] = (__bf16)K1N[id]; return; }
  id -= 8192;
  if (id < 16384) { K2Nb[id] = (__bf16)K2N[id]; return; }
}

// ================= lnres: xeT = bf16(f32(xeT) + 0.1*ln(eB)) =================
__global__ __launch_bounds__(256) void lnres_k(
    const __bf16* __restrict__ eBT, __bf16* __restrict__ xeT,
    const float2* __restrict__ pp, int pnblk)
{
  const size_t base = (size_t)blockIdx.x * (256 * 16);
  const size_t i0 = base + (size_t)threadIdx.x * 8;
  const size_t i1 = i0 + 2048;
  bf16x8_t b0 = *(const bf16x8_t*)(eBT + i0);
  bf16x8_t x0 = *(const bf16x8_t*)(xeT + i0);
  bf16x8_t b1 = *(const bf16x8_t*)(eBT + i1);
  bf16x8_t x1 = *(const bf16x8_t*)(xeT + i1);
  float2 pr = params_inline(pp, pnblk, (double)CH * NEDGES, 0);
  const float m = pr.x, r = pr.y;
  bf16x8_t o0, o1;
#pragma unroll
  for (int j = 0; j < 8; ++j) {
    o0[j] = (__bf16)((float)x0[j] + 0.1f * (((float)b0[j] - m) * r));
    o1[j] = (__bf16)((float)x1[j] + 0.1f * (((float)b1[j] - m) * r));
  }
  *(bf16x8_t*)(xeT + i0) = o0;
  *(bf16x8_t*)(xeT + i1) = o1;
}

// ================= CSR build =================
__global__ void hist_k(const int* __restrict__ iI, const int* __restrict__ jJ,
                       int* __restrict__ cnt)
{
  int e = blockIdx.x * 256 + threadIdx.x;
  atomicAdd(&cnt[iI[e]], 1);
  atomicAdd(&cnt[jJ[e]], 1);
}

__global__ __launch_bounds__(1024) void scan_k(const int* __restrict__ cnt,
                                               int* __restrict__ offs,
                                               int* __restrict__ cursor)
{
  __shared__ int tmp[1024];
  const int tid = threadIdx.x;
  int4 v = *(const int4*)&cnt[tid * 4];
  int s = v.x + v.y + v.z + v.w;
  tmp[tid] = s; __syncthreads();
  for (int d = 1; d < 1024; d <<= 1) {
    int t = (tid >= d) ? tmp[tid - d] : 0;
    __syncthreads();
    tmp[tid] += t;
    __syncthreads();
  }
  int base = tmp[tid] - s;
  int4 o = {base, base + v.x, base + v.x + v.y, base + v.x + v.y + v.z};
  *(int4*)&offs[tid * 4] = o;
  *(int4*)&cursor[tid * 4] = o;
  if (tid == 1023) offs[4096] = tmp[1023];
}

__global__ void fill_k(const int* __restrict__ iI, const int* __restrict__ jJ,
                       int* __restrict__ cursor, int* __restrict__ list)
{
  int e = blockIdx.x * 256 + threadIdx.x;
  int p1 = atomicAdd(&cursor[iI[e]], 1);
  list[p1] = e;
  int p2 = atomicAdd(&cursor[jJ[e]], 1);
  list[p2] = e | 0x80000000;
}

// ================= gather: 8 waves, 2 per node (incidence-split) -> catb bf16 [n][256] =================
__global__ __launch_bounds__(512) void gather_k(
    const __bf16* __restrict__ xeT, const float* __restrict__ w,
    const int* __restrict__ offs, const int* __restrict__ list,
    __bf16* __restrict__ catb)
{
  __shared__ float comb[4][4][64];
  const int wv = threadIdx.x >> 6, lane = threadIdx.x & 63;
  const int nn = wv >> 1, half = wv & 1;
  const int n = blockIdx.x * 4 + nn;
  const int k0 = offs[n], k1 = offs[n + 1];
  float s1a = 0.f, s1b = 0.f, s2a = 0.f, s2b = 0.f;
#pragma unroll 2
  for (int k = k0 + half; k < k1; k += 2) {
    int enc = list[k];
    int e = enc & 0x7fffffff;
    float we = w[e];
    bf16x2_t xv = *(const bf16x2_t*)&xeT[(size_t)e * 128 + lane * 2];
    float va = (float)xv[0] * we;
    float vb = (float)xv[1] * we;
    if (enc >= 0) { s1a += va; s1b += vb; }
    else          { s2a += va; s2b += vb; }
  }
  if (half == 1) {
    comb[nn][0][lane] = s1a; comb[nn][1][lane] = s1b;
    comb[nn][2][lane] = s2a; comb[nn][3][lane] = s2b;
  }
  __syncthreads();
  if (half == 0) {
    s1a += comb[nn][0][lane]; s1b += comb[nn][1][lane];
    s2a += comb[nn][2][lane]; s2b += comb[nn][3][lane];
    __bf16* row = catb + (size_t)n * 256;
    bf16x2_t av, dv;
    av[0] = (__bf16)(0.5f * (s1a + s2a)); av[1] = (__bf16)(0.5f * (s1b + s2b));
    dv[0] = (__bf16)(s1a - s2a);          dv[1] = (__bf16)(s1b - s2b);
    *(bf16x2_t*)&row[lane * 2] = av;
    *(bf16x2_t*)&row[128 + lane * 2] = dv;
  }
}

// ================= log_softmax rows of [N][1024] =================
__global__ __launch_bounds__(256) void logsoftmax_k(float* __restrict__ out)
{
  __shared__ float red[256];
  const int n = blockIdx.x, tid = threadIdx.x;
  float* row = out + (size_t)n * 1024;
  float v[4];
  float mx = -1e30f;
#pragma unroll
  for (int l = 0; l < 4; ++l) { v[l] = row[tid + 256 * l]; mx = fmaxf(mx, v[l]); }
  red[tid] = mx; __syncthreads();
  for (int s = 128; s > 0; s >>= 1) { if (tid < s) red[tid] = fmaxf(red[tid], red[tid + s]); __syncthreads(); }
  float m = red[0]; __syncthreads();
  float se = 0.f;
#pragma unroll
  for (int l = 0; l < 4; ++l) se += expf(v[l] - m);
  red[tid] = se; __syncthreads();
  for (int s = 128; s > 0; s >>= 1) { if (tid < s) red[tid] += red[tid + s]; __syncthreads(); }
  float L = m + logf(red[0]);
#pragma unroll
  for (int l = 0; l < 4; ++l) row[tid + 256 * l] = v[l] - L;
}

extern "C" void kernel_launch(void* const* d_in, const int* in_sizes, int n_in,
                              void* d_out, int out_size, void* d_ws, size_t ws_size,
                              hipStream_t stream)
{
  (void)in_sizes; (void)n_in; (void)out_size; (void)ws_size;
  const float* xn_in = (const float*)d_in[0];
  const float* xe_in = (const float*)d_in[1];
  const int*   iI    = (const int*)d_in[2];
  const int*   jJ    = (const int*)d_in[3];
  const float* K1N   = (const float*)d_in[4];
  const float* K2N   = (const float*)d_in[5];
  const float* K1E   = (const float*)d_in[6];
  const float* K2E   = (const float*)d_in[7];
  const float* KNc   = (const float*)d_in[8];
  const float* KE1   = (const float*)d_in[9];
  const float* KE2   = (const float*)d_in[10];
  const float* KN1   = (const float*)d_in[11];
  const float* KN2   = (const float*)d_in[12];
  const float* W1    = (const float*)d_in[13];
  const float* b1    = (const float*)d_in[14];
  const float* W2    = (const float*)d_in[15];
  const float* b2    = (const float*)d_in[16];
  float* out = (float*)d_out;

  float* ws = (float*)d_ws;
  size_t off = 0;
  auto alloc = [&](size_t n) { size_t o = off; off += (n + 63) & ~(size_t)63; return o; };
  float* xnN   = ws + alloc((size_t)NNODES * CH);                  // f32 node-major master
  __bf16* xeT  = (__bf16*)(ws + alloc((size_t)NEDGES * CH / 2));   // bf16 edge state
  __bf16* eAT  = (__bf16*)(ws + alloc((size_t)NEDGES * CH / 2));
  __bf16* eBT  = (__bf16*)(ws + alloc((size_t)NEDGES * CH / 2));
  float* sbufh = ws + alloc(2 * NNODES);                           // sqnorm halves
  float* wbuf  = ws + alloc(NEDGES);
  __bf16* UVb  = (__bf16*)(ws + alloc((size_t)NNODES * 256 / 2));
  __bf16* xnNb = (__bf16*)(ws + alloc((size_t)NNODES * CH / 2));
  __bf16* catb = (__bf16*)(ws + alloc((size_t)NNODES * 256 / 2));
  __bf16* nAb  = (__bf16*)(ws + alloc((size_t)NNODES * CH / 2));
  __bf16* zb   = (__bf16*)(ws + alloc((size_t)NNODES * CH / 2));
  __bf16* l1bb = (__bf16*)(ws + alloc((size_t)NNODES * 256 / 2));
  __bf16* K1Eb = (__bf16*)(ws + alloc(8192 / 2));
  __bf16* K2Eb = (__bf16*)(ws + alloc(16384 / 2));
  __bf16* KE1b = (__bf16*)(ws + alloc(65536 / 2));
  __bf16* KE2b = (__bf16*)(ws + alloc(65536 / 2));
  __bf16* KNcb = (__bf16*)(ws + alloc(16384 / 2));
  __bf16* W1b  = (__bf16*)(ws + alloc(32768 / 2));
  __bf16* W2b  = (__bf16*)(ws + alloc(262144 / 2));
  __bf16* KN1b = (__bf16*)(ws + alloc(196608 / 2));
  __bf16* KN2b = (__bf16*)(ws + alloc(65536 / 2));
  __bf16* a1a2b= (__bf16*)(ws + alloc(131072 / 2));
  __bf16* K1Nb = (__bf16*)(ws + alloc(8192 / 2));
  __bf16* K2Nb = (__bf16*)(ws + alloc(16384 / 2));
  int* csr_cnt    = (int*)(ws + alloc(4096));
  int* csr_offs   = (int*)(ws + alloc(4160));
  int* csr_cursor = (int*)(ws + alloc(4096));
  int* csr_list   = (int*)(ws + alloc(2 * NEDGES));
  float2* pA = (float2*)(ws + alloc((size_t)4096 * 2));
  float2* pB = (float2*)(ws + alloc((size_t)4096 * 2));
  float2* pC = (float2*)(ws + alloc((size_t)4096 * 2));
  // aliases (lifetimes disjoint): opening-only transposed inputs
  __bf16* xeT64  = eBT;               // [E][64], eBT first written layer-0 emfma pass 2
  __bf16* xnT64b = UVb;               // [N][64], UVb first written layer-0 UV kernel

  const __bf16* BNUL = nullptr;
  const float* NUL = nullptr;
  const int* NULI = nullptr;
  const float2* PNUL = nullptr;
  __bf16* BNULm = nullptr;
  float* NULm = nullptr;
  float* FNULm = nullptr;

  // ---- weight conversion + CSR build (once) ----
  wcvt_k<<<3456, 256, 0, stream>>>(K1E, K2E, KE1, KE2, KNc, W1, W2, KN1, KN2, K1N, K2N,
                                   K1Eb, K2Eb, KE1b, KE2b, KNcb, W1b, W2b, KN1b, KN2b,
                                   a1a2b, K1Nb, K2Nb);
  hipMemsetAsync(csr_cnt, 0, 4096 * sizeof(int), stream);
  hist_k<<<NEDGES / 256, 256, 0, stream>>>(iI, jJ, csr_cnt);
  scan_k<<<1, 1024, 0, stream>>>(csr_cnt, csr_offs, csr_cursor);
  fill_k<<<NEDGES / 256, 256, 0, stream>>>(iI, jJ, csr_cursor, csr_list);

  // ---- opening: node double layer (MFMA, node-major, emits xnNb + sqnorm) ----
  etrans_k<<<NNODES / 64, 256, 0, stream>>>(xn_in, xnT64b, NNODES);
  nmfma_k<64, false, false, true, 0, false, 1><<<dim3(64, 8), 256, 0, stream>>>(
      K1Nb, xnT64b, BNUL, nAb, nullptr, nullptr, NUL, 128, pA, PNUL, 0, 0.0, BNULm, NULm);
  nmfma_k<128, false, true, false, 3, true, 4><<<dim3(64, 2), 256, 0, stream>>>(
      K2Nb, nAb, BNUL, nullptr, xnN, nullptr, NUL, 128, nullptr,
      pA, 512, (double)CH * NNODES, xnNb, sbufh);

  // ---- opening: edge double layer (MFMA, EPB=4, y=2) ----
  etrans_k<<<NEDGES / 64, 256, 0, stream>>>(xe_in, xeT64, NEDGES);
  emfma_k<0, 64, 4, false, 4><<<dim3(NEDGES / 256, 2), 256, 0, stream>>>(
      K1Eb, xeT64, eAT, pA, BNUL, BNUL, NUL, NULI, NULI, FNULm, PNUL, PNUL, 0, 0.0);
  emfma_k<3, 128, 4, false, 4><<<dim3(NEDGES / 256, 2), 256, 0, stream>>>(
      K2Eb, eAT, xeT, nullptr, BNUL, BNUL, NUL, NULI, NULI, FNULm, PNUL,
      pA, 512, (double)CH * NEDGES);

  for (int i = 0; i < 4; ++i) {
    const __bf16* KE1bi = KE1b + (size_t)i * 128 * 128;
    const __bf16* KE2bi = KE2b + (size_t)i * 128 * 128;
    const __bf16* KN1bi = KN1b + (size_t)i * 128 * 384;
    const __bf16* KN2bi = KN2b + (size_t)i * 128 * 128;
    const __bf16* a1a2i = a1a2b + (size_t)i * 256 * 128;

    // D statistics -> pA
    dstat_k<<<2080, 256, 0, stream>>>(xnNb, sbufh, pA);

    // UVb[n][256] = xnNb @ a1a2^T (bf16 out)
    nmfma_k<128, false, false, false, 0, false, 1><<<dim3(64, 16), 256, 0, stream>>>(
        a1a2i, xnNb, BNUL, UVb, nullptr, nullptr, NUL, 256, nullptr, PNUL, 0, 0.0, BNULm, NULm);

    // edge pass 1 (w inline from pA): eA = xe @ KE1^T + w*(U_I+V_J), stats -> pB
    emfma_k<2, 128, 4, true, 4><<<dim3(NEDGES / 256, 2), 256, 0, stream>>>(
        KE1bi, xeT, eAT, pB, UVb, xnNb, sbufh, iI, jJ, wbuf, pA, PNUL, 0, 0.0);
    // edge pass 2: eB = tanh(ln(eA)) @ KE2^T, params<-pB, stats -> pC
    emfma_k<1, 128, 4, false, 4><<<dim3(NEDGES / 256, 2), 256, 0, stream>>>(
        KE2bi, eAT, eBT, pC, BNUL, BNUL, NUL, NULI, NULI, FNULm, PNUL,
        pB, 512, (double)CH * NEDGES);
    // xe += 0.1 * ln(eB), params<-pC
    lnres_k<<<2048, 256, 0, stream>>>(eBT, xeT, pC, 512);

    // node update: gather -> catb; KN1 (split cat+xn) stats -> pB; KN2 tanh + resid + emit
    gather_k<<<NNODES / 4, 512, 0, stream>>>(xeT, wbuf, csr_offs, csr_list, catb);
    nmfma_k<384, true, false, true, 0, false, 1><<<dim3(64, 8), 256, 0, stream>>>(
        KN1bi, catb, xnNb, nAb, nullptr, nullptr, NUL, 128, pB, PNUL, 0, 0.0, BNULm, NULm);
    nmfma_k<128, false, true, false, 4, true, 4><<<dim3(64, 2), 256, 0, stream>>>(
        KN2bi, nAb, BNUL, nullptr, nullptr, xnN, NUL, 128, nullptr,
        pB, 512, (double)CH * NNODES, xnNb, sbufh);
  }

  // ---- close + MLP head (bf16 MFMA, node-major) ----
  nmfma_k<128, false, false, false, 0, false, 1><<<dim3(64, 8), 256, 0, stream>>>(
      KNcb, xnNb, BNUL, zb, nullptr, nullptr, NUL, 128, nullptr, PNUL, 0, 0.0, BNULm, NULm);
  nmfma_k<128, false, false, false, 1, false, 1><<<dim3(64, 16), 256, 0, stream>>>(
      W1b, zb, BNUL, l1bb, nullptr, nullptr, b1, 256, nullptr, PNUL, 0, 0.0, BNULm, NULm);
  nmfma_k<256, false, false, false, 2, false, 1><<<dim3(64, 64), 256, 0, stream>>>(
      W2b, l1bb, BNUL, nullptr, out, nullptr, b2, 1024, nullptr, PNUL, 0, 0.0, BNULm, NULm);
  logsoftmax_k<<<NNODES, 256, 0, stream>>>(out);
}

// Round 13
// 658.767 us; speedup vs baseline: 2.3297x; 1.0116x over previous
//
#include <hip/hip_runtime.h>

#define NNODES 4096
#define NEDGES 65536
#define CH 128

typedef __bf16 bf16x8_t __attribute__((ext_vector_type(8)));
typedef __bf16 bf16x4_t __attribute__((ext_vector_type(4)));
typedef __bf16 bf16x2_t __attribute__((ext_vector_type(2)));
typedef float f32x4_t __attribute__((ext_vector_type(4)));

// ---- fast tanh via hw exp2/rcp ----
__device__ __forceinline__ float fast_tanh(float x)
{
  float t = __builtin_amdgcn_exp2f(x * 2.885390081777927f);   // 2*log2(e)
  return 1.f - 2.f * __builtin_amdgcn_rcpf(t + 1.f);
}

// ---- block stats writer: f32 wave shfl-reduce, one float2 per block ----
__device__ __forceinline__ void write_stats(float s, float q, float2* __restrict__ partials,
                                            int pid, int tid, int nwaves)
{
#pragma unroll
  for (int d = 1; d < 64; d <<= 1) { s += __shfl_xor(s, d); q += __shfl_xor(q, d); }
  __shared__ float rs[8][2];
  const int wv = tid >> 6, lane = tid & 63;
  if (lane == 0) { rs[wv][0] = s; rs[wv][1] = q; }
  __syncthreads();
  if (tid == 0) {
    float S = 0.f, Q = 0.f;
    for (int i = 0; i < nwaves; ++i) { S += rs[i][0]; Q += rs[i][1]; }
    partials[pid] = {S, Q};
  }
}

// ---- inline params: f64 cross-block reduce of f32 partials -> (mean,rstd) or (factor,0) ----
__device__ __forceinline__ float2 params_inline(const float2* __restrict__ pp,
                                                int nblk, double M, int type)
{
  const int tid = threadIdx.x;
  double s = 0.0, q = 0.0;
  for (int i = tid; i < nblk; i += 256) { float2 v = pp[i]; s += (double)v.x; q += (double)v.y; }
#pragma unroll
  for (int d = 1; d < 64; d <<= 1) { s += __shfl_xor(s, d); q += __shfl_xor(q, d); }
  __shared__ double rs4[4], rq4[4];
  __shared__ float pr[2];
  const int wv = tid >> 6, lane = tid & 63;
  if (lane == 0) { rs4[wv] = s; rq4[wv] = q; }
  __syncthreads();
  if (tid == 0) {
    double S = rs4[0] + rs4[1] + rs4[2] + rs4[3];
    double Q = rq4[0] + rq4[1] + rq4[2] + rq4[3];
    if (type == 0) {
      double mean = S / M;
      double var = Q / M - mean * mean;
      if (var < 0.0) var = 0.0;
      pr[0] = (float)mean;
      pr[1] = (float)(1.0 / sqrt(var + 1e-5));
    } else {
      double var = (Q - S * S / M) / (M - 1.0);
      if (var < 1e-30) var = 1e-30;
      pr[0] = (float)(-2.0 / sqrt(var));
      pr[1] = 0.f;
    }
  }
  __syncthreads();
  return {pr[0], pr[1]};
}

// ================= bf16 MFMA edge GEMM: EPB edge-groups (64 each) per block =================
// grid (E/(64*EPB), 8/OBS). EM 0: plain, stats   EM 2: + w*(U[I]+V[J]), stats (WPH inline w)
// EM 1: tanh-on-load, stats   EM 3: tanh-on-load, no stats
template<int EM, int K, int OBS, bool WPH, int EPB>
__global__ __launch_bounds__(256) void emfma_k(
    const __bf16* __restrict__ A, const __bf16* __restrict__ X,
    __bf16* __restrict__ Cb,
    float2* __restrict__ partials,
    const __bf16* __restrict__ UVb, const __bf16* __restrict__ xnNb,
    const float* __restrict__ sbufh,
    const int* __restrict__ iI, const int* __restrict__ jJ,
    float* __restrict__ wbuf, const float2* __restrict__ pD,
    const float2* __restrict__ pp, int pnblk, double pM)
{
  __shared__ float wl[64 * EPB];
  __shared__ int il[64 * EPB], jl[64 * EPB];
  const int tid = threadIdx.x;
  const int wv = tid >> 6, lane = tid & 63;
  const int l15 = lane & 15, ks = lane >> 4;
  const int row = wv * 16 + l15;
  const int base_e = blockIdx.x * 64 * EPB;
  constexpr int KK = K / 32;
  // hoisted raw X loads for all groups
  bf16x8_t bq[EPB][KK];
#pragma unroll
  for (int g = 0; g < EPB; ++g) {
    const __bf16* xr = X + (size_t)(base_e + g * 64 + row) * K + ks * 8;
#pragma unroll
    for (int kk = 0; kk < KK; ++kk) bq[g][kk] = *(const bf16x8_t*)(xr + kk * 32);
  }
  if constexpr (WPH) {
    static_assert(EPB == 4, "WPH assumes 256 edges/block");
    double s = 0.0, q = 0.0;
    for (int i = tid; i < 2080; i += 256) { float2 v = pD[i]; s += (double)v.x; q += (double)v.y; }
    const int eg = base_e + tid;
    const int a = iI[eg], b = jJ[eg];
    il[tid] = a; jl[tid] = b;
    const bf16x8_t* pa = (const bf16x8_t*)(xnNb + (size_t)a * CH);
    const bf16x8_t* pb = (const bf16x8_t*)(xnNb + (size_t)b * CH);
    float g0 = 0.f, g1 = 0.f, g2 = 0.f, g3 = 0.f;
#pragma unroll
    for (int q16 = 0; q16 < 16; q16 += 4) {
      bf16x8_t u0 = pa[q16],     v0 = pb[q16];
      bf16x8_t u1 = pa[q16 + 1], v1 = pb[q16 + 1];
      bf16x8_t u2 = pa[q16 + 2], v2 = pb[q16 + 2];
      bf16x8_t u3 = pa[q16 + 3], v3 = pb[q16 + 3];
#pragma unroll
      for (int j = 0; j < 8; ++j) {
        g0 = fmaf((float)u0[j], (float)v0[j], g0);
        g1 = fmaf((float)u1[j], (float)v1[j], g1);
        g2 = fmaf((float)u2[j], (float)v2[j], g2);
        g3 = fmaf((float)u3[j], (float)v3[j], g3);
      }
    }
    float gg = (g0 + g1) + (g2 + g3);
    float dd = sbufh[a] + sbufh[NNODES + a] + sbufh[b] + sbufh[NNODES + b] - 2.f * gg;
    dd = dd > 0.f ? dd : 0.f;
#pragma unroll
    for (int d = 1; d < 64; d <<= 1) { s += __shfl_xor(s, d); q += __shfl_xor(q, d); }
    __shared__ double rs4[4], rq4[4];
    __shared__ float prf;
    if (lane == 0) { rs4[wv] = s; rq4[wv] = q; }
    __syncthreads();
    if (tid == 0) {
      double S = rs4[0] + rs4[1] + rs4[2] + rs4[3];
      double Q = rq4[0] + rq4[1] + rq4[2] + rq4[3];
      const double M = (double)NNODES * (double)NNODES;
      double var = (Q - S * S / M) / (M - 1.0);
      if (var < 1e-30) var = 1e-30;
      prf = (float)(-2.0 / sqrt(var));
    }
    __syncthreads();
    float wgt = __builtin_amdgcn_exp2f(prf * dd * 1.4426950408889634f);
    wl[tid] = wgt;
    if (blockIdx.y == 0) wbuf[eg] = wgt;
    __syncthreads();
  }
  if constexpr (EM == 1 || EM == 3) {
    float2 pr = params_inline(pp, pnblk, pM, 0);
    const float p0 = pr.x, p1 = pr.y;
#pragma unroll
    for (int g = 0; g < EPB; ++g)
#pragma unroll
      for (int kk = 0; kk < KK; ++kk) {
#pragma unroll
        for (int j = 0; j < 8; ++j)
          bq[g][kk][j] = (__bf16)fast_tanh(((float)bq[g][kk][j] - p0) * p1);
      }
  }
  float dsum = 0.f, dsq = 0.f;
  const int ob0 = blockIdx.y * OBS;
#pragma unroll
  for (int g = 0; g < EPB; ++g) {
    const int e = base_e + g * 64 + row;
    float we = 0.f; int ie = 0, je = 0;
    if constexpr (EM == 2) { we = wl[g * 64 + row]; ie = il[g * 64 + row]; je = jl[g * 64 + row]; }
#pragma unroll
    for (int obb = 0; obb < OBS; ++obb) {
      const int ob = ob0 + obb;
      f32x4_t acc = {0.f, 0.f, 0.f, 0.f};
      const __bf16* ar = A + (size_t)(ob * 16 + l15) * K + ks * 8;
#pragma unroll
      for (int kk = 0; kk < KK; ++kk) {
        bf16x8_t a = *(const bf16x8_t*)(ar + kk * 32);
        acc = __builtin_amdgcn_mfma_f32_16x16x32_bf16(a, bq[g][kk], acc, 0, 0, 0);
      }
      const int ro = ob * 16 + ks * 4;
      float v0 = acc[0], v1 = acc[1], v2 = acc[2], v3 = acc[3];
      if constexpr (EM == 2) {
        bf16x4_t u4 = *(const bf16x4_t*)&UVb[(size_t)ie * 256 + ro];
        bf16x4_t w4 = *(const bf16x4_t*)&UVb[(size_t)je * 256 + 128 + ro];
        v0 += we * ((float)u4[0] + (float)w4[0]);
        v1 += we * ((float)u4[1] + (float)w4[1]);
        v2 += we * ((float)u4[2] + (float)w4[2]);
        v3 += we * ((float)u4[3] + (float)w4[3]);
      }
      if constexpr (EM != 3) {
        dsum += v0 + v1 + v2 + v3;
        dsq  += v0 * v0 + v1 * v1 + v2 * v2 + v3 * v3;
      }
      bf16x4_t bv;
      bv[0] = (__bf16)v0; bv[1] = (__bf16)v1; bv[2] = (__bf16)v2; bv[3] = (__bf16)v3;
      *(bf16x4_t*)(Cb + (size_t)e * 128 + ro) = bv;
    }
  }
  if constexpr (EM != 3)
    write_stats(dsum, dsq, partials, blockIdx.y * gridDim.x + blockIdx.x, tid, 4);
}

// ================= bf16 MFMA node GEMM, col-tiled, OBS outs/block =================
// OM 0: bf16 out; 1: +bias elu bf16 out; 2: +bias f32 out; 3: f32 out; 4: resid[n][128] += 0.1*v
template<int K, bool XSPLIT, bool XT, bool STATS, int OM, bool EMITB, int OBS>
__global__ __launch_bounds__(256) void nmfma_k(
    const __bf16* __restrict__ A, const __bf16* __restrict__ X,
    const __bf16* __restrict__ X2,
    __bf16* __restrict__ Cb, float* __restrict__ Cf, float* __restrict__ resid,
    const float* __restrict__ bias, int nout_stride,
    float2* __restrict__ partials,
    const float2* __restrict__ pp, int pnblk, double pM,
    __bf16* __restrict__ xbout, float* __restrict__ shout)
{
  const int tid = threadIdx.x;
  const int wv = tid >> 6, lane = tid & 63;
  const int l15 = lane & 15, ks = lane >> 4;
  const int n = blockIdx.x * 64 + wv * 16 + l15;
  constexpr int KK = K / 32;
  bf16x8_t bq[KK];
  if constexpr (XSPLIT) {
    const __bf16* xr  = X  + (size_t)n * 256 + ks * 8;
    const __bf16* xr2 = X2 + (size_t)n * 128 + ks * 8;
#pragma unroll
    for (int kk = 0; kk < 8; ++kk) bq[kk] = *(const bf16x8_t*)(xr + kk * 32);
#pragma unroll
    for (int kk = 8; kk < KK; ++kk) bq[kk] = *(const bf16x8_t*)(xr2 + (kk - 8) * 32);
  } else {
    const __bf16* xr = X + (size_t)n * K + ks * 8;
#pragma unroll
    for (int kk = 0; kk < KK; ++kk) bq[kk] = *(const bf16x8_t*)(xr + kk * 32);
  }
  if constexpr (XT) {
    float2 pr = params_inline(pp, pnblk, pM, 0);
    const float p0 = pr.x, p1 = pr.y;
#pragma unroll
    for (int kk = 0; kk < KK; ++kk) {
#pragma unroll
      for (int j = 0; j < 8; ++j)
        bq[kk][j] = (__bf16)fast_tanh(((float)bq[kk][j] - p0) * p1);
    }
  }
  float dsum = 0.f, dsq = 0.f, ss = 0.f;
  const int ob0 = blockIdx.y * OBS;
#pragma unroll
  for (int obb = 0; obb < OBS; ++obb) {
    const int ob = ob0 + obb;
    f32x4_t acc = {0.f, 0.f, 0.f, 0.f};
    const __bf16* ar = A + (size_t)(ob * 16 + l15) * K + ks * 8;
#pragma unroll
    for (int kk = 0; kk < KK; ++kk) {
      bf16x8_t a = *(const bf16x8_t*)(ar + kk * 32);
      acc = __builtin_amdgcn_mfma_f32_16x16x32_bf16(a, bq[kk], acc, 0, 0, 0);
    }
    const int ro = ob * 16 + ks * 4;
    float v[4] = {acc[0], acc[1], acc[2], acc[3]};
    if constexpr (OM == 1 || OM == 2) {
#pragma unroll
      for (int r = 0; r < 4; ++r) v[r] += bias[ro + r];
    }
    if constexpr (OM == 1) {
#pragma unroll
      for (int r = 0; r < 4; ++r) v[r] = v[r] > 0.f ? v[r] : expm1f(v[r]);
    }
    if constexpr (STATS) {
#pragma unroll
      for (int r = 0; r < 4; ++r) { dsum += v[r]; dsq += v[r] * v[r]; }
    }
    if constexpr (OM == 4) {
      float4* rp = (float4*)&resid[(size_t)n * 128 + ro];
      float4 rr = *rp;
      rr.x += 0.1f * v[0]; rr.y += 0.1f * v[1]; rr.z += 0.1f * v[2]; rr.w += 0.1f * v[3];
      *rp = rr;
      if constexpr (EMITB) {
        bf16x4_t eb;
        eb[0] = (__bf16)rr.x; eb[1] = (__bf16)rr.y; eb[2] = (__bf16)rr.z; eb[3] = (__bf16)rr.w;
        *(bf16x4_t*)(xbout + (size_t)n * 128 + ro) = eb;
#pragma unroll
        for (int r = 0; r < 4; ++r) { float f = (float)eb[r]; ss += f * f; }
      }
    } else if constexpr (OM == 2 || OM == 3) {
      float4 fv = {v[0], v[1], v[2], v[3]};
      *(float4*)(Cf + (size_t)n * nout_stride + ro) = fv;
      if constexpr (EMITB) {
        bf16x4_t eb;
        eb[0] = (__bf16)v[0]; eb[1] = (__bf16)v[1]; eb[2] = (__bf16)v[2]; eb[3] = (__bf16)v[3];
        *(bf16x4_t*)(xbout + (size_t)n * 128 + ro) = eb;
#pragma unroll
        for (int r = 0; r < 4; ++r) { float f = (float)eb[r]; ss += f * f; }
      }
    } else {
      bf16x4_t bv;
      bv[0] = (__bf16)v[0]; bv[1] = (__bf16)v[1]; bv[2] = (__bf16)v[2]; bv[3] = (__bf16)v[3];
      *(bf16x4_t*)(Cb + (size_t)n * nout_stride + ro) = bv;
    }
  }
  if constexpr (EMITB) {
    ss += __shfl_xor(ss, 16);
    ss += __shfl_xor(ss, 32);
    if (lane < 16) shout[blockIdx.y * NNODES + n] = ss;
  }
  if constexpr (STATS)
    write_stats(dsum, dsq, partials, blockIdx.y * gridDim.x + blockIdx.x, tid, 4);
}

// ================= merged dstat (blocks 0..2079) + UV GEMM (blocks 2080..3103) =================
__global__ __launch_bounds__(256) void duv_k(
    const __bf16* __restrict__ fT, const float* __restrict__ sh,
    float2* __restrict__ partials,
    const __bf16* __restrict__ a1a2i, __bf16* __restrict__ UVb)
{
  const int tid = threadIdx.x;
  const int wv = tid >> 6, lane = tid & 63, l15 = lane & 15, ks = lane >> 4;
  if (blockIdx.x < 2080) {
    // ---- dstat tile ----
    int rem = blockIdx.x, i0t = 0;
    while (rem >= 64 - i0t) { rem -= 64 - i0t; ++i0t; }
    const int i0 = i0t * 64, j0 = (i0t + rem) * 64;
    const float wgt = (j0 > i0) ? 2.f : 1.f;
    const int irow = i0 + wv * 16 + l15;
    bf16x8_t aq[4];
    const __bf16* ar = fT + (size_t)irow * 128 + ks * 8;
#pragma unroll
    for (int kk = 0; kk < 4; ++kk) aq[kk] = *(const bf16x8_t*)(ar + kk * 32);
    float si[4];
#pragma unroll
    for (int r = 0; r < 4; ++r) {
      int ii = i0 + wv * 16 + ks * 4 + r;
      si[r] = sh[ii] + sh[NNODES + ii];
    }
    float dsum = 0.f, dsq = 0.f;
#pragma unroll
    for (int jb = 0; jb < 4; ++jb) {
      const int jcol = j0 + jb * 16 + l15;
      const __bf16* br = fT + (size_t)jcol * 128 + ks * 8;
      f32x4_t acc = {0.f, 0.f, 0.f, 0.f};
#pragma unroll
      for (int kk = 0; kk < 4; ++kk) {
        bf16x8_t b = *(const bf16x8_t*)(br + kk * 32);
        acc = __builtin_amdgcn_mfma_f32_16x16x32_bf16(aq[kk], b, acc, 0, 0, 0);
      }
      const float sj = sh[jcol] + sh[NNODES + jcol];
#pragma unroll
      for (int r = 0; r < 4; ++r) {
        float d = si[r] + sj - 2.f * acc[r];
        d = d > 0.f ? d : 0.f;
        dsum += d; dsq += d * d;
      }
    }
    write_stats(dsum * wgt, dsq * wgt, partials, blockIdx.x, tid, 4);
  } else {
    // ---- UV tile: UVb[n][256] = xnNb @ a1a2^T ----
    const int ub = blockIdx.x - 2080;
    const int ux = ub & 63, ob = ub >> 6;          // 64 x-tiles, 16 out-tiles
    const int n = ux * 64 + wv * 16 + l15;
    bf16x8_t bq[4];
    const __bf16* xr = fT + (size_t)n * 128 + ks * 8;
#pragma unroll
    for (int kk = 0; kk < 4; ++kk) bq[kk] = *(const bf16x8_t*)(xr + kk * 32);
    f32x4_t acc = {0.f, 0.f, 0.f, 0.f};
    const __bf16* ar = a1a2i + (size_t)(ob * 16 + l15) * 128 + ks * 8;
#pragma unroll
    for (int kk = 0; kk < 4; ++kk) {
      bf16x8_t a = *(const bf16x8_t*)(ar + kk * 32);
      acc = __builtin_amdgcn_mfma_f32_16x16x32_bf16(a, bq[kk], acc, 0, 0, 0);
    }
    const int ro = ob * 16 + ks * 4;
    bf16x4_t bv;
    bv[0] = (__bf16)acc[0]; bv[1] = (__bf16)acc[1];
    bv[2] = (__bf16)acc[2]; bv[3] = (__bf16)acc[3];
    *(bf16x4_t*)(UVb + (size_t)n * 256 + ro) = bv;
  }
}

// ================= transpose src [64][ncols] f32 -> dst [ncols][64] bf16 =================
__global__ __launch_bounds__(256) void etrans_k(const float* __restrict__ src,
                                                __bf16* __restrict__ dst, int ncols)
{
  __shared__ float t[64][65];
  const int e0 = blockIdx.x * 64;
  const int tx = threadIdx.x & 63, tw = threadIdx.x >> 6;
  for (int c = tw; c < 64; c += 4)
    t[tx][c] = src[(size_t)c * ncols + e0 + tx];
  __syncthreads();
  const int el = threadIdx.x >> 2, c0 = (threadIdx.x & 3) * 16;
  for (int q = 0; q < 4; ++q) {
    int c = c0 + q * 4;
    bf16x4_t b;
    b[0] = (__bf16)t[el][c];     b[1] = (__bf16)t[el][c + 1];
    b[2] = (__bf16)t[el][c + 2]; b[3] = (__bf16)t[el][c + 3];
    *(bf16x4_t*)&dst[(size_t)(e0 + el) * 64 + c] = b;
  }
}

// ================= weight conversion to bf16 (one launch) =================
__global__ void wcvt_k(const float* __restrict__ K1E, const float* __restrict__ K2E,
                       const float* __restrict__ KE1, const float* __restrict__ KE2,
                       const float* __restrict__ KNc, const float* __restrict__ W1,
                       const float* __restrict__ W2, const float* __restrict__ KN1,
                       const float* __restrict__ KN2, const float* __restrict__ K1N,
                       const float* __restrict__ K2N,
                       __bf16* __restrict__ K1Eb, __bf16* __restrict__ K2Eb,
                       __bf16* __restrict__ KE1b, __bf16* __restrict__ KE2b,
                       __bf16* __restrict__ KNcb, __bf16* __restrict__ W1b,
                       __bf16* __restrict__ W2b, __bf16* __restrict__ KN1b,
                       __bf16* __restrict__ KN2b, __bf16* __restrict__ a1a2b,
                       __bf16* __restrict__ K1Nb, __bf16* __restrict__ K2Nb)
{
  int id = blockIdx.x * 256 + threadIdx.x;
  if (id < 8192) { K1Eb[id] = (__bf16)K1E[id]; return; }
  id -= 8192;
  if (id < 16384) { K2Eb[id] = (__bf16)K2E[id]; return; }
  id -= 16384;
  if (id < 65536) {
    int l = id >> 14, rem = id & 16383, r = rem >> 7, c = rem & 127;
    KE1b[id] = (__bf16)KE1[(size_t)l * 49152 + r * 384 + 128 + c];
    return;
  }
  id -= 65536;
  if (id < 65536) { KE2b[id] = (__bf16)KE2[id]; return; }
  id -= 65536;
  if (id < 16384) { KNcb[id] = (__bf16)KNc[id]; return; }
  id -= 16384;
  if (id < 32768) { W1b[id] = (__bf16)W1[id]; return; }
  id -= 32768;
  if (id < 262144) { W2b[id] = (__bf16)W2[id]; return; }
  id -= 262144;
  if (id < 196608) { KN1b[id] = (__bf16)KN1[id]; return; }
  id -= 196608;
  if (id < 65536) { KN2b[id] = (__bf16)KN2[id]; return; }
  id -= 65536;
  if (id < 131072) {
    int l = id >> 15, rem = id & 32767, r = rem >> 7, c = rem & 127;
    int o = r & 127;
    float k1 = KE1[(size_t)l * 49152 + o * 384 + c];
    float k3 = KE1[(size_t)l * 49152 + o * 384 + 256 + c];
    a1a2b[id] = (__bf16)((r < 128) ? (0.5f * k1 + k3) : (0.5f * k1 - k3));
    return;
  }
  id -= 131072;
  if (id < 8192) { K1Nb[id] = (__bf16)K1N[id]; return; }
  id -= 8192;
  if (id < 16384) { K2Nb[id] = (__bf16)K2N[id]; return; }
}

// ================= lnres: xeT = bf16(f32(xeT) + 0.1*ln(eB)) =================
__global__ __launch_bounds__(256) void lnres_k(
    const __bf16* __restrict__ eBT, __bf16* __restrict__ xeT,
    const float2* __restrict__ pp, int pnblk)
{
  const size_t base = (size_t)blockIdx.x * (256 * 16);
  const size_t i0 = base + (size_t)threadIdx.x * 8;
  const size_t i1 = i0 + 2048;
  bf16x8_t b0 = *(const bf16x8_t*)(eBT + i0);
  bf16x8_t x0 = *(const bf16x8_t*)(xeT + i0);
  bf16x8_t b1 = *(const bf16x8_t*)(eBT + i1);
  bf16x8_t x1 = *(const bf16x8_t*)(xeT + i1);
  float2 pr = params_inline(pp, pnblk, (double)CH * NEDGES, 0);
  const float m = pr.x, r = pr.y;
  bf16x8_t o0, o1;
#pragma unroll
  for (int j = 0; j < 8; ++j) {
    o0[j] = (__bf16)((float)x0[j] + 0.1f * (((float)b0[j] - m) * r));
    o1[j] = (__bf16)((float)x1[j] + 0.1f * (((float)b1[j] - m) * r));
  }
  *(bf16x8_t*)(xeT + i0) = o0;
  *(bf16x8_t*)(xeT + i1) = o1;
}

// ================= CSR build =================
__global__ void hist_k(const int* __restrict__ iI, const int* __restrict__ jJ,
                       int* __restrict__ cnt)
{
  int e = blockIdx.x * 256 + threadIdx.x;
  atomicAdd(&cnt[iI[e]], 1);
  atomicAdd(&cnt[jJ[e]], 1);
}

__global__ __launch_bounds__(1024) void scan_k(const int* __restrict__ cnt,
                                               int* __restrict__ offs,
                                               int* __restrict__ cursor)
{
  __shared__ int tmp[1024];
  const int tid = threadIdx.x;
  int4 v = *(const int4*)&cnt[tid * 4];
  int s = v.x + v.y + v.z + v.w;
  tmp[tid] = s; __syncthreads();
  for (int d = 1; d < 1024; d <<= 1) {
    int t = (tid >= d) ? tmp[tid - d] : 0;
    __syncthreads();
    tmp[tid] += t;
    __syncthreads();
  }
  int base = tmp[tid] - s;
  int4 o = {base, base + v.x, base + v.x + v.y, base + v.x + v.y + v.z};
  *(int4*)&offs[tid * 4] = o;
  *(int4*)&cursor[tid * 4] = o;
  if (tid == 1023) offs[4096] = tmp[1023];
}

__global__ void fill_k(const int* __restrict__ iI, const int* __restrict__ jJ,
                       int* __restrict__ cursor, int* __restrict__ list)
{
  int e = blockIdx.x * 256 + threadIdx.x;
  int p1 = atomicAdd(&cursor[iI[e]], 1);
  list[p1] = e;
  int p2 = atomicAdd(&cursor[jJ[e]], 1);
  list[p2] = e | 0x80000000;
}

// ================= gather: 8 waves, 2 per node (incidence-split) -> catb bf16 [n][256] =================
__global__ __launch_bounds__(512) void gather_k(
    const __bf16* __restrict__ xeT, const float* __restrict__ w,
    const int* __restrict__ offs, const int* __restrict__ list,
    __bf16* __restrict__ catb)
{
  __shared__ float comb[4][4][64];
  const int wv = threadIdx.x >> 6, lane = threadIdx.x & 63;
  const int nn = wv >> 1, half = wv & 1;
  const int n = blockIdx.x * 4 + nn;
  const int k0 = offs[n], k1 = offs[n + 1];
  float s1a = 0.f, s1b = 0.f, s2a = 0.f, s2b = 0.f;
#pragma unroll 2
  for (int k = k0 + half; k < k1; k += 2) {
    int enc = list[k];
    int e = enc & 0x7fffffff;
    float we = w[e];
    bf16x2_t xv = *(const bf16x2_t*)&xeT[(size_t)e * 128 + lane * 2];
    float va = (float)xv[0] * we;
    float vb = (float)xv[1] * we;
    if (enc >= 0) { s1a += va; s1b += vb; }
    else          { s2a += va; s2b += vb; }
  }
  if (half == 1) {
    comb[nn][0][lane] = s1a; comb[nn][1][lane] = s1b;
    comb[nn][2][lane] = s2a; comb[nn][3][lane] = s2b;
  }
  __syncthreads();
  if (half == 0) {
    s1a += comb[nn][0][lane]; s1b += comb[nn][1][lane];
    s2a += comb[nn][2][lane]; s2b += comb[nn][3][lane];
    __bf16* row = catb + (size_t)n * 256;
    bf16x2_t av, dv;
    av[0] = (__bf16)(0.5f * (s1a + s2a)); av[1] = (__bf16)(0.5f * (s1b + s2b));
    dv[0] = (__bf16)(s1a - s2a);          dv[1] = (__bf16)(s1b - s2b);
    *(bf16x2_t*)&row[lane * 2] = av;
    *(bf16x2_t*)&row[128 + lane * 2] = dv;
  }
}

// ================= log_softmax rows of [N][1024] =================
__global__ __launch_bounds__(256) void logsoftmax_k(float* __restrict__ out)
{
  __shared__ float red[256];
  const int n = blockIdx.x, tid = threadIdx.x;
  float* row = out + (size_t)n * 1024;
  float v[4];
  float mx = -1e30f;
#pragma unroll
  for (int l = 0; l < 4; ++l) { v[l] = row[tid + 256 * l]; mx = fmaxf(mx, v[l]); }
  red[tid] = mx; __syncthreads();
  for (int s = 128; s > 0; s >>= 1) { if (tid < s) red[tid] = fmaxf(red[tid], red[tid + s]); __syncthreads(); }
  float m = red[0]; __syncthreads();
  float se = 0.f;
#pragma unroll
  for (int l = 0; l < 4; ++l) se += expf(v[l] - m);
  red[tid] = se; __syncthreads();
  for (int s = 128; s > 0; s >>= 1) { if (tid < s) red[tid] += red[tid + s]; __syncthreads(); }
  float L = m + logf(red[0]);
#pragma unroll
  for (int l = 0; l < 4; ++l) row[tid + 256 * l] = v[l] - L;
}

extern "C" void kernel_launch(void* const* d_in, const int* in_sizes, int n_in,
                              void* d_out, int out_size, void* d_ws, size_t ws_size,
                              hipStream_t stream)
{
  (void)in_sizes; (void)n_in; (void)out_size; (void)ws_size;
  const float* xn_in = (const float*)d_in[0];
  const float* xe_in = (const float*)d_in[1];
  const int*   iI    = (const int*)d_in[2];
  const int*   jJ    = (const int*)d_in[3];
  const float* K1N   = (const float*)d_in[4];
  const float* K2N   = (const float*)d_in[5];
  const float* K1E   = (const float*)d_in[6];
  const float* K2E   = (const float*)d_in[7];
  const float* KNc   = (const float*)d_in[8];
  const float* KE1   = (const float*)d_in[9];
  const float* KE2   = (const float*)d_in[10];
  const float* KN1   = (const float*)d_in[11];
  const float* KN2   = (const float*)d_in[12];
  const float* W1    = (const float*)d_in[13];
  const float* b1    = (const float*)d_in[14];
  const float* W2    = (const float*)d_in[15];
  const float* b2    = (const float*)d_in[16];
  float* out = (float*)d_out;

  float* ws = (float*)d_ws;
  size_t off = 0;
  auto alloc = [&](size_t n) { size_t o = off; off += (n + 63) & ~(size_t)63; return o; };
  float* xnN   = ws + alloc((size_t)NNODES * CH);                  // f32 node-major master
  __bf16* xeT  = (__bf16*)(ws + alloc((size_t)NEDGES * CH / 2));   // bf16 edge state
  __bf16* eAT  = (__bf16*)(ws + alloc((size_t)NEDGES * CH / 2));
  __bf16* eBT  = (__bf16*)(ws + alloc((size_t)NEDGES * CH / 2));
  float* sbufh = ws + alloc(2 * NNODES);                           // sqnorm halves
  float* wbuf  = ws + alloc(NEDGES);
  __bf16* UVb  = (__bf16*)(ws + alloc((size_t)NNODES * 256 / 2));
  __bf16* xnNb = (__bf16*)(ws + alloc((size_t)NNODES * CH / 2));
  __bf16* catb = (__bf16*)(ws + alloc((size_t)NNODES * 256 / 2));
  __bf16* nAb  = (__bf16*)(ws + alloc((size_t)NNODES * CH / 2));
  __bf16* zb   = (__bf16*)(ws + alloc((size_t)NNODES * CH / 2));
  __bf16* l1bb = (__bf16*)(ws + alloc((size_t)NNODES * 256 / 2));
  __bf16* K1Eb = (__bf16*)(ws + alloc(8192 / 2));
  __bf16* K2Eb = (__bf16*)(ws + alloc(16384 / 2));
  __bf16* KE1b = (__bf16*)(ws + alloc(65536 / 2));
  __bf16* KE2b = (__bf16*)(ws + alloc(65536 / 2));
  __bf16* KNcb = (__bf16*)(ws + alloc(16384 / 2));
  __bf16* W1b  = (__bf16*)(ws + alloc(32768 / 2));
  __bf16* W2b  = (__bf16*)(ws + alloc(262144 / 2));
  __bf16* KN1b = (__bf16*)(ws + alloc(196608 / 2));
  __bf16* KN2b = (__bf16*)(ws + alloc(65536 / 2));
  __bf16* a1a2b= (__bf16*)(ws + alloc(131072 / 2));
  __bf16* K1Nb = (__bf16*)(ws + alloc(8192 / 2));
  __bf16* K2Nb = (__bf16*)(ws + alloc(16384 / 2));
  int* csr_cnt    = (int*)(ws + alloc(4096));
  int* csr_offs   = (int*)(ws + alloc(4160));
  int* csr_cursor = (int*)(ws + alloc(4096));
  int* csr_list   = (int*)(ws + alloc(2 * NEDGES));
  float2* pA = (float2*)(ws + alloc((size_t)4096 * 2));
  float2* pB = (float2*)(ws + alloc((size_t)4096 * 2));
  float2* pC = (float2*)(ws + alloc((size_t)4096 * 2));
  // aliases (lifetimes disjoint): opening-only transposed inputs
  __bf16* xeT64  = eBT;               // [E][64], eBT first written layer-0 emfma pass 2
  __bf16* xnT64b = UVb;               // [N][64], UVb first written layer-0 duv

  const __bf16* BNUL = nullptr;
  const float* NUL = nullptr;
  const int* NULI = nullptr;
  const float2* PNUL = nullptr;
  __bf16* BNULm = nullptr;
  float* NULm = nullptr;
  float* FNULm = nullptr;

  // ---- weight conversion + CSR build (once) ----
  wcvt_k<<<3456, 256, 0, stream>>>(K1E, K2E, KE1, KE2, KNc, W1, W2, KN1, KN2, K1N, K2N,
                                   K1Eb, K2Eb, KE1b, KE2b, KNcb, W1b, W2b, KN1b, KN2b,
                                   a1a2b, K1Nb, K2Nb);
  hipMemsetAsync(csr_cnt, 0, 4096 * sizeof(int), stream);
  hist_k<<<NEDGES / 256, 256, 0, stream>>>(iI, jJ, csr_cnt);
  scan_k<<<1, 1024, 0, stream>>>(csr_cnt, csr_offs, csr_cursor);
  fill_k<<<NEDGES / 256, 256, 0, stream>>>(iI, jJ, csr_cursor, csr_list);

  // ---- opening: node double layer (MFMA, node-major, emits xnNb + sqnorm) ----
  etrans_k<<<NNODES / 64, 256, 0, stream>>>(xn_in, xnT64b, NNODES);
  nmfma_k<64, false, false, true, 0, false, 1><<<dim3(64, 8), 256, 0, stream>>>(
      K1Nb, xnT64b, BNUL, nAb, nullptr, nullptr, NUL, 128, pA, PNUL, 0, 0.0, BNULm, NULm);
  nmfma_k<128, false, true, false, 3, true, 4><<<dim3(64, 2), 256, 0, stream>>>(
      K2Nb, nAb, BNUL, nullptr, xnN, nullptr, NUL, 128, nullptr,
      pA, 512, (double)CH * NNODES, xnNb, sbufh);

  // ---- opening: edge double layer (MFMA, EPB=4, y=2) ----
  etrans_k<<<NEDGES / 64, 256, 0, stream>>>(xe_in, xeT64, NEDGES);
  emfma_k<0, 64, 4, false, 4><<<dim3(NEDGES / 256, 2), 256, 0, stream>>>(
      K1Eb, xeT64, eAT, pA, BNUL, BNUL, NUL, NULI, NULI, FNULm, PNUL, PNUL, 0, 0.0);
  emfma_k<3, 128, 4, false, 4><<<dim3(NEDGES / 256, 2), 256, 0, stream>>>(
      K2Eb, eAT, xeT, nullptr, BNUL, BNUL, NUL, NULI, NULI, FNULm, PNUL,
      pA, 512, (double)CH * NEDGES);

  for (int i = 0; i < 4; ++i) {
    const __bf16* KE1bi = KE1b + (size_t)i * 128 * 128;
    const __bf16* KE2bi = KE2b + (size_t)i * 128 * 128;
    const __bf16* KN1bi = KN1b + (size_t)i * 128 * 384;
    const __bf16* KN2bi = KN2b + (size_t)i * 128 * 128;
    const __bf16* a1a2i = a1a2b + (size_t)i * 256 * 128;

    // merged: D statistics -> pA  ||  UVb = xnNb @ a1a2^T
    duv_k<<<3104, 256, 0, stream>>>(xnNb, sbufh, pA, a1a2i, UVb);

    // edge pass 1 (w inline from pA): eA = xe @ KE1^T + w*(U_I+V_J), stats -> pB
    emfma_k<2, 128, 4, true, 4><<<dim3(NEDGES / 256, 2), 256, 0, stream>>>(
        KE1bi, xeT, eAT, pB, UVb, xnNb, sbufh, iI, jJ, wbuf, pA, PNUL, 0, 0.0);
    // edge pass 2: eB = tanh(ln(eA)) @ KE2^T, params<-pB, stats -> pC
    emfma_k<1, 128, 4, false, 4><<<dim3(NEDGES / 256, 2), 256, 0, stream>>>(
        KE2bi, eAT, eBT, pC, BNUL, BNUL, NUL, NULI, NULI, FNULm, PNUL,
        pB, 512, (double)CH * NEDGES);
    // xe += 0.1 * ln(eB), params<-pC
    lnres_k<<<2048, 256, 0, stream>>>(eBT, xeT, pC, 512);

    // node update: gather -> catb; KN1 (split cat+xn) stats -> pB; KN2 tanh + resid + emit
    gather_k<<<NNODES / 4, 512, 0, stream>>>(xeT, wbuf, csr_offs, csr_list, catb);
    nmfma_k<384, true, false, true, 0, false, 1><<<dim3(64, 8), 256, 0, stream>>>(
        KN1bi, catb, xnNb, nAb, nullptr, nullptr, NUL, 128, pB, PNUL, 0, 0.0, BNULm, NULm);
    nmfma_k<128, false, true, false, 4, true, 4><<<dim3(64, 2), 256, 0, stream>>>(
        KN2bi, nAb, BNUL, nullptr, nullptr, xnN, NUL, 128, nullptr,
        pB, 512, (double)CH * NNODES, xnNb, sbufh);
  }

  // ---- close + MLP head (bf16 MFMA, node-major) ----
  nmfma_k<128, false, false, false, 0, false, 1><<<dim3(64, 8), 256, 0, stream>>>(
      KNcb, xnNb, BNUL, zb, nullptr, nullptr, NUL, 128, nullptr, PNUL, 0, 0.0, BNULm, NULm);
  nmfma_k<128, false, false, false, 1, false, 1><<<dim3(64, 16), 256, 0, stream>>>(
      W1b, zb, BNUL, l1bb, nullptr, nullptr, b1, 256, nullptr, PNUL, 0, 0.0, BNULm, NULm);
  nmfma_k<256, false, false, false, 2, false, 1><<<dim3(64, 64), 256, 0, stream>>>(
      W2b, l1bb, BNUL, nullptr, out, nullptr, b2, 1024, nullptr, PNUL, 0, 0.0, BNULm, NULm);
  logsoftmax_k<<<NNODES, 256, 0, stream>>>(out);
}